// Round 8
// baseline (1591.686 us; speedup 1.0000x reference)
//
#include <hip/hip_runtime.h>

typedef unsigned short u16;
typedef unsigned int u32;

typedef __attribute__((ext_vector_type(8))) __bf16 bf16x8;
typedef __attribute__((ext_vector_type(4))) float f32x4;

__device__ __forceinline__ float bf2f(u16 u) {
    u32 t = ((u32)u) << 16;
    float f;
    __builtin_memcpy(&f, &t, 4);
    return f;
}
__device__ __forceinline__ u16 f2bf(float f) {
    u32 u;
    __builtin_memcpy(&u, &f, 4);
    u32 r = (u + 0x7fffu + ((u >> 16) & 1u)) >> 16;
    return (u16)r;
}
__device__ __forceinline__ float tanh_fast(float x) {
    float xc = fminf(fmaxf(x, -15.f), 15.f);
    float e = __expf(2.f * xc);
    return (e - 1.f) * __builtin_amdgcn_rcpf(e + 1.f);
}

// Async global->LDS DMA, 16B per lane. LDS dest = wave-uniform base + lane*16.
__device__ __forceinline__ void gld16(const u16* g, u16* l) {
    __builtin_amdgcn_global_load_lds(
        (const __attribute__((address_space(1))) u32*)(uintptr_t)g,
        (__attribute__((address_space(3))) u32*)(u32)(uintptr_t)l,
        16, 0, 0);
}

// XCD-aware bijective block swizzle (T1, m204 formula). MI355X round-robins
// consecutive blocks across 8 XCDs with private L2s; this remap gives each
// XCD a CONTIGUOUS chunk of logical tiles so tap-neighbor / shared-panel
// reads hit the local L2 instead of re-fetching from HBM (R6 PMC: conv4
// FETCH 188 MB vs ~54 ideal = 3.5x overfetch). Bijective for any nwg.
__device__ __forceinline__ int xcd_swz(int orig, int nwg) {
    const int xcd = orig & 7, base = orig >> 3;
    const int q = nwg >> 3, r = nwg & 7;
    return (xcd < r ? xcd * (q + 1) : r * (q + 1) + (xcd - r) * q) + base;
}

// LDS bank swizzle (round 5, kept): chunk c (16B) of row r staged into slot
// (c + (r>>1)) & 3; consumer reads chunk qd of row R at (qd + (R>>1)) & 3.
// Verified round 5: SQ_LDS_BANK_CONFLICT 5.5M -> 0.

// ---------------------------------------------------------------------------
// bf16 MFMA GEMM, tile 128 x NT, SINGLE-BARRIER PIPELINED K-LOOP (round 6).
// Round 11: + XCD swizzle on blockIdx.x (content-neutral tile permutation).
// A: [spatial][Bc][ldA] (k-contiguous). W: [T][N][ldW]. T==9 -> 3x3 conv via
// shift-GEMM. EPI 0: relu(acc*epiA[n]+epiB[n]); EPI 1: tanh(acc+epiB[n]).
// ---------------------------------------------------------------------------
template <int EPI, int NT>
__global__ __launch_bounds__(256, 3) void gemm_bt(
    const u16* __restrict__ A, const u16* __restrict__ W, u16* __restrict__ O,
    const float* __restrict__ epiA, const float* __restrict__ epiB,
    int Kin, int N, int T, int Himg, int Wimg,
    int ldA, int ldW, int ldO,
    long long Az, long long Wz, long long Oz, int epiZ,
    int Bc, int bshift)
{
    constexpr int NJ = NT / 32;          // 4 (NT=128) or 2 (NT=64)
    __shared__ __align__(16) u16 lsA[2][128 * 32];
    __shared__ __align__(16) u16 lsW[2][NT * 32];

    const int tid = threadIdx.x;
    const int z = blockIdx.z;
    A += (long long)z * Az;
    W += (long long)z * Wz;
    O += (long long)z * Oz;
    epiB += (long long)z * epiZ;

    const int m0 = xcd_swz(blockIdx.x, gridDim.x) * 128;
    const int n0 = blockIdx.y * NT;
    const int s = m0 >> bshift;          // spatial index (0 for MLP)
    const int b0 = m0 & (Bc - 1);        // batch offset
    const int hh0 = s / Wimg, ww0 = s % Wimg;

    const int wave = tid >> 6;
    const int lane = tid & 63;
    const int mbase = (wave >> 1) * 64;
    const int nbase = (wave & 1) * (NT / 2);
    const int ln = lane & 15, qd = lane >> 4;

    const int srow = lane >> 2;                                // staging row in 16-slab
    const int sc = (((lane & 3) - ((srow >> 1) & 3)) & 3) * 8; // swizzled fetch chunk
    const int csel = ((qd + (ln >> 1)) & 3) * 8;               // swizzled read chunk

    // lane-constant staging offsets (elems)
    const int rowA = wave * 32 + srow;
    const int rowW = (NT == 128) ? (wave * 32 + srow) : (wave * 16 + srow);
    const int offA0 = rowA * ldA + sc;
    const int offA1 = offA0 + 16 * ldA;
    const int offW0 = rowW * ldW + sc;
    const int offW1 = offW0 + 16 * ldW;   // NT==128 only
    u16* const lA0 = &lsA[0][0] + wave * 1024;
    u16* const lW0 = (NT == 128) ? (&lsW[0][0] + wave * 1024) : (&lsW[0][0] + wave * 512);
    constexpr int LPAR_A = 128 * 32;      // parity stride (elems)
    constexpr int LPAR_W = NT * 32;

    // tap helpers (all wave-uniform)
    auto tapvalid = [&](int t) -> bool {
        if (T != 9) return true;
        const int hh = hh0 + t / 3 - 1, ww = ww0 + t % 3 - 1;
        return hh >= 0 && hh < Himg && ww >= 0 && ww < Wimg;
    };
    auto tapA = [&](int t) -> const u16* {
        int sp = s;
        if (T == 9) sp = (hh0 + t / 3 - 1) * Wimg + (ww0 + t % 3 - 1);
        return A + (long long)(sp * Bc + b0) * ldA;
    };

    int t0 = 0;
    while (!tapvalid(t0)) ++t0;
    int nvalid = 0;
    for (int t = 0; t < T; ++t) nvalid += tapvalid(t) ? 1 : 0;
    const int KS = Kin >> 5;
    const int S = nvalid * KS;

    const u16* Ab = tapA(t0);
    const u16* Wb = W + ((long long)t0 * N + n0) * ldW;

    // prologue: prefetch step 0 into parity 0
    gld16(Ab + offA0, lA0);
    gld16(Ab + offA1, lA0 + 512);
    gld16(Wb + offW0, lW0);
    if (NT == 128) gld16(Wb + offW1, lW0 + 512);

    int ntap = t0, nkk = 0;

    f32x4 acc[4][NJ];
#pragma unroll
    for (int i = 0; i < 4; ++i)
#pragma unroll
        for (int j = 0; j < NJ; ++j)
            acc[i][j] = (f32x4){0.f, 0.f, 0.f, 0.f};

    for (int st = 0; st < S; ++st) {
        __syncthreads();   // drains prefetch issued at st-1 (had full MFMA phase in flight)
        if (st + 1 < S) {
            nkk += 32;
            if (nkk == Kin) {
                nkk = 0;
                do { ++ntap; } while (!tapvalid(ntap));
                Ab = tapA(ntap);
                Wb = W + ((long long)ntap * N + n0) * ldW;
            }
            const int pp = (st + 1) & 1;
            gld16(Ab + offA0 + nkk, lA0 + pp * LPAR_A);
            gld16(Ab + offA1 + nkk, lA0 + pp * LPAR_A + 512);
            gld16(Wb + offW0 + nkk, lW0 + pp * LPAR_W);
            if (NT == 128) gld16(Wb + offW1 + nkk, lW0 + pp * LPAR_W + 512);
        }
        const int cp = st & 1;
        bf16x8 af[4], bfr[NJ];
#pragma unroll
        for (int f = 0; f < 4; ++f)
            af[f] = *(const bf16x8*)&lsA[cp][(mbase + f * 16 + ln) * 32 + csel];
#pragma unroll
        for (int f = 0; f < NJ; ++f)
            bfr[f] = *(const bf16x8*)&lsW[cp][(nbase + f * 16 + ln) * 32 + csel];
#pragma unroll
        for (int i = 0; i < 4; ++i)
#pragma unroll
            for (int j = 0; j < NJ; ++j)
                acc[i][j] = __builtin_amdgcn_mfma_f32_16x16x32_bf16(
                    af[i], bfr[j], acc[i][j], 0, 0, 0);
    }

#pragma unroll
    for (int j = 0; j < NJ; ++j) {
        const int n = n0 + nbase + j * 16 + ln;
        const float sh = epiB[n];
        float sc2 = 1.f;
        if (EPI == 0) sc2 = epiA[n];
#pragma unroll
        for (int i = 0; i < 4; ++i) {
            const int mrow = mbase + i * 16 + qd * 4;
#pragma unroll
            for (int rr = 0; rr < 4; ++rr) {
                float v = acc[i][j][rr];
                if (EPI == 0) v = fmaxf(v * sc2 + sh, 0.f);
                else          v = tanh_fast(v + sh);
                O[(long long)(m0 + mrow + rr) * ldO + n] = f2bf(v);
            }
        }
    }
}

// ---------------------------------------------------------------------------
// FUSED MLP (Linear->tanh, 5 n-tiles) + logits (600->10 via 640->16) +
// softmax. Round 11: lsH halved to one 64-col chunk (128x68) and the logits
// GEMM runs in two chunk passes -> LDS 66.3 KB -> 49 KB -> 3 blocks/CU
// (occupancy was the limiter for this barrier-latency-bound loop; cross-block
// overlap is the hiding mechanism). Chunk cc is written only by the waves
// whose nbase==cc*64 (their acc holds exactly those columns); all waves then
// MFMA that chunk's 64 k-cols into acc_lg. Same fragments, same MFMA
// accumulation order -> values bit-identical to round 10. + XCD swizzle over
// linearized (x,z) so same-node blocks (sharing the 450 KB W panel) land on
// the same XCD's L2.
// ---------------------------------------------------------------------------
template <int STAGE>
__global__ __launch_bounds__(256, 3) void mlp_head(
    const u16* __restrict__ A, const u16* __restrict__ W,
    const float* __restrict__ bap, const u16* __restrict__ Wbp,
    const float* __restrict__ bbp,
    u16* __restrict__ preds, float* __restrict__ dout,
    int Kin, int Bc, int gbase)
{
    __shared__ __align__(16) u16 lsA[2][128 * 32];
    __shared__ __align__(16) u16 lsW[2][128 * 32];
    __shared__ __align__(16) u16 lsH[128 * 68];   // one 64-col chunk (+4 pad)

    const int tid = threadIdx.x;
    const int nwg = gridDim.x * 25;
    const int lin = xcd_swz(blockIdx.z * gridDim.x + blockIdx.x, nwg);
    const int z = lin / gridDim.x;            // node 0..24
    const int m0 = (lin % gridDim.x) * 128;   // batch row base

    A += (long long)z * Bc * Kin;
    W += (long long)z * 640 * 352;
    const float* bz = bap + z * 640;

    const int wave = tid >> 6;
    const int lane = tid & 63;
    const int mbase = (wave >> 1) * 64;
    const int nbase = (wave & 1) * 64;
    const int wsel = wave & 1;                // chunk ownership
    const int ln = lane & 15, qd = lane >> 4;
    const int srow = lane >> 2;
    const int sc = (((lane & 3) - ((srow >> 1) & 3)) & 3) * 8;
    const int csel = ((qd + (ln >> 1)) & 3) * 8;

    const int rowS = wave * 32 + srow;
    const int offA0 = rowS * Kin + sc;        // ldA = Kin
    const int offA1 = offA0 + 16 * Kin;
    const int offW0 = rowS * 352 + sc;        // ldW = 352
    const int offW1 = offW0 + 16 * 352;
    u16* const lA0 = &lsA[0][0] + wave * 1024;
    u16* const lW0 = &lsW[0][0] + wave * 1024;

    const int KS = Kin >> 5;                  // 8 (stage1) or 11 (stage2)
    const int Stot = 5 * KS;

    const u16* Ab = A + (long long)m0 * Kin;
    const u16* Wb = W;
    int pnt = 0, pnkk = 0;

    // prologue: prefetch flat step 0 into parity 0
    gld16(Ab + offA0, lA0);
    gld16(Ab + offA1, lA0 + 512);
    gld16(Wb + offW0, lW0);
    gld16(Wb + offW1, lW0 + 512);

    f32x4 acc[4][4];
#pragma unroll
    for (int i = 0; i < 4; ++i)
#pragma unroll
        for (int j = 0; j < 4; ++j)
            acc[i][j] = (f32x4){0.f, 0.f, 0.f, 0.f};
    f32x4 acc_lg[2];
    acc_lg[0] = (f32x4){0.f, 0.f, 0.f, 0.f};
    acc_lg[1] = (f32x4){0.f, 0.f, 0.f, 0.f};

    int g = 0;   // flat step index
    for (int nt = 0; nt < 5; ++nt) {
        for (int st = 0; st < KS; ++st, ++g) {
            __syncthreads();   // drains prefetch issued at g-1
            if (g + 1 < Stot) {
                pnkk += 32;
                if (pnkk == Kin) {   // next n-tile: K wraps, W column base advances
                    pnkk = 0;
                    ++pnt;
                    Wb = W + (long long)pnt * 128 * 352;
                }
                const int pp = (g + 1) & 1;
                gld16(Ab + offA0 + pnkk, lA0 + pp * (128 * 32));
                gld16(Ab + offA1 + pnkk, lA0 + pp * (128 * 32) + 512);
                gld16(Wb + offW0 + pnkk, lW0 + pp * (128 * 32));
                gld16(Wb + offW1 + pnkk, lW0 + pp * (128 * 32) + 512);
            }
            const int cp = g & 1;
            bf16x8 af[4], bfr[4];
#pragma unroll
            for (int f = 0; f < 4; ++f)
                af[f] = *(const bf16x8*)&lsA[cp][(mbase + f * 16 + ln) * 32 + csel];
#pragma unroll
            for (int f = 0; f < 4; ++f)
                bfr[f] = *(const bf16x8*)&lsW[cp][(nbase + f * 16 + ln) * 32 + csel];
#pragma unroll
            for (int i = 0; i < 4; ++i)
#pragma unroll
                for (int j = 0; j < 4; ++j)
                    acc[i][j] = __builtin_amdgcn_mfma_f32_16x16x32_bf16(
                        af[i], bfr[j], acc[i][j], 0, 0, 0);
        }

        // ---- tile epilogue in two 64-col chunks ----
        // cc=0 needs no pre-write barrier: the K-loop's barriers already
        // ordered the previous tile's chunk-1 readers before these writes.
#pragma unroll
        for (int cc = 0; cc < 2; ++cc) {
            if (cc) __syncthreads();          // chunk-0 lsH reads done
            if (wsel == cc) {
#pragma unroll
                for (int j = 0; j < 4; ++j) {
                    const int hcl = j * 16 + ln;          // chunk-local col 0..63
                    const float sh = bz[nt * 128 + cc * 64 + hcl];
#pragma unroll
                    for (int i = 0; i < 4; ++i) {
                        const int br = mbase + i * 16 + qd * 4;
#pragma unroll
                        for (int rr = 0; rr < 4; ++rr)
                            lsH[(br + rr) * 68 + hcl] =
                                f2bf(tanh_fast(acc[i][j][rr] + sh));
                    }
                }
            }
            // hoist logits B-frags for this chunk (global, L2-hot)
            bf16x8 bfrg[2];
#pragma unroll
            for (int ks = 0; ks < 2; ++ks)
                bfrg[ks] = *(const bf16x8*)&Wbp[((long long)z * 16 + ln) * 640 +
                                                nt * 128 + cc * 64 + ks * 32 + qd * 8];
            __syncthreads();                  // h chunk visible

            // logits partial GEMM over this chunk's 64 h-cols
#pragma unroll
            for (int ks = 0; ks < 2; ++ks) {
#pragma unroll
                for (int i = 0; i < 2; ++i) {
                    const int base = (wave * 32 + i * 16 + ln) * 68 + ks * 32 + qd * 8;
                    const uint2 u0 = *(const uint2*)&lsH[base];
                    const uint2 u1 = *(const uint2*)&lsH[base + 4];
                    u32 w4[4] = {u0.x, u0.y, u1.x, u1.y};
                    bf16x8 a8;
                    __builtin_memcpy(&a8, w4, 16);
                    acc_lg[i] = __builtin_amdgcn_mfma_f32_16x16x32_bf16(
                        a8, bfrg[ks], acc_lg[i], 0, 0, 0);
                }
            }
        }
#pragma unroll
        for (int i = 0; i < 4; ++i)
#pragma unroll
            for (int j = 0; j < 4; ++j)
                acc[i][j] = (f32x4){0.f, 0.f, 0.f, 0.f};
        // next tile's first K-step barrier orders lsH reuse
    }

    // softmax over the 16-lane group (pad cols have bbp=-1e30 -> excluded)
    const float bias = bbp[z * 16 + ln];
#pragma unroll
    for (int i = 0; i < 2; ++i) {
#pragma unroll
        for (int rr = 0; rr < 4; ++rr) {
            const float v = acc_lg[i][rr] + bias;
            float mx = v;
#pragma unroll
            for (int mk = 1; mk < 16; mk <<= 1)
                mx = fmaxf(mx, __shfl_xor(mx, mk));
            const float e = __expf(v - mx);
            float ssum = e;
#pragma unroll
            for (int mk = 1; mk < 16; mk <<= 1)
                ssum += __shfl_xor(ssum, mk);
            const float p = e / ssum;
            const int row = m0 + wave * 32 + i * 16 + qd * 4 + rr;
            if (ln < 10) {
                if (STAGE == 1)
                    preds[((long long)z * Bc + row) * 10 + ln] = f2bf(p);
                else
                    dout[81920 + ((long long)z * 8192 + gbase + row) * 10 + ln] = p;
            }
        }
    }
}

// ---------------------------------------------------------------------------
// FUSED conv1 + BN + ReLU + maxpool3s2p1, v2 (round 8): NO LDS, NO BARRIERS.
// Round 11: + XCD swizzle over linearized (x,y) so blocks sharing xcol tap
// rows (same pooled position) co-locate on one XCD's L2.
// ---------------------------------------------------------------------------
__global__ __launch_bounds__(256) void conv1pool(
    const u16* __restrict__ xcol, const u16* __restrict__ W1t, u16* __restrict__ p1,
    const float* __restrict__ epiA, const float* __restrict__ epiB, int Bc)
{
    const int tid = threadIdx.x;
    const int wave = tid >> 6;
    const int lane = tid & 63;
    const int ln = lane & 15, qd = lane >> 4;

    const int nwg = gridDim.x * gridDim.y;
    const int lin = xcd_swz(blockIdx.y * gridDim.x + blockIdx.x, nwg);
    const int b0 = (lin % gridDim.x) * 128;
    const int so = lin / gridDim.x;       // pooled spatial index 0..99
    const int ho = so / 10, wo = so % 10;

    const int mbase = (wave >> 1) * 64;
    const int nbase = (wave & 1) * 32;

    bf16x8 bfr[2];
#pragma unroll
    for (int j = 0; j < 2; ++j)
        bfr[j] = *(const bf16x8*)&W1t[(nbase + j * 16 + ln) * 32 + qd * 8];

    float sc2[2], sh[2];
#pragma unroll
    for (int j = 0; j < 2; ++j) {
        const int n = nbase + j * 16 + ln;
        sc2[j] = epiA[n];
        sh[j] = epiB[n];
    }

    f32x4 best[4][2];
#pragma unroll
    for (int i = 0; i < 4; ++i)
#pragma unroll
        for (int j = 0; j < 2; ++j)
            best[i][j] = (f32x4){0.f, 0.f, 0.f, 0.f};

#pragma unroll
    for (int st = 0; st < 9; ++st) {
        int hh = 2 * ho - 1 + st / 3;
        int ww = 2 * wo - 1 + st % 3;
        hh = hh < 0 ? 0 : (hh > 19 ? 19 : hh);
        ww = ww < 0 ? 0 : (ww > 19 ? 19 : ww);
        const u16* Ab = xcol + (long long)((hh * 20 + ww) * Bc + b0) * 32;

        bf16x8 af[4];
#pragma unroll
        for (int f = 0; f < 4; ++f)
            af[f] = *(const bf16x8*)&Ab[(mbase + f * 16 + ln) * 32 + qd * 8];

#pragma unroll
        for (int i = 0; i < 4; ++i)
#pragma unroll
            for (int j = 0; j < 2; ++j) {
                f32x4 acc = (f32x4){0.f, 0.f, 0.f, 0.f};
                acc = __builtin_amdgcn_mfma_f32_16x16x32_bf16(af[i], bfr[j], acc, 0, 0, 0);
#pragma unroll
                for (int rr = 0; rr < 4; ++rr) {
                    const float v = fmaxf(acc[rr] * sc2[j] + sh[j], 0.f);
                    best[i][j][rr] = fmaxf(best[i][j][rr], v);
                }
            }
    }

#pragma unroll
    for (int j = 0; j < 2; ++j) {
        const int n = nbase + j * 16 + ln;
#pragma unroll
        for (int i = 0; i < 4; ++i) {
            const int mrow = mbase + i * 16 + qd * 4;
#pragma unroll
            for (int rr = 0; rr < 4; ++rr)
                p1[(long long)(so * Bc + b0 + mrow + rr) * 64 + n] = f2bf(best[i][j][rr]);
        }
    }
}

// ---------------------------------------------------------------------------
// x chunk [Bc,3,20,20] fp32 -> xt [400][Bc][4] bf16 (ch padded to 4, pad=0)
// ---------------------------------------------------------------------------
__global__ __launch_bounds__(256) void transpose_x(
    const float* __restrict__ x, u16* __restrict__ xt, int Bc, int bshift)
{
    const int t = blockIdx.x * 256 + threadIdx.x;
    if (t >= 400 * Bc) return;
    const int s = t >> bshift;
    const int b = t & (Bc - 1);
    const u32 c0 = f2bf(x[((long long)b * 3 + 0) * 400 + s]);
    const u32 c1 = f2bf(x[((long long)b * 3 + 1) * 400 + s]);
    const u32 c2 = f2bf(x[((long long)b * 3 + 2) * 400 + s]);
    uint2 st;
    st.x = c0 | (c1 << 16);
    st.y = c2;                              // high 16 = 0 pad
    *(uint2*)(xt + ((long long)s * Bc + b) * 4) = st;
}

// ---------------------------------------------------------------------------
// im2col for conv1: xt[400][Bc][4] -> xcol[400][Bc][32] (k = tap*3+ci, pad 0).
// ---------------------------------------------------------------------------
__global__ __launch_bounds__(256) void im2col1(
    const u16* __restrict__ xt, u16* __restrict__ xcol, int Bc, int bshift)
{
    const int t = blockIdx.x * 256 + threadIdx.x;
    if (t >= 400 * Bc) return;
    const int s = t >> bshift;
    const int b = t & (Bc - 1);
    const int hh = s / 20, ww = s % 20;

    u32 p0, q0, p1, q1, p2, q2, p3, q3, p4, q4, p5, q5, p6, q6, p7, q7, p8, q8;
#define LOADTAP(T, P, Q)                                                      \
    {                                                                         \
        const int ih = hh + (T) / 3 - 1, iw = ww + (T) % 3 - 1;               \
        P = 0u; Q = 0u;                                                       \
        if (ih >= 0 && ih < 20 && iw >= 0 && iw < 20) {                       \
            const uint2 v = *(const uint2*)(xt +                              \
                ((long long)(ih * 20 + iw) * Bc + b) * 4);                    \
            P = v.x; Q = v.y;                                                 \
        }                                                                     \
    }
    LOADTAP(0, p0, q0) LOADTAP(1, p1, q1) LOADTAP(2, p2, q2)
    LOADTAP(3, p3, q3) LOADTAP(4, p4, q4) LOADTAP(5, p5, q5)
    LOADTAP(6, p6, q6) LOADTAP(7, p7, q7) LOADTAP(8, p8, q8)
#undef LOADTAP

    u16* o = xcol + (long long)t * 32;
    uint4 w;
    w.x = p0;                w.y = q0 | (p1 << 16);
    w.z = (p1 >> 16) | (q1 << 16);
    w.w = p2;
    *(uint4*)(o + 0) = w;
    w.x = q2 | (p3 << 16);   w.y = (p3 >> 16) | (q3 << 16);
    w.z = p4;                w.w = q4 | (p5 << 16);
    *(uint4*)(o + 8) = w;
    w.x = (p5 >> 16) | (q5 << 16);
    w.y = p6;                w.z = q6 | (p7 << 16);
    w.w = (p7 >> 16) | (q7 << 16);
    *(uint4*)(o + 16) = w;
    w.x = p8;                w.y = q8;   // k=24..26 (+pad)
    w.z = 0u;                w.w = 0u;
    *(uint4*)(o + 24) = w;
}

// ---------------------------------------------------------------------------
// maxpool 3x3 s2 p1, square maps: src[Hi*Hi][Bc][CH] -> dst[Ho*Ho][Bc][CH].
// ---------------------------------------------------------------------------
template <int CH>
__global__ __launch_bounds__(256) void pool_k(
    const u16* __restrict__ src, u16* __restrict__ dst, int Bc, int Hi, int Ho)
{
    constexpr int G = CH / 8;
    const int t = blockIdx.x * 256 + threadIdx.x;
    const int cc = t & (G - 1);
    const int b = t / G;
    if (b >= Bc) return;
    const int so = blockIdx.y;
    const int ho = so / Ho, wo = so % Ho;
    float best[8];
#pragma unroll
    for (int e = 0; e < 8; ++e) best[e] = 0.f;
    for (int ph = 0; ph < 3; ++ph) {
        const int hh = 2 * ho - 1 + ph;
        if (hh < 0 || hh >= Hi) continue;
        for (int pw = 0; pw < 3; ++pw) {
            const int ww = 2 * wo - 1 + pw;
            if (ww < 0 || ww >= Hi) continue;
            const uint4 u = *(const uint4*)(src + ((long long)(hh * Hi + ww) * Bc + b) * CH + cc * 8);
            const u32 uw[4] = {u.x, u.y, u.z, u.w};
#pragma unroll
            for (int e = 0; e < 4; ++e) {
                best[2 * e]     = fmaxf(best[2 * e],     bf2f((u16)(uw[e] & 0xffff)));
                best[2 * e + 1] = fmaxf(best[2 * e + 1], bf2f((u16)(uw[e] >> 16)));
            }
        }
    }
    u32 pk[4];
#pragma unroll
    for (int e = 0; e < 4; ++e)
        pk[e] = (u32)f2bf(best[2 * e]) | (((u32)f2bf(best[2 * e + 1])) << 16);
    uint4 st;
    st.x = pk[0]; st.y = pk[1]; st.z = pk[2]; st.w = pk[3];
    *(uint4*)(dst + ((long long)so * Bc + b) * CH + cc * 8) = st;
}

// ---------------------------------------------------------------------------
// Stage-2 input assembly.
// ---------------------------------------------------------------------------
__device__ __forceinline__ void neighbors5x5(int i, int* nb) {
    const int w = 5, size = 25;
    int cnt = 0;
    if (i - w >= 0) nb[cnt++] = i - w;
    if (i % w != 0) nb[cnt++] = i - 1;
    if ((i + 1) % w != 0) nb[cnt++] = i + 1;
    if (i + w < size) nb[cnt++] = i + w;
    if (i - w - 1 >= 0 && i % w != 0) nb[cnt++] = i - w - 1;
    if (i - w + 1 >= 0 && (i + 1) % w != 0) nb[cnt++] = i - w + 1;
    if (i + w - 1 < size && i % w != 0) nb[cnt++] = i + w - 1;
    if (i + w + 1 < size && (i + 1) % w != 0) nb[cnt++] = i + w + 1;
    for (; cnt < 8; ++cnt) nb[cnt] = -1;
}

__global__ __launch_bounds__(256) void gather_nb(
    const u16* __restrict__ preds, const u16* __restrict__ feats, u16* __restrict__ A2,
    int Bc, int bshift)
{
    const int g = blockIdx.x * 256 + threadIdx.x;  // n*Bc+b
    if (g >= 25 * Bc) return;
    const int n = g >> bshift;
    const int b = g & (Bc - 1);
    int nb[8];
    neighbors5x5(n, nb);
    u16* dst = A2 + (long long)g * 352;
#pragma unroll
    for (int j = 0; j < 8; ++j) {
        u32* d32 = (u32*)(dst + j * 10);
        if (nb[j] >= 0) {
            const u32* s32 = (const u32*)(preds + ((long long)nb[j] * Bc + b) * 10);
#pragma unroll
            for (int q = 0; q < 5; ++q) d32[q] = s32[q];
        } else {
#pragma unroll
            for (int q = 0; q < 5; ++q) d32[q] = 0u;
        }
    }
    const uint4* fs = (const uint4*)(feats + (long long)g * 256);
    uint4* fd = (uint4*)(dst + 80);
#pragma unroll
    for (int q = 0; q < 32; ++q) fd[q] = fs[q];
    uint4 z;
    z.x = 0u; z.y = 0u; z.z = 0u; z.w = 0u;
    *(uint4*)(dst + 336) = z;
    *(uint4*)(dst + 344) = z;
}

__global__ __launch_bounds__(256) void mean_k(float* __restrict__ dout)
{
    const int t = blockIdx.x * 256 + threadIdx.x;
    float s = 0.f;
#pragma unroll
    for (int n = 0; n < 25; ++n) s += dout[81920 + n * 81920 + t];
    dout[t] = s * 0.04f;
}

// ---------------------------------------------------------------------------
// Weight/param prep (once per launch)
// ---------------------------------------------------------------------------
__global__ void prep_bn_all(
    const float* b1, const float* g1, const float* be1, const float* m1, const float* v1,
    const float* b2, const float* g2, const float* be2, const float* m2, const float* v2,
    const float* b3, const float* g3, const float* be3, const float* m3, const float* v3,
    const float* b4, const float* g4, const float* be4, const float* m4, const float* v4,
    float* bnA, float* bnB)
{
    const int t = blockIdx.x * 256 + threadIdx.x;
    if (t >= 704) return;
    const float *bp, *gp, *bep, *mp, *vp;
    int idx;
    if (t < 64)       { bp=b1; gp=g1; bep=be1; mp=m1; vp=v1; idx=t; }
    else if (t < 192) { bp=b2; gp=g2; bep=be2; mp=m2; vp=v2; idx=t-64; }
    else if (t < 448) { bp=b3; gp=g3; bep=be3; mp=m3; vp=v3; idx=t-192; }
    else              { bp=b4; gp=g4; bep=be4; mp=m4; vp=v4; idx=t-448; }
    const float A = gp[idx] * rsqrtf(vp[idx] + 1e-5f);
    bnA[t] = A;
    bnB[t] = (bp[idx] - mp[idx]) * A + bep[idx];
}

// W1 [64][3][3][3] -> W1t [64][32], k = tap*3+ci (tap = kh*3+kw), pad 0
__global__ void prep_w1col(const float* __restrict__ W1, u16* __restrict__ W1t)
{
    const int t = blockIdx.x * 256 + threadIdx.x;
    if (t >= 64 * 32) return;
    const int n = t >> 5, k = t & 31;
    u16 v = 0;
    if (k < 27) {
        const int tap = k / 3, ci = k % 3;
        v = f2bf(W1[n * 27 + ci * 9 + tap]);
    }
    W1t[t] = v;
}

// W [Co][Ci][3][3] fp32 -> Wt [9][Co][Ci] bf16
__global__ void prep_convw(const float* __restrict__ W, u16* __restrict__ Wt, int Co, int Ci)
{
    const int t = blockIdx.x * 256 + threadIdx.x;
    const int tot = 9 * Co * Ci;
    if (t >= tot) return;
    const int sh = t / (Co * Ci);
    const int rem = t % (Co * Ci);
    const int co = rem / Ci, ci = rem % Ci;
    Wt[t] = f2bf(W[(long long)(co * Ci + ci) * 9 + sh]);
}

__global__ void prep_wat(const float* __restrict__ Wa, u16* __restrict__ Wat)
{
    const int t = blockIdx.x * 256 + threadIdx.x;
    if (t >= 25 * 640 * 352) return;
    const int n = t / (640 * 352);
    const int rem = t % (640 * 352);
    const int hcol = rem / 352;
    const int k = rem % 352;
    float v = 0.f;
    if (hcol < 600 && k < 336) v = Wa[((long long)n * 336 + k) * 600 + hcol];
    Wat[t] = f2bf(v);
}

__global__ void prep_ba(const float* __restrict__ ba, float* __restrict__ bap)
{
    const int t = blockIdx.x * 256 + threadIdx.x;
    if (t >= 25 * 640) return;
    const int n = t / 640, hcol = t % 640;
    bap[t] = (hcol < 600) ? ba[n * 600 + hcol] : 0.f;
}

// Wb [25][600][10] fp32 -> Wbp [25][16][640] bf16 (transposed, zero-pad);
// bb [25][10] -> bbp [25][16] fp32 (pad -1e30 so softmax ignores pad cols)
__global__ void prep_wbt(const float* __restrict__ Wb, const float* __restrict__ bb,
                         u16* __restrict__ Wbp, float* __restrict__ bbp)
{
    const int t = blockIdx.x * 256 + threadIdx.x;
    if (t < 25 * 16 * 640) {
        const int n = t / (16 * 640);
        const int rem = t % (16 * 640);
        const int c = rem / 640, k = rem % 640;
        u16 v = 0;
        if (c < 10 && k < 600) v = f2bf(Wb[((long long)n * 600 + k) * 10 + c]);
        Wbp[t] = v;
    }
    if (t < 25 * 16) {
        const int n = t >> 4, c = t & 15;
        bbp[t] = (c < 10) ? bb[n * 10 + c] : -1e30f;
    }
}

// ---------------------------------------------------------------------------
extern "C" void kernel_launch(void* const* d_in, const int* in_sizes, int n_in,
                              void* d_out, int out_size, void* d_ws, size_t ws_size,
                              hipStream_t stream)
{
    (void)in_sizes; (void)n_in; (void)out_size;

    const float* x  = (const float*)d_in[0];
    const float* W1 = (const float*)d_in[1];
    const float* b1 = (const float*)d_in[2];
    const float* g1 = (const float*)d_in[3];
    const float* be1= (const float*)d_in[4];
    const float* m1 = (const float*)d_in[5];
    const float* v1 = (const float*)d_in[6];
    const float* W2 = (const float*)d_in[7];
    const float* b2 = (const float*)d_in[8];
    const float* g2 = (const float*)d_in[9];
    const float* be2= (const float*)d_in[10];
    const float* m2 = (const float*)d_in[11];
    const float* v2 = (const float*)d_in[12];
    const float* W3 = (const float*)d_in[13];
    const float* b3 = (const float*)d_in[14];
    const float* g3 = (const float*)d_in[15];
    const float* be3= (const float*)d_in[16];
    const float* m3 = (const float*)d_in[17];
    const float* v3 = (const float*)d_in[18];
    const float* W4 = (const float*)d_in[19];
    const float* b4 = (const float*)d_in[20];
    const float* g4 = (const float*)d_in[21];
    const float* be4= (const float*)d_in[22];
    const float* m4 = (const float*)d_in[23];
    const float* v4 = (const float*)d_in[24];
    const float* Wa = (const float*)d_in[25];
    const float* ba = (const float*)d_in[26];
    const float* Wb = (const float*)d_in[27];
    const float* bb = (const float*)d_in[28];
    float* dout = (float*)d_out;

    // ---- choose Bc: overlay peak = 44032 bytes per batch element ----
    auto al = [](long long v) { return (v + 255LL) & ~255LL; };
    const long long fixedB = al(4096) + al(147456) + al(589824) + al(1179648) +
                             al(11264000) + al(64000) + al(2816) + al(2816) +
                             al(512000) + al(1600);
    int Bc = 256;
    for (int cand = 8192; cand >= 256; cand >>= 1) {
        long long need = fixedB + al(44032LL * cand);
        if (need <= (long long)ws_size) { Bc = cand; break; }
    }
    const int bshift = __builtin_ctz((unsigned)Bc);
    const int C = 8192 / Bc;

    // ---- workspace: fixed region + one overlaid chunk region ----
    char* wsp = (char*)d_ws;
    long long off = 0;
    auto alloc = [&](long long bytes) { long long o = off; off += al(bytes); return o; };
    u16* W1t  = (u16*)(wsp + alloc(4096));
    u16* Wt2  = (u16*)(wsp + alloc(147456));
    u16* Wt3  = (u16*)(wsp + alloc(589824));
    u16* Wt4  = (u16*)(wsp + alloc(1179648));
    u16* Wat  = (u16*)(wsp + alloc(11264000));
    float* bap = (float*)(wsp + alloc(64000));
    float* bnA = (float*)(wsp + alloc(2816));
    float* bnB = (float*)(wsp + alloc(2816));
    u16* Wbp  = (u16*)(wsp + alloc(512000));
    float* bbp = (float*)(wsp + alloc(1600));
    char* ch = wsp + alloc(44032LL * Bc);
    // overlay (bytes-per-elem offsets; lifetimes disjoint where ranges overlap):
    u16* xt   = (u16*)(ch + 0LL     * Bc);   // [0,3200)       t1-t1.5
    u16* xcol = (u16*)(ch + 3200LL  * Bc);   // [3200,28800)   t1.5-t2
    u16* p1   = (u16*)(ch + 28800LL * Bc);   // [28800,41600)  t2-t3
    u16* a2   = (u16*)(ch + 0LL     * Bc);   // [0,25600)      t3-t3.5
    u16* p2   = (u16*)(ch + 25600LL * Bc);   // [25600,32000)  t3.5-t4
    u16* a3   = (u16*)(ch + 0LL     * Bc);   // [0,12800)      t4-t5
    u16* a4   = (u16*)(ch + 12800LL * Bc);   // [12800,25600)  t5-t8
    u16* preds= (u16*)(ch + 25600LL * Bc);   // [25600,26112)  t6-t7
    u16* A2   = (u16*)(ch + 26112LL * Bc);   // [26112,43712)  t7-t8

    // ---- prep (once) ----
    prep_bn_all<<<dim3(3), 256, 0, stream>>>(b1,g1,be1,m1,v1, b2,g2,be2,m2,v2,
                                             b3,g3,be3,m3,v3, b4,g4,be4,m4,v4, bnA, bnB);
    prep_w1col<<<dim3(8), 256, 0, stream>>>(W1, W1t);
    prep_convw<<<dim3(288),  256, 0, stream>>>(W2, Wt2, 128, 64);
    prep_convw<<<dim3(1152), 256, 0, stream>>>(W3, Wt3, 256, 128);
    prep_convw<<<dim3(2304), 256, 0, stream>>>(W4, Wt4, 256, 256);
    prep_wat<<<dim3(22000), 256, 0, stream>>>(Wa, Wat);
    prep_ba<<<dim3(63), 256, 0, stream>>>(ba, bap);
    prep_wbt<<<dim3(1000), 256, 0, stream>>>(Wb, bb, Wbp, bbp);

    // ---- batch chunks ----
    for (int c = 0; c < C; ++c) {
        const float* xc = x + (long long)c * Bc * 1200;

        transpose_x<<<dim3(400 * Bc / 256), 256, 0, stream>>>(xc, xt, Bc, bshift);
        im2col1<<<dim3(400 * Bc / 256), 256, 0, stream>>>(xt, xcol, Bc, bshift);
        conv1pool<<<dim3(Bc / 128, 100), 256, 0, stream>>>(xcol, W1t, p1, bnA, bnB, Bc);

        gemm_bt<0,128><<<dim3(100 * Bc / 128, 1), 256, 0, stream>>>(p1, Wt2, a2, bnA + 64, bnB + 64,
            64, 128, 9, 10, 10, 64, 64, 128, 0LL, 0LL, 0LL, 0, Bc, bshift);
        pool_k<128><<<dim3(Bc * 16 / 256, 25), 256, 0, stream>>>(a2, p2, Bc, 10, 5);

        gemm_bt<0,128><<<dim3(25 * Bc / 128, 2), 256, 0, stream>>>(p2, Wt3, a3, bnA + 192, bnB + 192,
            128, 256, 9, 5, 5, 128, 128, 256, 0LL, 0LL, 0LL, 0, Bc, bshift);
        gemm_bt<0,128><<<dim3(25 * Bc / 128, 2), 256, 0, stream>>>(a3, Wt4, a4, bnA + 448, bnB + 448,
            256, 256, 9, 5, 5, 256, 256, 256, 0LL, 0LL, 0LL, 0, Bc, bshift);

        // stage 1: fused MLP+tanh+logits+softmax (zeros||feats -> Wa k-rows [80:336))
        mlp_head<1><<<dim3(Bc / 128, 1, 25), 256, 0, stream>>>(
            a4, Wat + 80, bap, Wbp, bbp, preds, nullptr, 256, Bc, 0);

        // stage 2
        gather_nb<<<dim3(25 * Bc / 256, 1), 256, 0, stream>>>(preds, a4, A2, Bc, bshift);
        mlp_head<2><<<dim3(Bc / 128, 1, 25), 256, 0, stream>>>(
            A2, Wat, bap, Wbp, bbp, nullptr, dout, 352, Bc, c * Bc);
    }

    mean_k<<<dim3(320), 256, 0, stream>>>(dout);
}

// Round 9
// 1480.846 us; speedup vs baseline: 1.0748x; 1.0748x over previous
//
#include <hip/hip_runtime.h>

typedef unsigned short u16;
typedef unsigned int u32;

typedef __attribute__((ext_vector_type(8))) __bf16 bf16x8;
typedef __attribute__((ext_vector_type(4))) float f32x4;

__device__ __forceinline__ float bf2f(u16 u) {
    u32 t = ((u32)u) << 16;
    float f;
    __builtin_memcpy(&f, &t, 4);
    return f;
}
__device__ __forceinline__ u16 f2bf(float f) {
    u32 u;
    __builtin_memcpy(&u, &f, 4);
    u32 r = (u + 0x7fffu + ((u >> 16) & 1u)) >> 16;
    return (u16)r;
}
__device__ __forceinline__ float tanh_fast(float x) {
    float xc = fminf(fmaxf(x, -15.f), 15.f);
    float e = __expf(2.f * xc);
    return (e - 1.f) * __builtin_amdgcn_rcpf(e + 1.f);
}

// Async global->LDS DMA, 16B per lane. LDS dest = wave-uniform base + lane*16.
__device__ __forceinline__ void gld16(const u16* g, u16* l) {
    __builtin_amdgcn_global_load_lds(
        (const __attribute__((address_space(1))) u32*)(uintptr_t)g,
        (__attribute__((address_space(3))) u32*)(u32)(uintptr_t)l,
        16, 0, 0);
}

// NOTE (round 12 post-mortem): the round-11 XCD "contiguous chunk" swizzle is
// REVERTED. Measured R8: conv FETCH 188->308 MB, dur 127->167 us. For these
// grids the blocks sharing A-panels sit at linearized distances that are
// multiples of 8 (x+-32 tap rows, x+-160, y-pair +-800), so the DEFAULT
// round-robin id%8 assignment already co-locates all sharers on one XCD; the
// remap destroyed that alignment. Check reuse-distance mod 8 before T1.

// LDS bank swizzle (round 5, kept): chunk c (16B) of row r staged into slot
// (c + (r>>1)) & 3; consumer reads chunk qd of row R at (qd + (R>>1)) & 3.
// Verified round 5: SQ_LDS_BANK_CONFLICT 5.5M -> 0.

// ---------------------------------------------------------------------------
// bf16 MFMA GEMM, tile 128 x NT, SINGLE-BARRIER PIPELINED K-LOOP (round 6).
// EXACT R3/R6 form (measured 1398 us total).
// A: [spatial][Bc][ldA] (k-contiguous). W: [T][N][ldW]. T==9 -> 3x3 conv via
// shift-GEMM. EPI 0: relu(acc*epiA[n]+epiB[n]); EPI 1: tanh(acc+epiB[n]).
// ---------------------------------------------------------------------------
template <int EPI, int NT>
__global__ __launch_bounds__(256, 3) void gemm_bt(
    const u16* __restrict__ A, const u16* __restrict__ W, u16* __restrict__ O,
    const float* __restrict__ epiA, const float* __restrict__ epiB,
    int Kin, int N, int T, int Himg, int Wimg,
    int ldA, int ldW, int ldO,
    long long Az, long long Wz, long long Oz, int epiZ,
    int Bc, int bshift)
{
    constexpr int NJ = NT / 32;          // 4 (NT=128) or 2 (NT=64)
    __shared__ __align__(16) u16 lsA[2][128 * 32];
    __shared__ __align__(16) u16 lsW[2][NT * 32];

    const int tid = threadIdx.x;
    const int z = blockIdx.z;
    A += (long long)z * Az;
    W += (long long)z * Wz;
    O += (long long)z * Oz;
    epiB += (long long)z * epiZ;

    const int m0 = blockIdx.x * 128;
    const int n0 = blockIdx.y * NT;
    const int s = m0 >> bshift;          // spatial index (0 for MLP)
    const int b0 = m0 & (Bc - 1);        // batch offset
    const int hh0 = s / Wimg, ww0 = s % Wimg;

    const int wave = tid >> 6;
    const int lane = tid & 63;
    const int mbase = (wave >> 1) * 64;
    const int nbase = (wave & 1) * (NT / 2);
    const int ln = lane & 15, qd = lane >> 4;

    const int srow = lane >> 2;                                // staging row in 16-slab
    const int sc = (((lane & 3) - ((srow >> 1) & 3)) & 3) * 8; // swizzled fetch chunk
    const int csel = ((qd + (ln >> 1)) & 3) * 8;               // swizzled read chunk

    // lane-constant staging offsets (elems)
    const int rowA = wave * 32 + srow;
    const int rowW = (NT == 128) ? (wave * 32 + srow) : (wave * 16 + srow);
    const int offA0 = rowA * ldA + sc;
    const int offA1 = offA0 + 16 * ldA;
    const int offW0 = rowW * ldW + sc;
    const int offW1 = offW0 + 16 * ldW;   // NT==128 only
    u16* const lA0 = &lsA[0][0] + wave * 1024;
    u16* const lW0 = (NT == 128) ? (&lsW[0][0] + wave * 1024) : (&lsW[0][0] + wave * 512);
    constexpr int LPAR_A = 128 * 32;      // parity stride (elems)
    constexpr int LPAR_W = NT * 32;

    // tap helpers (all wave-uniform)
    auto tapvalid = [&](int t) -> bool {
        if (T != 9) return true;
        const int hh = hh0 + t / 3 - 1, ww = ww0 + t % 3 - 1;
        return hh >= 0 && hh < Himg && ww >= 0 && ww < Wimg;
    };
    auto tapA = [&](int t) -> const u16* {
        int sp = s;
        if (T == 9) sp = (hh0 + t / 3 - 1) * Wimg + (ww0 + t % 3 - 1);
        return A + (long long)(sp * Bc + b0) * ldA;
    };

    int t0 = 0;
    while (!tapvalid(t0)) ++t0;
    int nvalid = 0;
    for (int t = 0; t < T; ++t) nvalid += tapvalid(t) ? 1 : 0;
    const int KS = Kin >> 5;
    const int S = nvalid * KS;

    const u16* Ab = tapA(t0);
    const u16* Wb = W + ((long long)t0 * N + n0) * ldW;

    // prologue: prefetch step 0 into parity 0
    gld16(Ab + offA0, lA0);
    gld16(Ab + offA1, lA0 + 512);
    gld16(Wb + offW0, lW0);
    if (NT == 128) gld16(Wb + offW1, lW0 + 512);

    int ntap = t0, nkk = 0;

    f32x4 acc[4][NJ];
#pragma unroll
    for (int i = 0; i < 4; ++i)
#pragma unroll
        for (int j = 0; j < NJ; ++j)
            acc[i][j] = (f32x4){0.f, 0.f, 0.f, 0.f};

    for (int st = 0; st < S; ++st) {
        __syncthreads();   // drains prefetch issued at st-1 (had full MFMA phase in flight)
        if (st + 1 < S) {
            nkk += 32;
            if (nkk == Kin) {
                nkk = 0;
                do { ++ntap; } while (!tapvalid(ntap));
                Ab = tapA(ntap);
                Wb = W + ((long long)ntap * N + n0) * ldW;
            }
            const int pp = (st + 1) & 1;
            gld16(Ab + offA0 + nkk, lA0 + pp * LPAR_A);
            gld16(Ab + offA1 + nkk, lA0 + pp * LPAR_A + 512);
            gld16(Wb + offW0 + nkk, lW0 + pp * LPAR_W);
            if (NT == 128) gld16(Wb + offW1 + nkk, lW0 + pp * LPAR_W + 512);
        }
        const int cp = st & 1;
        bf16x8 af[4], bfr[NJ];
#pragma unroll
        for (int f = 0; f < 4; ++f)
            af[f] = *(const bf16x8*)&lsA[cp][(mbase + f * 16 + ln) * 32 + csel];
#pragma unroll
        for (int f = 0; f < NJ; ++f)
            bfr[f] = *(const bf16x8*)&lsW[cp][(nbase + f * 16 + ln) * 32 + csel];
#pragma unroll
        for (int i = 0; i < 4; ++i)
#pragma unroll
            for (int j = 0; j < NJ; ++j)
                acc[i][j] = __builtin_amdgcn_mfma_f32_16x16x32_bf16(
                    af[i], bfr[j], acc[i][j], 0, 0, 0);
    }

#pragma unroll
    for (int j = 0; j < NJ; ++j) {
        const int n = n0 + nbase + j * 16 + ln;
        const float sh = epiB[n];
        float sc2 = 1.f;
        if (EPI == 0) sc2 = epiA[n];
#pragma unroll
        for (int i = 0; i < 4; ++i) {
            const int mrow = mbase + i * 16 + qd * 4;
#pragma unroll
            for (int rr = 0; rr < 4; ++rr) {
                float v = acc[i][j][rr];
                if (EPI == 0) v = fmaxf(v * sc2 + sh, 0.f);
                else          v = tanh_fast(v + sh);
                O[(long long)(m0 + mrow + rr) * ldO + n] = f2bf(v);
            }
        }
    }
}

// ---------------------------------------------------------------------------
// FUSED MLP (Linear->tanh, 5 n-tiles) + logits (600->10 via 640->16) +
// softmax. Round 12: NO XCD swizzle (reverted); KEEPS the round-11 lsH
// chunking — lsH is one 64-col chunk (128x68), logits GEMM in two chunk
// passes -> LDS 66.3 KB -> 49 KB -> 3 blocks/CU (cross-block overlap hides
// the barrier-drain latency; m114). Chunk cc written only by waves with
// nbase==cc*64; all waves then MFMA that chunk's 64 k-cols into acc_lg.
// Same fragments, same MFMA accumulation order -> values bit-identical.
// ---------------------------------------------------------------------------
template <int STAGE>
__global__ __launch_bounds__(256, 3) void mlp_head(
    const u16* __restrict__ A, const u16* __restrict__ W,
    const float* __restrict__ bap, const u16* __restrict__ Wbp,
    const float* __restrict__ bbp,
    u16* __restrict__ preds, float* __restrict__ dout,
    int Kin, int Bc, int gbase)
{
    __shared__ __align__(16) u16 lsA[2][128 * 32];
    __shared__ __align__(16) u16 lsW[2][128 * 32];
    __shared__ __align__(16) u16 lsH[128 * 68];   // one 64-col chunk (+4 pad)

    const int tid = threadIdx.x;
    const int z = blockIdx.z;                 // node 0..24
    const int m0 = blockIdx.x * 128;          // batch row base

    A += (long long)z * Bc * Kin;
    W += (long long)z * 640 * 352;
    const float* bz = bap + z * 640;

    const int wave = tid >> 6;
    const int lane = tid & 63;
    const int mbase = (wave >> 1) * 64;
    const int nbase = (wave & 1) * 64;
    const int wsel = wave & 1;                // chunk ownership
    const int ln = lane & 15, qd = lane >> 4;
    const int srow = lane >> 2;
    const int sc = (((lane & 3) - ((srow >> 1) & 3)) & 3) * 8;
    const int csel = ((qd + (ln >> 1)) & 3) * 8;

    const int rowS = wave * 32 + srow;
    const int offA0 = rowS * Kin + sc;        // ldA = Kin
    const int offA1 = offA0 + 16 * Kin;
    const int offW0 = rowS * 352 + sc;        // ldW = 352
    const int offW1 = offW0 + 16 * 352;
    u16* const lA0 = &lsA[0][0] + wave * 1024;
    u16* const lW0 = &lsW[0][0] + wave * 1024;

    const int KS = Kin >> 5;                  // 8 (stage1) or 11 (stage2)
    const int Stot = 5 * KS;

    const u16* Ab = A + (long long)m0 * Kin;
    const u16* Wb = W;
    int pnt = 0, pnkk = 0;

    // prologue: prefetch flat step 0 into parity 0
    gld16(Ab + offA0, lA0);
    gld16(Ab + offA1, lA0 + 512);
    gld16(Wb + offW0, lW0);
    gld16(Wb + offW1, lW0 + 512);

    f32x4 acc[4][4];
#pragma unroll
    for (int i = 0; i < 4; ++i)
#pragma unroll
        for (int j = 0; j < 4; ++j)
            acc[i][j] = (f32x4){0.f, 0.f, 0.f, 0.f};
    f32x4 acc_lg[2];
    acc_lg[0] = (f32x4){0.f, 0.f, 0.f, 0.f};
    acc_lg[1] = (f32x4){0.f, 0.f, 0.f, 0.f};

    int g = 0;   // flat step index
    for (int nt = 0; nt < 5; ++nt) {
        for (int st = 0; st < KS; ++st, ++g) {
            __syncthreads();   // drains prefetch issued at g-1
            if (g + 1 < Stot) {
                pnkk += 32;
                if (pnkk == Kin) {   // next n-tile: K wraps, W column base advances
                    pnkk = 0;
                    ++pnt;
                    Wb = W + (long long)pnt * 128 * 352;
                }
                const int pp = (g + 1) & 1;
                gld16(Ab + offA0 + pnkk, lA0 + pp * (128 * 32));
                gld16(Ab + offA1 + pnkk, lA0 + pp * (128 * 32) + 512);
                gld16(Wb + offW0 + pnkk, lW0 + pp * (128 * 32));
                gld16(Wb + offW1 + pnkk, lW0 + pp * (128 * 32) + 512);
            }
            const int cp = g & 1;
            bf16x8 af[4], bfr[4];
#pragma unroll
            for (int f = 0; f < 4; ++f)
                af[f] = *(const bf16x8*)&lsA[cp][(mbase + f * 16 + ln) * 32 + csel];
#pragma unroll
            for (int f = 0; f < 4; ++f)
                bfr[f] = *(const bf16x8*)&lsW[cp][(nbase + f * 16 + ln) * 32 + csel];
#pragma unroll
            for (int i = 0; i < 4; ++i)
#pragma unroll
                for (int j = 0; j < 4; ++j)
                    acc[i][j] = __builtin_amdgcn_mfma_f32_16x16x32_bf16(
                        af[i], bfr[j], acc[i][j], 0, 0, 0);
        }

        // ---- tile epilogue in two 64-col chunks ----
        // cc=0 needs no pre-write barrier: the K-loop's barriers already
        // ordered the previous tile's chunk-1 readers before these writes.
#pragma unroll
        for (int cc = 0; cc < 2; ++cc) {
            if (cc) __syncthreads();          // chunk-0 lsH reads done
            if (wsel == cc) {
#pragma unroll
                for (int j = 0; j < 4; ++j) {
                    const int hcl = j * 16 + ln;          // chunk-local col 0..63
                    const float sh = bz[nt * 128 + cc * 64 + hcl];
#pragma unroll
                    for (int i = 0; i < 4; ++i) {
                        const int br = mbase + i * 16 + qd * 4;
#pragma unroll
                        for (int rr = 0; rr < 4; ++rr)
                            lsH[(br + rr) * 68 + hcl] =
                                f2bf(tanh_fast(acc[i][j][rr] + sh));
                    }
                }
            }
            // hoist logits B-frags for this chunk (global, L2-hot)
            bf16x8 bfrg[2];
#pragma unroll
            for (int ks = 0; ks < 2; ++ks)
                bfrg[ks] = *(const bf16x8*)&Wbp[((long long)z * 16 + ln) * 640 +
                                                nt * 128 + cc * 64 + ks * 32 + qd * 8];
            __syncthreads();                  // h chunk visible

            // logits partial GEMM over this chunk's 64 h-cols
#pragma unroll
            for (int ks = 0; ks < 2; ++ks) {
#pragma unroll
                for (int i = 0; i < 2; ++i) {
                    const int base = (wave * 32 + i * 16 + ln) * 68 + ks * 32 + qd * 8;
                    const uint2 u0 = *(const uint2*)&lsH[base];
                    const uint2 u1 = *(const uint2*)&lsH[base + 4];
                    u32 w4[4] = {u0.x, u0.y, u1.x, u1.y};
                    bf16x8 a8;
                    __builtin_memcpy(&a8, w4, 16);
                    acc_lg[i] = __builtin_amdgcn_mfma_f32_16x16x32_bf16(
                        a8, bfrg[ks], acc_lg[i], 0, 0, 0);
                }
            }
        }
#pragma unroll
        for (int i = 0; i < 4; ++i)
#pragma unroll
            for (int j = 0; j < 4; ++j)
                acc[i][j] = (f32x4){0.f, 0.f, 0.f, 0.f};
        // next tile's first K-step barrier orders lsH reuse
    }

    // softmax over the 16-lane group (pad cols have bbp=-1e30 -> excluded)
    const float bias = bbp[z * 16 + ln];
#pragma unroll
    for (int i = 0; i < 2; ++i) {
#pragma unroll
        for (int rr = 0; rr < 4; ++rr) {
            const float v = acc_lg[i][rr] + bias;
            float mx = v;
#pragma unroll
            for (int mk = 1; mk < 16; mk <<= 1)
                mx = fmaxf(mx, __shfl_xor(mx, mk));
            const float e = __expf(v - mx);
            float ssum = e;
#pragma unroll
            for (int mk = 1; mk < 16; mk <<= 1)
                ssum += __shfl_xor(ssum, mk);
            const float p = e / ssum;
            const int row = m0 + wave * 32 + i * 16 + qd * 4 + rr;
            if (ln < 10) {
                if (STAGE == 1)
                    preds[((long long)z * Bc + row) * 10 + ln] = f2bf(p);
                else
                    dout[81920 + ((long long)z * 8192 + gbase + row) * 10 + ln] = p;
            }
        }
    }
}

// ---------------------------------------------------------------------------
// FUSED conv1 + BN + ReLU + maxpool3s2p1, v2 (round 8): NO LDS, NO BARRIERS.
// (XCD swizzle reverted.)
// ---------------------------------------------------------------------------
__global__ __launch_bounds__(256) void conv1pool(
    const u16* __restrict__ xcol, const u16* __restrict__ W1t, u16* __restrict__ p1,
    const float* __restrict__ epiA, const float* __restrict__ epiB, int Bc)
{
    const int tid = threadIdx.x;
    const int wave = tid >> 6;
    const int lane = tid & 63;
    const int ln = lane & 15, qd = lane >> 4;

    const int b0 = blockIdx.x * 128;
    const int so = blockIdx.y;            // pooled spatial index 0..99
    const int ho = so / 10, wo = so % 10;

    const int mbase = (wave >> 1) * 64;
    const int nbase = (wave & 1) * 32;

    bf16x8 bfr[2];
#pragma unroll
    for (int j = 0; j < 2; ++j)
        bfr[j] = *(const bf16x8*)&W1t[(nbase + j * 16 + ln) * 32 + qd * 8];

    float sc2[2], sh[2];
#pragma unroll
    for (int j = 0; j < 2; ++j) {
        const int n = nbase + j * 16 + ln;
        sc2[j] = epiA[n];
        sh[j] = epiB[n];
    }

    f32x4 best[4][2];
#pragma unroll
    for (int i = 0; i < 4; ++i)
#pragma unroll
        for (int j = 0; j < 2; ++j)
            best[i][j] = (f32x4){0.f, 0.f, 0.f, 0.f};

#pragma unroll
    for (int st = 0; st < 9; ++st) {
        int hh = 2 * ho - 1 + st / 3;
        int ww = 2 * wo - 1 + st % 3;
        hh = hh < 0 ? 0 : (hh > 19 ? 19 : hh);
        ww = ww < 0 ? 0 : (ww > 19 ? 19 : ww);
        const u16* Ab = xcol + (long long)((hh * 20 + ww) * Bc + b0) * 32;

        bf16x8 af[4];
#pragma unroll
        for (int f = 0; f < 4; ++f)
            af[f] = *(const bf16x8*)&Ab[(mbase + f * 16 + ln) * 32 + qd * 8];

#pragma unroll
        for (int i = 0; i < 4; ++i)
#pragma unroll
            for (int j = 0; j < 2; ++j) {
                f32x4 acc = (f32x4){0.f, 0.f, 0.f, 0.f};
                acc = __builtin_amdgcn_mfma_f32_16x16x32_bf16(af[i], bfr[j], acc, 0, 0, 0);
#pragma unroll
                for (int rr = 0; rr < 4; ++rr) {
                    const float v = fmaxf(acc[rr] * sc2[j] + sh[j], 0.f);
                    best[i][j][rr] = fmaxf(best[i][j][rr], v);
                }
            }
    }

#pragma unroll
    for (int j = 0; j < 2; ++j) {
        const int n = nbase + j * 16 + ln;
#pragma unroll
        for (int i = 0; i < 4; ++i) {
            const int mrow = mbase + i * 16 + qd * 4;
#pragma unroll
            for (int rr = 0; rr < 4; ++rr)
                p1[(long long)(so * Bc + b0 + mrow + rr) * 64 + n] = f2bf(best[i][j][rr]);
        }
    }
}

// ---------------------------------------------------------------------------
// x chunk [Bc,3,20,20] fp32 -> xt [400][Bc][4] bf16 (ch padded to 4, pad=0)
// ---------------------------------------------------------------------------
__global__ __launch_bounds__(256) void transpose_x(
    const float* __restrict__ x, u16* __restrict__ xt, int Bc, int bshift)
{
    const int t = blockIdx.x * 256 + threadIdx.x;
    if (t >= 400 * Bc) return;
    const int s = t >> bshift;
    const int b = t & (Bc - 1);
    const u32 c0 = f2bf(x[((long long)b * 3 + 0) * 400 + s]);
    const u32 c1 = f2bf(x[((long long)b * 3 + 1) * 400 + s]);
    const u32 c2 = f2bf(x[((long long)b * 3 + 2) * 400 + s]);
    uint2 st;
    st.x = c0 | (c1 << 16);
    st.y = c2;                              // high 16 = 0 pad
    *(uint2*)(xt + ((long long)s * Bc + b) * 4) = st;
}

// ---------------------------------------------------------------------------
// im2col for conv1: xt[400][Bc][4] -> xcol[400][Bc][32] (k = tap*3+ci, pad 0).
// ---------------------------------------------------------------------------
__global__ __launch_bounds__(256) void im2col1(
    const u16* __restrict__ xt, u16* __restrict__ xcol, int Bc, int bshift)
{
    const int t = blockIdx.x * 256 + threadIdx.x;
    if (t >= 400 * Bc) return;
    const int s = t >> bshift;
    const int b = t & (Bc - 1);
    const int hh = s / 20, ww = s % 20;

    u32 p0, q0, p1, q1, p2, q2, p3, q3, p4, q4, p5, q5, p6, q6, p7, q7, p8, q8;
#define LOADTAP(T, P, Q)                                                      \
    {                                                                         \
        const int ih = hh + (T) / 3 - 1, iw = ww + (T) % 3 - 1;               \
        P = 0u; Q = 0u;                                                       \
        if (ih >= 0 && ih < 20 && iw >= 0 && iw < 20) {                       \
            const uint2 v = *(const uint2*)(xt +                              \
                ((long long)(ih * 20 + iw) * Bc + b) * 4);                    \
            P = v.x; Q = v.y;                                                 \
        }                                                                     \
    }
    LOADTAP(0, p0, q0) LOADTAP(1, p1, q1) LOADTAP(2, p2, q2)
    LOADTAP(3, p3, q3) LOADTAP(4, p4, q4) LOADTAP(5, p5, q5)
    LOADTAP(6, p6, q6) LOADTAP(7, p7, q7) LOADTAP(8, p8, q8)
#undef LOADTAP

    u16* o = xcol + (long long)t * 32;
    uint4 w;
    w.x = p0;                w.y = q0 | (p1 << 16);
    w.z = (p1 >> 16) | (q1 << 16);
    w.w = p2;
    *(uint4*)(o + 0) = w;
    w.x = q2 | (p3 << 16);   w.y = (p3 >> 16) | (q3 << 16);
    w.z = p4;                w.w = q4 | (p5 << 16);
    *(uint4*)(o + 8) = w;
    w.x = (p5 >> 16) | (q5 << 16);
    w.y = p6;                w.z = q6 | (p7 << 16);
    w.w = (p7 >> 16) | (q7 << 16);
    *(uint4*)(o + 16) = w;
    w.x = p8;                w.y = q8;   // k=24..26 (+pad)
    w.z = 0u;                w.w = 0u;
    *(uint4*)(o + 24) = w;
}

// ---------------------------------------------------------------------------
// maxpool 3x3 s2 p1, square maps: src[Hi*Hi][Bc][CH] -> dst[Ho*Ho][Bc][CH].
// ---------------------------------------------------------------------------
template <int CH>
__global__ __launch_bounds__(256) void pool_k(
    const u16* __restrict__ src, u16* __restrict__ dst, int Bc, int Hi, int Ho)
{
    constexpr int G = CH / 8;
    const int t = blockIdx.x * 256 + threadIdx.x;
    const int cc = t & (G - 1);
    const int b = t / G;
    if (b >= Bc) return;
    const int so = blockIdx.y;
    const int ho = so / Ho, wo = so % Ho;
    float best[8];
#pragma unroll
    for (int e = 0; e < 8; ++e) best[e] = 0.f;
    for (int ph = 0; ph < 3; ++ph) {
        const int hh = 2 * ho - 1 + ph;
        if (hh < 0 || hh >= Hi) continue;
        for (int pw = 0; pw < 3; ++pw) {
            const int ww = 2 * wo - 1 + pw;
            if (ww < 0 || ww >= Hi) continue;
            const uint4 u = *(const uint4*)(src + ((long long)(hh * Hi + ww) * Bc + b) * CH + cc * 8);
            const u32 uw[4] = {u.x, u.y, u.z, u.w};
#pragma unroll
            for (int e = 0; e < 4; ++e) {
                best[2 * e]     = fmaxf(best[2 * e],     bf2f((u16)(uw[e] & 0xffff)));
                best[2 * e + 1] = fmaxf(best[2 * e + 1], bf2f((u16)(uw[e] >> 16)));
            }
        }
    }
    u32 pk[4];
#pragma unroll
    for (int e = 0; e < 4; ++e)
        pk[e] = (u32)f2bf(best[2 * e]) | (((u32)f2bf(best[2 * e + 1])) << 16);
    uint4 st;
    st.x = pk[0]; st.y = pk[1]; st.z = pk[2]; st.w = pk[3];
    *(uint4*)(dst + ((long long)so * Bc + b) * CH + cc * 8) = st;
}

// ---------------------------------------------------------------------------
// Stage-2 input assembly.
// ---------------------------------------------------------------------------
__device__ __forceinline__ void neighbors5x5(int i, int* nb) {
    const int w = 5, size = 25;
    int cnt = 0;
    if (i - w >= 0) nb[cnt++] = i - w;
    if (i % w != 0) nb[cnt++] = i - 1;
    if ((i + 1) % w != 0) nb[cnt++] = i + 1;
    if (i + w < size) nb[cnt++] = i + w;
    if (i - w - 1 >= 0 && i % w != 0) nb[cnt++] = i - w - 1;
    if (i - w + 1 >= 0 && (i + 1) % w != 0) nb[cnt++] = i - w + 1;
    if (i + w - 1 < size && i % w != 0) nb[cnt++] = i + w - 1;
    if (i + w + 1 < size && (i + 1) % w != 0) nb[cnt++] = i + w + 1;
    for (; cnt < 8; ++cnt) nb[cnt] = -1;
}

__global__ __launch_bounds__(256) void gather_nb(
    const u16* __restrict__ preds, const u16* __restrict__ feats, u16* __restrict__ A2,
    int Bc, int bshift)
{
    const int g = blockIdx.x * 256 + threadIdx.x;  // n*Bc+b
    if (g >= 25 * Bc) return;
    const int n = g >> bshift;
    const int b = g & (Bc - 1);
    int nb[8];
    neighbors5x5(n, nb);
    u16* dst = A2 + (long long)g * 352;
#pragma unroll
    for (int j = 0; j < 8; ++j) {
        u32* d32 = (u32*)(dst + j * 10);
        if (nb[j] >= 0) {
            const u32* s32 = (const u32*)(preds + ((long long)nb[j] * Bc + b) * 10);
#pragma unroll
            for (int q = 0; q < 5; ++q) d32[q] = s32[q];
        } else {
#pragma unroll
            for (int q = 0; q < 5; ++q) d32[q] = 0u;
        }
    }
    const uint4* fs = (const uint4*)(feats + (long long)g * 256);
    uint4* fd = (uint4*)(dst + 80);
#pragma unroll
    for (int q = 0; q < 32; ++q) fd[q] = fs[q];
    uint4 z;
    z.x = 0u; z.y = 0u; z.z = 0u; z.w = 0u;
    *(uint4*)(dst + 336) = z;
    *(uint4*)(dst + 344) = z;
}

__global__ __launch_bounds__(256) void mean_k(float* __restrict__ dout)
{
    const int t = blockIdx.x * 256 + threadIdx.x;
    float s = 0.f;
#pragma unroll
    for (int n = 0; n < 25; ++n) s += dout[81920 + n * 81920 + t];
    dout[t] = s * 0.04f;
}

// ---------------------------------------------------------------------------
// Weight/param prep (once per launch)
// ---------------------------------------------------------------------------
__global__ void prep_bn_all(
    const float* b1, const float* g1, const float* be1, const float* m1, const float* v1,
    const float* b2, const float* g2, const float* be2, const float* m2, const float* v2,
    const float* b3, const float* g3, const float* be3, const float* m3, const float* v3,
    const float* b4, const float* g4, const float* be4, const float* m4, const float* v4,
    float* bnA, float* bnB)
{
    const int t = blockIdx.x * 256 + threadIdx.x;
    if (t >= 704) return;
    const float *bp, *gp, *bep, *mp, *vp;
    int idx;
    if (t < 64)       { bp=b1; gp=g1; bep=be1; mp=m1; vp=v1; idx=t; }
    else if (t < 192) { bp=b2; gp=g2; bep=be2; mp=m2; vp=v2; idx=t-64; }
    else if (t < 448) { bp=b3; gp=g3; bep=be3; mp=m3; vp=v3; idx=t-192; }
    else              { bp=b4; gp=g4; bep=be4; mp=m4; vp=v4; idx=t-448; }
    const float A = gp[idx] * rsqrtf(vp[idx] + 1e-5f);
    bnA[t] = A;
    bnB[t] = (bp[idx] - mp[idx]) * A + bep[idx];
}

// W1 [64][3][3][3] -> W1t [64][32], k = tap*3+ci (tap = kh*3+kw), pad 0
__global__ void prep_w1col(const float* __restrict__ W1, u16* __restrict__ W1t)
{
    const int t = blockIdx.x * 256 + threadIdx.x;
    if (t >= 64 * 32) return;
    const int n = t >> 5, k = t & 31;
    u16 v = 0;
    if (k < 27) {
        const int tap = k / 3, ci = k % 3;
        v = f2bf(W1[n * 27 + ci * 9 + tap]);
    }
    W1t[t] = v;
}

// W [Co][Ci][3][3] fp32 -> Wt [9][Co][Ci] bf16
__global__ void prep_convw(const float* __restrict__ W, u16* __restrict__ Wt, int Co, int Ci)
{
    const int t = blockIdx.x * 256 + threadIdx.x;
    const int tot = 9 * Co * Ci;
    if (t >= tot) return;
    const int sh = t / (Co * Ci);
    const int rem = t % (Co * Ci);
    const int co = rem / Ci, ci = rem % Ci;
    Wt[t] = f2bf(W[(long long)(co * Ci + ci) * 9 + sh]);
}

__global__ void prep_wat(const float* __restrict__ Wa, u16* __restrict__ Wat)
{
    const int t = blockIdx.x * 256 + threadIdx.x;
    if (t >= 25 * 640 * 352) return;
    const int n = t / (640 * 352);
    const int rem = t % (640 * 352);
    const int hcol = rem / 352;
    const int k = rem % 352;
    float v = 0.f;
    if (hcol < 600 && k < 336) v = Wa[((long long)n * 336 + k) * 600 + hcol];
    Wat[t] = f2bf(v);
}

__global__ void prep_ba(const float* __restrict__ ba, float* __restrict__ bap)
{
    const int t = blockIdx.x * 256 + threadIdx.x;
    if (t >= 25 * 640) return;
    const int n = t / 640, hcol = t % 640;
    bap[t] = (hcol < 600) ? ba[n * 600 + hcol] : 0.f;
}

// Wb [25][600][10] fp32 -> Wbp [25][16][640] bf16 (transposed, zero-pad);
// bb [25][10] -> bbp [25][16] fp32 (pad -1e30 so softmax ignores pad cols)
__global__ void prep_wbt(const float* __restrict__ Wb, const float* __restrict__ bb,
                         u16* __restrict__ Wbp, float* __restrict__ bbp)
{
    const int t = blockIdx.x * 256 + threadIdx.x;
    if (t < 25 * 16 * 640) {
        const int n = t / (16 * 640);
        const int rem = t % (16 * 640);
        const int c = rem / 640, k = rem % 640;
        u16 v = 0;
        if (c < 10 && k < 600) v = f2bf(Wb[((long long)n * 600 + k) * 10 + c]);
        Wbp[t] = v;
    }
    if (t < 25 * 16) {
        const int n = t >> 4, c = t & 15;
        bbp[t] = (c < 10) ? bb[n * 10 + c] : -1e30f;
    }
}

// ---------------------------------------------------------------------------
extern "C" void kernel_launch(void* const* d_in, const int* in_sizes, int n_in,
                              void* d_out, int out_size, void* d_ws, size_t ws_size,
                              hipStream_t stream)
{
    (void)in_sizes; (void)n_in; (void)out_size;

    const float* x  = (const float*)d_in[0];
    const float* W1 = (const float*)d_in[1];
    const float* b1 = (const float*)d_in[2];
    const float* g1 = (const float*)d_in[3];
    const float* be1= (const float*)d_in[4];
    const float* m1 = (const float*)d_in[5];
    const float* v1 = (const float*)d_in[6];
    const float* W2 = (const float*)d_in[7];
    const float* b2 = (const float*)d_in[8];
    const float* g2 = (const float*)d_in[9];
    const float* be2= (const float*)d_in[10];
    const float* m2 = (const float*)d_in[11];
    const float* v2 = (const float*)d_in[12];
    const float* W3 = (const float*)d_in[13];
    const float* b3 = (const float*)d_in[14];
    const float* g3 = (const float*)d_in[15];
    const float* be3= (const float*)d_in[16];
    const float* m3 = (const float*)d_in[17];
    const float* v3 = (const float*)d_in[18];
    const float* W4 = (const float*)d_in[19];
    const float* b4 = (const float*)d_in[20];
    const float* g4 = (const float*)d_in[21];
    const float* be4= (const float*)d_in[22];
    const float* m4 = (const float*)d_in[23];
    const float* v4 = (const float*)d_in[24];
    const float* Wa = (const float*)d_in[25];
    const float* ba = (const float*)d_in[26];
    const float* Wb = (const float*)d_in[27];
    const float* bb = (const float*)d_in[28];
    float* dout = (float*)d_out;

    // ---- choose Bc: overlay peak = 44032 bytes per batch element ----
    auto al = [](long long v) { return (v + 255LL) & ~255LL; };
    const long long fixedB = al(4096) + al(147456) + al(589824) + al(1179648) +
                             al(11264000) + al(64000) + al(2816) + al(2816) +
                             al(512000) + al(1600);
    int Bc = 256;
    for (int cand = 8192; cand >= 256; cand >>= 1) {
        long long need = fixedB + al(44032LL * cand);
        if (need <= (long long)ws_size) { Bc = cand; break; }
    }
    const int bshift = __builtin_ctz((unsigned)Bc);
    const int C = 8192 / Bc;

    // ---- workspace: fixed region + one overlaid chunk region ----
    char* wsp = (char*)d_ws;
    long long off = 0;
    auto alloc = [&](long long bytes) { long long o = off; off += al(bytes); return o; };
    u16* W1t  = (u16*)(wsp + alloc(4096));
    u16* Wt2  = (u16*)(wsp + alloc(147456));
    u16* Wt3  = (u16*)(wsp + alloc(589824));
    u16* Wt4  = (u16*)(wsp + alloc(1179648));
    u16* Wat  = (u16*)(wsp + alloc(11264000));
    float* bap = (float*)(wsp + alloc(64000));
    float* bnA = (float*)(wsp + alloc(2816));
    float* bnB = (float*)(wsp + alloc(2816));
    u16* Wbp  = (u16*)(wsp + alloc(512000));
    float* bbp = (float*)(wsp + alloc(1600));
    char* ch = wsp + alloc(44032LL * Bc);
    // overlay (bytes-per-elem offsets; lifetimes disjoint where ranges overlap):
    u16* xt   = (u16*)(ch + 0LL     * Bc);   // [0,3200)       t1-t1.5
    u16* xcol = (u16*)(ch + 3200LL  * Bc);   // [3200,28800)   t1.5-t2
    u16* p1   = (u16*)(ch + 28800LL * Bc);   // [28800,41600)  t2-t3
    u16* a2   = (u16*)(ch + 0LL     * Bc);   // [0,25600)      t3-t3.5
    u16* p2   = (u16*)(ch + 25600LL * Bc);   // [25600,32000)  t3.5-t4
    u16* a3   = (u16*)(ch + 0LL     * Bc);   // [0,12800)      t4-t5
    u16* a4   = (u16*)(ch + 12800LL * Bc);   // [12800,25600)  t5-t8
    u16* preds= (u16*)(ch + 25600LL * Bc);   // [25600,26112)  t6-t7
    u16* A2   = (u16*)(ch + 26112LL * Bc);   // [26112,43712)  t7-t8

    // ---- prep (once) ----
    prep_bn_all<<<dim3(3), 256, 0, stream>>>(b1,g1,be1,m1,v1, b2,g2,be2,m2,v2,
                                             b3,g3,be3,m3,v3, b4,g4,be4,m4,v4, bnA, bnB);
    prep_w1col<<<dim3(8), 256, 0, stream>>>(W1, W1t);
    prep_convw<<<dim3(288),  256, 0, stream>>>(W2, Wt2, 128, 64);
    prep_convw<<<dim3(1152), 256, 0, stream>>>(W3, Wt3, 256, 128);
    prep_convw<<<dim3(2304), 256, 0, stream>>>(W4, Wt4, 256, 256);
    prep_wat<<<dim3(22000), 256, 0, stream>>>(Wa, Wat);
    prep_ba<<<dim3(63), 256, 0, stream>>>(ba, bap);
    prep_wbt<<<dim3(1000), 256, 0, stream>>>(Wb, bb, Wbp, bbp);

    // ---- batch chunks ----
    for (int c = 0; c < C; ++c) {
        const float* xc = x + (long long)c * Bc * 1200;

        transpose_x<<<dim3(400 * Bc / 256), 256, 0, stream>>>(xc, xt, Bc, bshift);
        im2col1<<<dim3(400 * Bc / 256), 256, 0, stream>>>(xt, xcol, Bc, bshift);
        conv1pool<<<dim3(Bc / 128, 100), 256, 0, stream>>>(xcol, W1t, p1, bnA, bnB, Bc);

        gemm_bt<0,128><<<dim3(100 * Bc / 128, 1), 256, 0, stream>>>(p1, Wt2, a2, bnA + 64, bnB + 64,
            64, 128, 9, 10, 10, 64, 64, 128, 0LL, 0LL, 0LL, 0, Bc, bshift);
        pool_k<128><<<dim3(Bc * 16 / 256, 25), 256, 0, stream>>>(a2, p2, Bc, 10, 5);

        gemm_bt<0,128><<<dim3(25 * Bc / 128, 2), 256, 0, stream>>>(p2, Wt3, a3, bnA + 192, bnB + 192,
            128, 256, 9, 5, 5, 128, 128, 256, 0LL, 0LL, 0LL, 0, Bc, bshift);
        gemm_bt<0,128><<<dim3(25 * Bc / 128, 2), 256, 0, stream>>>(a3, Wt4, a4, bnA + 448, bnB + 448,
            256, 256, 9, 5, 5, 256, 256, 256, 0LL, 0LL, 0LL, 0, Bc, bshift);

        // stage 1: fused MLP+tanh+logits+softmax (zeros||feats -> Wa k-rows [80:336))
        mlp_head<1><<<dim3(Bc / 128, 1, 25), 256, 0, stream>>>(
            a4, Wat + 80, bap, Wbp, bbp, preds, nullptr, 256, Bc, 0);

        // stage 2
        gather_nb<<<dim3(25 * Bc / 256, 1), 256, 0, stream>>>(preds, a4, A2, Bc, bshift);
        mlp_head<2><<<dim3(Bc / 128, 1, 25), 256, 0, stream>>>(
            A2, Wat, bap, Wbp, bbp, nullptr, dout, 352, Bc, c * Bc);
    }

    mean_k<<<dim3(320), 256, 0, stream>>>(dout);
}

// Round 11
// 1435.449 us; speedup vs baseline: 1.1088x; 1.0316x over previous
//
#include <hip/hip_runtime.h>

typedef unsigned short u16;
typedef unsigned int u32;

typedef __attribute__((ext_vector_type(8))) __bf16 bf16x8;
typedef __attribute__((ext_vector_type(4))) float f32x4;

__device__ __forceinline__ float bf2f(u16 u) {
    u32 t = ((u32)u) << 16;
    float f;
    __builtin_memcpy(&f, &t, 4);
    return f;
}
__device__ __forceinline__ u16 f2bf(float f) {
    u32 u;
    __builtin_memcpy(&u, &f, 4);
    u32 r = (u + 0x7fffu + ((u >> 16) & 1u)) >> 16;
    return (u16)r;
}
__device__ __forceinline__ float tanh_fast(float x) {
    float xc = fminf(fmaxf(x, -15.f), 15.f);
    float e = __expf(2.f * xc);
    return (e - 1.f) * __builtin_amdgcn_rcpf(e + 1.f);
}

// Async global->LDS DMA, 16B per lane. LDS dest = wave-uniform base + lane*16.
__device__ __forceinline__ void gld16(const u16* g, u16* l) {
    __builtin_amdgcn_global_load_lds(
        (const __attribute__((address_space(1))) u32*)(uintptr_t)g,
        (__attribute__((address_space(3))) u32*)(u32)(uintptr_t)l,
        16, 0, 0);
}

// HISTORY (kept as journal):
// - R8: XCD "contiguous chunk" swizzle REVERTED — conv FETCH 188->308 MB,
//   dur 127->167 us. Blocks sharing A-panels sit at linearized distances that
//   are multiples of 8, so default round-robin id%8 already co-locates them.
// - R9: mlp_head lsH-chunking (66->49 KB) REVERTED — total 1398->1481 us.
//   Occupancy measured 21.7% (grid/tail-bound, not LDS-bound); the +2
//   barriers per n-tile were pure cost.
// This file is the exact R6 configuration (measured 1398 us).

// LDS bank swizzle (round 5, kept): chunk c (16B) of row r staged into slot
// (c + (r>>1)) & 3; consumer reads chunk qd of row R at (qd + (R>>1)) & 3.
// Verified round 5: SQ_LDS_BANK_CONFLICT 5.5M -> 0.

// ---------------------------------------------------------------------------
// bf16 MFMA GEMM, tile 128 x NT, SINGLE-BARRIER PIPELINED K-LOOP (round 6).
// A: [spatial][Bc][ldA] (k-contiguous). W: [T][N][ldW]. T==9 -> 3x3 conv via
// shift-GEMM. EPI 0: relu(acc*epiA[n]+epiB[n]); EPI 1: tanh(acc+epiB[n]).
// ---------------------------------------------------------------------------
template <int EPI, int NT>
__global__ __launch_bounds__(256, 3) void gemm_bt(
    const u16* __restrict__ A, const u16* __restrict__ W, u16* __restrict__ O,
    const float* __restrict__ epiA, const float* __restrict__ epiB,
    int Kin, int N, int T, int Himg, int Wimg,
    int ldA, int ldW, int ldO,
    long long Az, long long Wz, long long Oz, int epiZ,
    int Bc, int bshift)
{
    constexpr int NJ = NT / 32;          // 4 (NT=128) or 2 (NT=64)
    __shared__ __align__(16) u16 lsA[2][128 * 32];
    __shared__ __align__(16) u16 lsW[2][NT * 32];

    const int tid = threadIdx.x;
    const int z = blockIdx.z;
    A += (long long)z * Az;
    W += (long long)z * Wz;
    O += (long long)z * Oz;
    epiB += (long long)z * epiZ;

    const int m0 = blockIdx.x * 128;
    const int n0 = blockIdx.y * NT;
    const int s = m0 >> bshift;          // spatial index (0 for MLP)
    const int b0 = m0 & (Bc - 1);        // batch offset
    const int hh0 = s / Wimg, ww0 = s % Wimg;

    const int wave = tid >> 6;
    const int lane = tid & 63;
    const int mbase = (wave >> 1) * 64;
    const int nbase = (wave & 1) * (NT / 2);
    const int ln = lane & 15, qd = lane >> 4;

    const int srow = lane >> 2;                                // staging row in 16-slab
    const int sc = (((lane & 3) - ((srow >> 1) & 3)) & 3) * 8; // swizzled fetch chunk
    const int csel = ((qd + (ln >> 1)) & 3) * 8;               // swizzled read chunk

    // lane-constant staging offsets (elems)
    const int rowA = wave * 32 + srow;
    const int rowW = (NT == 128) ? (wave * 32 + srow) : (wave * 16 + srow);
    const int offA0 = rowA * ldA + sc;
    const int offA1 = offA0 + 16 * ldA;
    const int offW0 = rowW * ldW + sc;
    const int offW1 = offW0 + 16 * ldW;   // NT==128 only
    u16* const lA0 = &lsA[0][0] + wave * 1024;
    u16* const lW0 = (NT == 128) ? (&lsW[0][0] + wave * 1024) : (&lsW[0][0] + wave * 512);
    constexpr int LPAR_A = 128 * 32;      // parity stride (elems)
    constexpr int LPAR_W = NT * 32;

    // tap helpers (all wave-uniform)
    auto tapvalid = [&](int t) -> bool {
        if (T != 9) return true;
        const int hh = hh0 + t / 3 - 1, ww = ww0 + t % 3 - 1;
        return hh >= 0 && hh < Himg && ww >= 0 && ww < Wimg;
    };
    auto tapA = [&](int t) -> const u16* {
        int sp = s;
        if (T == 9) sp = (hh0 + t / 3 - 1) * Wimg + (ww0 + t % 3 - 1);
        return A + (long long)(sp * Bc + b0) * ldA;
    };

    int t0 = 0;
    while (!tapvalid(t0)) ++t0;
    int nvalid = 0;
    for (int t = 0; t < T; ++t) nvalid += tapvalid(t) ? 1 : 0;
    const int KS = Kin >> 5;
    const int S = nvalid * KS;

    const u16* Ab = tapA(t0);
    const u16* Wb = W + ((long long)t0 * N + n0) * ldW;

    // prologue: prefetch step 0 into parity 0
    gld16(Ab + offA0, lA0);
    gld16(Ab + offA1, lA0 + 512);
    gld16(Wb + offW0, lW0);
    if (NT == 128) gld16(Wb + offW1, lW0 + 512);

    int ntap = t0, nkk = 0;

    f32x4 acc[4][NJ];
#pragma unroll
    for (int i = 0; i < 4; ++i)
#pragma unroll
        for (int j = 0; j < NJ; ++j)
            acc[i][j] = (f32x4){0.f, 0.f, 0.f, 0.f};

    for (int st = 0; st < S; ++st) {
        __syncthreads();   // drains prefetch issued at st-1 (had full MFMA phase in flight)
        if (st + 1 < S) {
            nkk += 32;
            if (nkk == Kin) {
                nkk = 0;
                do { ++ntap; } while (!tapvalid(ntap));
                Ab = tapA(ntap);
                Wb = W + ((long long)ntap * N + n0) * ldW;
            }
            const int pp = (st + 1) & 1;
            gld16(Ab + offA0 + nkk, lA0 + pp * LPAR_A);
            gld16(Ab + offA1 + nkk, lA0 + pp * LPAR_A + 512);
            gld16(Wb + offW0 + nkk, lW0 + pp * LPAR_W);
            if (NT == 128) gld16(Wb + offW1 + nkk, lW0 + pp * LPAR_W + 512);
        }
        const int cp = st & 1;
        bf16x8 af[4], bfr[NJ];
#pragma unroll
        for (int f = 0; f < 4; ++f)
            af[f] = *(const bf16x8*)&lsA[cp][(mbase + f * 16 + ln) * 32 + csel];
#pragma unroll
        for (int f = 0; f < NJ; ++f)
            bfr[f] = *(const bf16x8*)&lsW[cp][(nbase + f * 16 + ln) * 32 + csel];
#pragma unroll
        for (int i = 0; i < 4; ++i)
#pragma unroll
            for (int j = 0; j < NJ; ++j)
                acc[i][j] = __builtin_amdgcn_mfma_f32_16x16x32_bf16(
                    af[i], bfr[j], acc[i][j], 0, 0, 0);
    }

#pragma unroll
    for (int j = 0; j < NJ; ++j) {
        const int n = n0 + nbase + j * 16 + ln;
        const float sh = epiB[n];
        float sc2 = 1.f;
        if (EPI == 0) sc2 = epiA[n];
#pragma unroll
        for (int i = 0; i < 4; ++i) {
            const int mrow = mbase + i * 16 + qd * 4;
#pragma unroll
            for (int rr = 0; rr < 4; ++rr) {
                float v = acc[i][j][rr];
                if (EPI == 0) v = fmaxf(v * sc2 + sh, 0.f);
                else          v = tanh_fast(v + sh);
                O[(long long)(m0 + mrow + rr) * ldO + n] = f2bf(v);
            }
        }
    }
}

// ---------------------------------------------------------------------------
// FUSED MLP (Linear->tanh, 5 n-tiles) + logits (600->10 via 640->16) +
// softmax (round 10 form, measured-best). Eliminates h1/h2 HBM round-trip
// and the separate latency-bound logits kernel. One block = 128 batch rows x
// one node (z). Per n-tile: single-barrier pipelined K-loop computes a
// 128x128 h-tile; epilogue applies tanh and writes bf16 into lsH[128][132];
// then 4 k-steps x 2 MFMA/wave accumulate the logits GEMM from lsH (B-frags
// hoisted from global before the barrier). After 5 tiles: shfl-softmax.
// LDS 66.3 KB -> 2 blocks/CU; R9 proved chunking lsH to 49 KB REGRESSES
// (occupancy is grid/tail-bound, not LDS-bound; extra barriers pure cost).
// ---------------------------------------------------------------------------
template <int STAGE>
__global__ __launch_bounds__(256, 2) void mlp_head(
    const u16* __restrict__ A, const u16* __restrict__ W,
    const float* __restrict__ bap, const u16* __restrict__ Wbp,
    const float* __restrict__ bbp,
    u16* __restrict__ preds, float* __restrict__ dout,
    int Kin, int Bc, int gbase)
{
    __shared__ __align__(16) u16 lsA[2][128 * 32];
    __shared__ __align__(16) u16 lsW[2][128 * 32];
    __shared__ __align__(16) u16 lsH[128 * 132];

    const int tid = threadIdx.x;
    const int z = blockIdx.z;                 // node 0..24
    A += (long long)z * Bc * Kin;
    W += (long long)z * 640 * 352;
    const float* bz = bap + z * 640;

    const int m0 = blockIdx.x * 128;          // batch row base
    const int wave = tid >> 6;
    const int lane = tid & 63;
    const int mbase = (wave >> 1) * 64;
    const int nbase = (wave & 1) * 64;
    const int ln = lane & 15, qd = lane >> 4;
    const int srow = lane >> 2;
    const int sc = (((lane & 3) - ((srow >> 1) & 3)) & 3) * 8;
    const int csel = ((qd + (ln >> 1)) & 3) * 8;

    const int rowS = wave * 32 + srow;
    const int offA0 = rowS * Kin + sc;        // ldA = Kin
    const int offA1 = offA0 + 16 * Kin;
    const int offW0 = rowS * 352 + sc;        // ldW = 352
    const int offW1 = offW0 + 16 * 352;
    u16* const lA0 = &lsA[0][0] + wave * 1024;
    u16* const lW0 = &lsW[0][0] + wave * 1024;

    const int KS = Kin >> 5;                  // 8 (stage1) or 11 (stage2)
    const int Stot = 5 * KS;

    const u16* Ab = A + (long long)m0 * Kin;
    const u16* Wb = W;
    int pnt = 0, pnkk = 0;

    // prologue: prefetch flat step 0 into parity 0
    gld16(Ab + offA0, lA0);
    gld16(Ab + offA1, lA0 + 512);
    gld16(Wb + offW0, lW0);
    gld16(Wb + offW1, lW0 + 512);

    f32x4 acc[4][4];
#pragma unroll
    for (int i = 0; i < 4; ++i)
#pragma unroll
        for (int j = 0; j < 4; ++j)
            acc[i][j] = (f32x4){0.f, 0.f, 0.f, 0.f};
    f32x4 acc_lg[2];
    acc_lg[0] = (f32x4){0.f, 0.f, 0.f, 0.f};
    acc_lg[1] = (f32x4){0.f, 0.f, 0.f, 0.f};

    int g = 0;   // flat step index
    for (int nt = 0; nt < 5; ++nt) {
        for (int st = 0; st < KS; ++st, ++g) {
            __syncthreads();   // drains prefetch issued at g-1
            if (g + 1 < Stot) {
                pnkk += 32;
                if (pnkk == Kin) {   // next n-tile: K wraps, W column base advances
                    pnkk = 0;
                    ++pnt;
                    Wb = W + (long long)pnt * 128 * 352;
                }
                const int pp = (g + 1) & 1;
                gld16(Ab + offA0 + pnkk, lA0 + pp * (128 * 32));
                gld16(Ab + offA1 + pnkk, lA0 + pp * (128 * 32) + 512);
                gld16(Wb + offW0 + pnkk, lW0 + pp * (128 * 32));
                gld16(Wb + offW1 + pnkk, lW0 + pp * (128 * 32) + 512);
            }
            const int cp = g & 1;
            bf16x8 af[4], bfr[4];
#pragma unroll
            for (int f = 0; f < 4; ++f)
                af[f] = *(const bf16x8*)&lsA[cp][(mbase + f * 16 + ln) * 32 + csel];
#pragma unroll
            for (int f = 0; f < 4; ++f)
                bfr[f] = *(const bf16x8*)&lsW[cp][(nbase + f * 16 + ln) * 32 + csel];
#pragma unroll
            for (int i = 0; i < 4; ++i)
#pragma unroll
                for (int j = 0; j < 4; ++j)
                    acc[i][j] = __builtin_amdgcn_mfma_f32_16x16x32_bf16(
                        af[i], bfr[j], acc[i][j], 0, 0, 0);
        }

        // tile epilogue: tanh -> bf16 h-tile into LDS (no global write)
#pragma unroll
        for (int j = 0; j < 4; ++j) {
            const int hc = nbase + j * 16 + ln;          // local h-col 0..127
            const float sh = bz[nt * 128 + hc];
#pragma unroll
            for (int i = 0; i < 4; ++i) {
                const int br = mbase + i * 16 + qd * 4;  // batch row (local)
#pragma unroll
                for (int rr = 0; rr < 4; ++rr)
                    lsH[(br + rr) * 132 + hc] = f2bf(tanh_fast(acc[i][j][rr] + sh));
                acc[i][j] = (f32x4){0.f, 0.f, 0.f, 0.f};
            }
        }
        // hoist logits B-frags (global, L2-hot) before the barrier
        bf16x8 bfrg[4];
#pragma unroll
        for (int ks = 0; ks < 4; ++ks)
            bfrg[ks] = *(const bf16x8*)&Wbp[((long long)z * 16 + ln) * 640 +
                                            nt * 128 + ks * 32 + qd * 8];
        __syncthreads();   // all h writes visible (also drains next-tile prefetch)

        // logits partial GEMM: rows wave*32..+31, K = this tile's 128 h-cols
#pragma unroll
        for (int ks = 0; ks < 4; ++ks) {
#pragma unroll
            for (int i = 0; i < 2; ++i) {
                const int base = (wave * 32 + i * 16 + ln) * 132 + ks * 32 + qd * 8;
                const uint2 u0 = *(const uint2*)&lsH[base];
                const uint2 u1 = *(const uint2*)&lsH[base + 4];
                u32 w4[4] = {u0.x, u0.y, u1.x, u1.y};
                bf16x8 a8;
                __builtin_memcpy(&a8, w4, 16);
                acc_lg[i] = __builtin_amdgcn_mfma_f32_16x16x32_bf16(
                    a8, bfrg[ks], acc_lg[i], 0, 0, 0);
            }
        }
        // next tile's first MLP step barrier orders lsH reuse
    }

    // softmax over the 16-lane group (pad cols have bbp=-1e30 -> excluded)
    const float bias = bbp[z * 16 + ln];
#pragma unroll
    for (int i = 0; i < 2; ++i) {
#pragma unroll
        for (int rr = 0; rr < 4; ++rr) {
            const float v = acc_lg[i][rr] + bias;
            float mx = v;
#pragma unroll
            for (int mk = 1; mk < 16; mk <<= 1)
                mx = fmaxf(mx, __shfl_xor(mx, mk));
            const float e = __expf(v - mx);
            float ssum = e;
#pragma unroll
            for (int mk = 1; mk < 16; mk <<= 1)
                ssum += __shfl_xor(ssum, mk);
            const float p = e / ssum;
            const int row = m0 + wave * 32 + i * 16 + qd * 4 + rr;
            if (ln < 10) {
                if (STAGE == 1)
                    preds[((long long)z * Bc + row) * 10 + ln] = f2bf(p);
                else
                    dout[81920 + ((long long)z * 8192 + gbase + row) * 10 + ln] = p;
            }
        }
    }
}

// ---------------------------------------------------------------------------
// FUSED conv1 + BN + ReLU + maxpool3s2p1, v2 (round 8): NO LDS, NO BARRIERS.
// ---------------------------------------------------------------------------
__global__ __launch_bounds__(256) void conv1pool(
    const u16* __restrict__ xcol, const u16* __restrict__ W1t, u16* __restrict__ p1,
    const float* __restrict__ epiA, const float* __restrict__ epiB, int Bc)
{
    const int tid = threadIdx.x;
    const int wave = tid >> 6;
    const int lane = tid & 63;
    const int ln = lane & 15, qd = lane >> 4;

    const int b0 = blockIdx.x * 128;
    const int so = blockIdx.y;            // pooled spatial index 0..99
    const int ho = so / 10, wo = so % 10;

    const int mbase = (wave >> 1) * 64;
    const int nbase = (wave & 1) * 32;

    bf16x8 bfr[2];
#pragma unroll
    for (int j = 0; j < 2; ++j)
        bfr[j] = *(const bf16x8*)&W1t[(nbase + j * 16 + ln) * 32 + qd * 8];

    float sc2[2], sh[2];
#pragma unroll
    for (int j = 0; j < 2; ++j) {
        const int n = nbase + j * 16 + ln;
        sc2[j] = epiA[n];
        sh[j] = epiB[n];
    }

    f32x4 best[4][2];
#pragma unroll
    for (int i = 0; i < 4; ++i)
#pragma unroll
        for (int j = 0; j < 2; ++j)
            best[i][j] = (f32x4){0.f, 0.f, 0.f, 0.f};

#pragma unroll
    for (int st = 0; st < 9; ++st) {
        int hh = 2 * ho - 1 + st / 3;
        int ww = 2 * wo - 1 + st % 3;
        hh = hh < 0 ? 0 : (hh > 19 ? 19 : hh);
        ww = ww < 0 ? 0 : (ww > 19 ? 19 : ww);
        const u16* Ab = xcol + (long long)((hh * 20 + ww) * Bc + b0) * 32;

        bf16x8 af[4];
#pragma unroll
        for (int f = 0; f < 4; ++f)
            af[f] = *(const bf16x8*)&Ab[(mbase + f * 16 + ln) * 32 + qd * 8];

#pragma unroll
        for (int i = 0; i < 4; ++i)
#pragma unroll
            for (int j = 0; j < 2; ++j) {
                f32x4 acc = (f32x4){0.f, 0.f, 0.f, 0.f};
                acc = __builtin_amdgcn_mfma_f32_16x16x32_bf16(af[i], bfr[j], acc, 0, 0, 0);
#pragma unroll
                for (int rr = 0; rr < 4; ++rr) {
                    const float v = fmaxf(acc[rr] * sc2[j] + sh[j], 0.f);
                    best[i][j][rr] = fmaxf(best[i][j][rr], v);
                }
            }
    }

#pragma unroll
    for (int j = 0; j < 2; ++j) {
        const int n = nbase + j * 16 + ln;
#pragma unroll
        for (int i = 0; i < 4; ++i) {
            const int mrow = mbase + i * 16 + qd * 4;
#pragma unroll
            for (int rr = 0; rr < 4; ++rr)
                p1[(long long)(so * Bc + b0 + mrow + rr) * 64 + n] = f2bf(best[i][j][rr]);
        }
    }
}

// ---------------------------------------------------------------------------
// x chunk [Bc,3,20,20] fp32 -> xt [400][Bc][4] bf16 (ch padded to 4, pad=0)
// ---------------------------------------------------------------------------
__global__ __launch_bounds__(256) void transpose_x(
    const float* __restrict__ x, u16* __restrict__ xt, int Bc, int bshift)
{
    const int t = blockIdx.x * 256 + threadIdx.x;
    if (t >= 400 * Bc) return;
    const int s = t >> bshift;
    const int b = t & (Bc - 1);
    const u32 c0 = f2bf(x[((long long)b * 3 + 0) * 400 + s]);
    const u32 c1 = f2bf(x[((long long)b * 3 + 1) * 400 + s]);
    const u32 c2 = f2bf(x[((long long)b * 3 + 2) * 400 + s]);
    uint2 st;
    st.x = c0 | (c1 << 16);
    st.y = c2;                              // high 16 = 0 pad
    *(uint2*)(xt + ((long long)s * Bc + b) * 4) = st;
}

// ---------------------------------------------------------------------------
// im2col for conv1: xt[400][Bc][4] -> xcol[400][Bc][32] (k = tap*3+ci, pad 0).
// ---------------------------------------------------------------------------
__global__ __launch_bounds__(256) void im2col1(
    const u16* __restrict__ xt, u16* __restrict__ xcol, int Bc, int bshift)
{
    const int t = blockIdx.x * 256 + threadIdx.x;
    if (t >= 400 * Bc) return;
    const int s = t >> bshift;
    const int b = t & (Bc - 1);
    const int hh = s / 20, ww = s % 20;

    u32 p0, q0, p1, q1, p2, q2, p3, q3, p4, q4, p5, q5, p6, q6, p7, q7, p8, q8;
#define LOADTAP(T, P, Q)                                                      \
    {                                                                         \
        const int ih = hh + (T) / 3 - 1, iw = ww + (T) % 3 - 1;               \
        P = 0u; Q = 0u;                                                       \
        if (ih >= 0 && ih < 20 && iw >= 0 && iw < 20) {                       \
            const uint2 v = *(const uint2*)(xt +                              \
                ((long long)(ih * 20 + iw) * Bc + b) * 4);                    \
            P = v.x; Q = v.y;                                                 \
        }                                                                     \
    }
    LOADTAP(0, p0, q0) LOADTAP(1, p1, q1) LOADTAP(2, p2, q2)
    LOADTAP(3, p3, q3) LOADTAP(4, p4, q4) LOADTAP(5, p5, q5)
    LOADTAP(6, p6, q6) LOADTAP(7, p7, q7) LOADTAP(8, p8, q8)
#undef LOADTAP

    u16* o = xcol + (long long)t * 32;
    uint4 w;
    w.x = p0;                w.y = q0 | (p1 << 16);
    w.z = (p1 >> 16) | (q1 << 16);
    w.w = p2;
    *(uint4*)(o + 0) = w;
    w.x = q2 | (p3 << 16);   w.y = (p3 >> 16) | (q3 << 16);
    w.z = p4;                w.w = q4 | (p5 << 16);
    *(uint4*)(o + 8) = w;
    w.x = (p5 >> 16) | (q5 << 16);
    w.y = p6;                w.z = q6 | (p7 << 16);
    w.w = (p7 >> 16) | (q7 << 16);
    *(uint4*)(o + 16) = w;
    w.x = p8;                w.y = q8;   // k=24..26 (+pad)
    w.z = 0u;                w.w = 0u;
    *(uint4*)(o + 24) = w;
}

// ---------------------------------------------------------------------------
// maxpool 3x3 s2 p1, square maps: src[Hi*Hi][Bc][CH] -> dst[Ho*Ho][Bc][CH].
// ---------------------------------------------------------------------------
template <int CH>
__global__ __launch_bounds__(256) void pool_k(
    const u16* __restrict__ src, u16* __restrict__ dst, int Bc, int Hi, int Ho)
{
    constexpr int G = CH / 8;
    const int t = blockIdx.x * 256 + threadIdx.x;
    const int cc = t & (G - 1);
    const int b = t / G;
    if (b >= Bc) return;
    const int so = blockIdx.y;
    const int ho = so / Ho, wo = so % Ho;
    float best[8];
#pragma unroll
    for (int e = 0; e < 8; ++e) best[e] = 0.f;
    for (int ph = 0; ph < 3; ++ph) {
        const int hh = 2 * ho - 1 + ph;
        if (hh < 0 || hh >= Hi) continue;
        for (int pw = 0; pw < 3; ++pw) {
            const int ww = 2 * wo - 1 + pw;
            if (ww < 0 || ww >= Hi) continue;
            const uint4 u = *(const uint4*)(src + ((long long)(hh * Hi + ww) * Bc + b) * CH + cc * 8);
            const u32 uw[4] = {u.x, u.y, u.z, u.w};
#pragma unroll
            for (int e = 0; e < 4; ++e) {
                best[2 * e]     = fmaxf(best[2 * e],     bf2f((u16)(uw[e] & 0xffff)));
                best[2 * e + 1] = fmaxf(best[2 * e + 1], bf2f((u16)(uw[e] >> 16)));
            }
        }
    }
    u32 pk[4];
#pragma unroll
    for (int e = 0; e < 4; ++e)
        pk[e] = (u32)f2bf(best[2 * e]) | (((u32)f2bf(best[2 * e + 1])) << 16);
    uint4 st;
    st.x = pk[0]; st.y = pk[1]; st.z = pk[2]; st.w = pk[3];
    *(uint4*)(dst + ((long long)so * Bc + b) * CH + cc * 8) = st;
}

// ---------------------------------------------------------------------------
// Stage-2 input assembly.
// ---------------------------------------------------------------------------
__device__ __forceinline__ void neighbors5x5(int i, int* nb) {
    const int w = 5, size = 25;
    int cnt = 0;
    if (i - w >= 0) nb[cnt++] = i - w;
    if (i % w != 0) nb[cnt++] = i - 1;
    if ((i + 1) % w != 0) nb[cnt++] = i + 1;
    if (i + w < size) nb[cnt++] = i + w;
    if (i - w - 1 >= 0 && i % w != 0) nb[cnt++] = i - w - 1;
    if (i - w + 1 >= 0 && (i + 1) % w != 0) nb[cnt++] = i - w + 1;
    if (i + w - 1 < size && i % w != 0) nb[cnt++] = i + w - 1;
    if (i + w + 1 < size && (i + 1) % w != 0) nb[cnt++] = i + w + 1;
    for (; cnt < 8; ++cnt) nb[cnt] = -1;
}

__global__ __launch_bounds__(256) void gather_nb(
    const u16* __restrict__ preds, const u16* __restrict__ feats, u16* __restrict__ A2,
    int Bc, int bshift)
{
    const int g = blockIdx.x * 256 + threadIdx.x;  // n*Bc+b
    if (g >= 25 * Bc) return;
    const int n = g >> bshift;
    const int b = g & (Bc - 1);
    int nb[8];
    neighbors5x5(n, nb);
    u16* dst = A2 + (long long)g * 352;
#pragma unroll
    for (int j = 0; j < 8; ++j) {
        u32* d32 = (u32*)(dst + j * 10);
        if (nb[j] >= 0) {
            const u32* s32 = (const u32*)(preds + ((long long)nb[j] * Bc + b) * 10);
#pragma unroll
            for (int q = 0; q < 5; ++q) d32[q] = s32[q];
        } else {
#pragma unroll
            for (int q = 0; q < 5; ++q) d32[q] = 0u;
        }
    }
    const uint4* fs = (const uint4*)(feats + (long long)g * 256);
    uint4* fd = (uint4*)(dst + 80);
#pragma unroll
    for (int q = 0; q < 32; ++q) fd[q] = fs[q];
    uint4 z;
    z.x = 0u; z.y = 0u; z.z = 0u; z.w = 0u;
    *(uint4*)(dst + 336) = z;
    *(uint4*)(dst + 344) = z;
}

__global__ __launch_bounds__(256) void mean_k(float* __restrict__ dout)
{
    const int t = blockIdx.x * 256 + threadIdx.x;
    float s = 0.f;
#pragma unroll
    for (int n = 0; n < 25; ++n) s += dout[81920 + n * 81920 + t];
    dout[t] = s * 0.04f;
}

// ---------------------------------------------------------------------------
// Weight/param prep (once per launch)
// ---------------------------------------------------------------------------
__global__ void prep_bn_all(
    const float* b1, const float* g1, const float* be1, const float* m1, const float* v1,
    const float* b2, const float* g2, const float* be2, const float* m2, const float* v2,
    const float* b3, const float* g3, const float* be3, const float* m3, const float* v3,
    const float* b4, const float* g4, const float* be4, const float* m4, const float* v4,
    float* bnA, float* bnB)
{
    const int t = blockIdx.x * 256 + threadIdx.x;
    if (t >= 704) return;
    const float *bp, *gp, *bep, *mp, *vp;
    int idx;
    if (t < 64)       { bp=b1; gp=g1; bep=be1; mp=m1; vp=v1; idx=t; }
    else if (t < 192) { bp=b2; gp=g2; bep=be2; mp=m2; vp=v2; idx=t-64; }
    else if (t < 448) { bp=b3; gp=g3; bep=be3; mp=m3; vp=v3; idx=t-192; }
    else              { bp=b4; gp=g4; bep=be4; mp=m4; vp=v4; idx=t-448; }
    const float A = gp[idx] * rsqrtf(vp[idx] + 1e-5f);
    bnA[t] = A;
    bnB[t] = (bp[idx] - mp[idx]) * A + bep[idx];
}

// W1 [64][3][3][3] -> W1t [64][32], k = tap*3+ci (tap = kh*3+kw), pad 0
__global__ void prep_w1col(const float* __restrict__ W1, u16* __restrict__ W1t)
{
    const int t = blockIdx.x * 256 + threadIdx.x;
    if (t >= 64 * 32) return;
    const int n = t >> 5, k = t & 31;
    u16 v = 0;
    if (k < 27) {
        const int tap = k / 3, ci = k % 3;
        v = f2bf(W1[n * 27 + ci * 9 + tap]);
    }
    W1t[t] = v;
}

// W [Co][Ci][3][3] fp32 -> Wt [9][Co][Ci] bf16
__global__ void prep_convw(const float* __restrict__ W, u16* __restrict__ Wt, int Co, int Ci)
{
    const int t = blockIdx.x * 256 + threadIdx.x;
    const int tot = 9 * Co * Ci;
    if (t >= tot) return;
    const int sh = t / (Co * Ci);
    const int rem = t % (Co * Ci);
    const int co = rem / Ci, ci = rem % Ci;
    Wt[t] = f2bf(W[(long long)(co * Ci + ci) * 9 + sh]);
}

__global__ void prep_wat(const float* __restrict__ Wa, u16* __restrict__ Wat)
{
    const int t = blockIdx.x * 256 + threadIdx.x;
    if (t >= 25 * 640 * 352) return;
    const int n = t / (640 * 352);
    const int rem = t % (640 * 352);
    const int hcol = rem / 352;
    const int k = rem % 352;
    float v = 0.f;
    if (hcol < 600 && k < 336) v = Wa[((long long)n * 336 + k) * 600 + hcol];
    Wat[t] = f2bf(v);
}

__global__ void prep_ba(const float* __restrict__ ba, float* __restrict__ bap)
{
    const int t = blockIdx.x * 256 + threadIdx.x;
    if (t >= 25 * 640) return;
    const int n = t / 640, hcol = t % 640;
    bap[t] = (hcol < 600) ? ba[n * 600 + hcol] : 0.f;
}

// Wb [25][600][10] fp32 -> Wbp [25][16][640] bf16 (transposed, zero-pad);
// bb [25][10] -> bbp [25][16] fp32 (pad -1e30 so softmax ignores pad cols)
__global__ void prep_wbt(const float* __restrict__ Wb, const float* __restrict__ bb,
                         u16* __restrict__ Wbp, float* __restrict__ bbp)
{
    const int t = blockIdx.x * 256 + threadIdx.x;
    if (t < 25 * 16 * 640) {
        const int n = t / (16 * 640);
        const int rem = t % (16 * 640);
        const int c = rem / 640, k = rem % 640;
        u16 v = 0;
        if (c < 10 && k < 600) v = f2bf(Wb[((long long)n * 600 + k) * 10 + c]);
        Wbp[t] = v;
    }
    if (t < 25 * 16) {
        const int n = t >> 4, c = t & 15;
        bbp[t] = (c < 10) ? bb[n * 10 + c] : -1e30f;
    }
}

// ---------------------------------------------------------------------------
extern "C" void kernel_launch(void* const* d_in, const int* in_sizes, int n_in,
                              void* d_out, int out_size, void* d_ws, size_t ws_size,
                              hipStream_t stream)
{
    (void)in_sizes; (void)n_in; (void)out_size;

    const float* x  = (const float*)d_in[0];
    const float* W1 = (const float*)d_in[1];
    const float* b1 = (const float*)d_in[2];
    const float* g1 = (const float*)d_in[3];
    const float* be1= (const float*)d_in[4];
    const float* m1 = (const float*)d_in[5];
    const float* v1 = (const float*)d_in[6];
    const float* W2 = (const float*)d_in[7];
    const float* b2 = (const float*)d_in[8];
    const float* g2 = (const float*)d_in[9];
    const float* be2= (const float*)d_in[10];
    const float* m2 = (const float*)d_in[11];
    const float* v2 = (const float*)d_in[12];
    const float* W3 = (const float*)d_in[13];
    const float* b3 = (const float*)d_in[14];
    const float* g3 = (const float*)d_in[15];
    const float* be3= (const float*)d_in[16];
    const float* m3 = (const float*)d_in[17];
    const float* v3 = (const float*)d_in[18];
    const float* W4 = (const float*)d_in[19];
    const float* b4 = (const float*)d_in[20];
    const float* g4 = (const float*)d_in[21];
    const float* be4= (const float*)d_in[22];
    const float* m4 = (const float*)d_in[23];
    const float* v4 = (const float*)d_in[24];
    const float* Wa = (const float*)d_in[25];
    const float* ba = (const float*)d_in[26];
    const float* Wb = (const float*)d_in[27];
    const float* bb = (const float*)d_in[28];
    float* dout = (float*)d_out;

    // ---- choose Bc: overlay peak = 44032 bytes per batch element ----
    auto al = [](long long v) { return (v + 255LL) & ~255LL; };
    const long long fixedB = al(4096) + al(147456) + al(589824) + al(1179648) +
                             al(11264000) + al(64000) + al(2816) + al(2816) +
                             al(512000) + al(1600);
    int Bc = 256;
    for (int cand = 8192; cand >= 256; cand >>= 1) {
        long long need = fixedB + al(44032LL * cand);
        if (need <= (long long)ws_size) { Bc = cand; break; }
    }
    const int bshift = __builtin_ctz((unsigned)Bc);
    const int C = 8192 / Bc;

    // ---- workspace: fixed region + one overlaid chunk region ----
    char* wsp = (char*)d_ws;
    long long off = 0;
    auto alloc = [&](long long bytes) { long long o = off; off += al(bytes); return o; };
    u16* W1t  = (u16*)(wsp + alloc(4096));
    u16* Wt2  = (u16*)(wsp + alloc(147456));
    u16* Wt3  = (u16*)(wsp + alloc(589824));
    u16* Wt4  = (u16*)(wsp + alloc(1179648));
    u16* Wat  = (u16*)(wsp + alloc(11264000));
    float* bap = (float*)(wsp + alloc(64000));
    float* bnA = (float*)(wsp + alloc(2816));
    float* bnB = (float*)(wsp + alloc(2816));
    u16* Wbp  = (u16*)(wsp + alloc(512000));
    float* bbp = (float*)(wsp + alloc(1600));
    char* ch = wsp + alloc(44032LL * Bc);
    // overlay (bytes-per-elem offsets; lifetimes disjoint where ranges overlap):
    u16* xt   = (u16*)(ch + 0LL     * Bc);   // [0,3200)       t1-t1.5
    u16* xcol = (u16*)(ch + 3200LL  * Bc);   // [3200,28800)   t1.5-t2
    u16* p1   = (u16*)(ch + 28800LL * Bc);   // [28800,41600)  t2-t3
    u16* a2   = (u16*)(ch + 0LL     * Bc);   // [0,25600)      t3-t3.5
    u16* p2   = (u16*)(ch + 25600LL * Bc);   // [25600,32000)  t3.5-t4
    u16* a3   = (u16*)(ch + 0LL     * Bc);   // [0,12800)      t4-t5
    u16* a4   = (u16*)(ch + 12800LL * Bc);   // [12800,25600)  t5-t8
    u16* preds= (u16*)(ch + 25600LL * Bc);   // [25600,26112)  t6-t7
    u16* A2   = (u16*)(ch + 26112LL * Bc);   // [26112,43712)  t7-t8

    // ---- prep (once) ----
    prep_bn_all<<<dim3(3), 256, 0, stream>>>(b1,g1,be1,m1,v1, b2,g2,be2,m2,v2,
                                             b3,g3,be3,m3,v3, b4,g4,be4,m4,v4, bnA, bnB);
    prep_w1col<<<dim3(8), 256, 0, stream>>>(W1, W1t);
    prep_convw<<<dim3(288),  256, 0, stream>>>(W2, Wt2, 128, 64);
    prep_convw<<<dim3(1152), 256, 0, stream>>>(W3, Wt3, 256, 128);
    prep_convw<<<dim3(2304), 256, 0, stream>>>(W4, Wt4, 256, 256);
    prep_wat<<<dim3(22000), 256, 0, stream>>>(Wa, Wat);
    prep_ba<<<dim3(63), 256, 0, stream>>>(ba, bap);
    prep_wbt<<<dim3(1000), 256, 0, stream>>>(Wb, bb, Wbp, bbp);

    // ---- batch chunks ----
    for (int c = 0; c < C; ++c) {
        const float* xc = x + (long long)c * Bc * 1200;

        transpose_x<<<dim3(400 * Bc / 256), 256, 0, stream>>>(xc, xt, Bc, bshift);
        im2col1<<<dim3(400 * Bc / 256), 256, 0, stream>>>(xt, xcol, Bc, bshift);
        conv1pool<<<dim3(Bc / 128, 100), 256, 0, stream>>>(xcol, W1t, p1, bnA, bnB, Bc);

        gemm_bt<0,128><<<dim3(100 * Bc / 128, 1), 256, 0, stream>>>(p1, Wt2, a2, bnA + 64, bnB + 64,
            64, 128, 9, 10, 10, 64, 64, 128, 0LL, 0LL, 0LL, 0, Bc, bshift);
        pool_k<128><<<dim3(Bc * 16 / 256, 25), 256, 0, stream>>>(a2, p2, Bc, 10, 5);

        gemm_bt<0,128><<<dim3(25 * Bc / 128, 2), 256, 0, stream>>>(p2, Wt3, a3, bnA + 192, bnB + 192,
            128, 256, 9, 5, 5, 128, 128, 256, 0LL, 0LL, 0LL, 0, Bc, bshift);
        gemm_bt<0,128><<<dim3(25 * Bc / 128, 2), 256, 0, stream>>>(a3, Wt4, a4, bnA + 448, bnB + 448,
            256, 256, 9, 5, 5, 256, 256, 256, 0LL, 0LL, 0LL, 0, Bc, bshift);

        // stage 1: fused MLP+tanh+logits+softmax (zeros||feats -> Wa k-rows [80:336))
        mlp_head<1><<<dim3(Bc / 128, 1, 25), 256, 0, stream>>>(
            a4, Wat + 80, bap, Wbp, bbp, preds, nullptr, 256, Bc, 0);

        // stage 2
        gather_nb<<<dim3(25 * Bc / 256, 1), 256, 0, stream>>>(preds, a4, A2, Bc, bshift);
        mlp_head<2><<<dim3(Bc / 128, 1, 25), 256, 0, stream>>>(
            A2, Wat, bap, Wbp, bbp, nullptr, dout, 352, Bc, c * Bc);
    }

    mean_k<<<dim3(320), 256, 0, stream>>>(dout);
}

// Round 14
// 1377.617 us; speedup vs baseline: 1.1554x; 1.0420x over previous
//
#include <hip/hip_runtime.h>

typedef unsigned short u16;
typedef unsigned int u32;

typedef __attribute__((ext_vector_type(8))) __bf16 bf16x8;
typedef __attribute__((ext_vector_type(4))) float f32x4;

__device__ __forceinline__ float bf2f(u16 u) {
    u32 t = ((u32)u) << 16;
    float f;
    __builtin_memcpy(&f, &t, 4);
    return f;
}
__device__ __forceinline__ u16 f2bf(float f) {
    u32 u;
    __builtin_memcpy(&u, &f, 4);
    u32 r = (u + 0x7fffu + ((u >> 16) & 1u)) >> 16;
    return (u16)r;
}
__device__ __forceinline__ float tanh_fast(float x) {
    float xc = fminf(fmaxf(x, -15.f), 15.f);
    float e = __expf(2.f * xc);
    return (e - 1.f) * __builtin_amdgcn_rcpf(e + 1.f);
}

// Async global->LDS DMA, 16B per lane. LDS dest = wave-uniform base + lane*16.
__device__ __forceinline__ void gld16(const u16* g, u16* l) {
    __builtin_amdgcn_global_load_lds(
        (const __attribute__((address_space(1))) u32*)(uintptr_t)g,
        (__attribute__((address_space(3))) u32*)(u32)(uintptr_t)l,
        16, 0, 0);
}

// HISTORY (journal):
// - R8: XCD "contiguous chunk" swizzle REVERTED — conv FETCH 188->308 MB.
//   Same-b0 A-sharers sit at linearized distances that are multiples of 8,
//   so default round-robin id%8 already co-locates them on one XCD L2.
// - R9: mlp_head lsH-chunking REVERTED — total 1398->1481 us (occupancy is
//   grid/tail-bound, not LDS-bound; extra barriers pure cost).
// - R11: R6 config re-measured 1435 us (noise band vs 1398). conv gemm_bt
//   ~129 us, FETCH 188 MB (~3.5x A over-fetch), MfmaUtil 29.5%.
// - R12/R13/R14 (resubmitted after infra timeouts): conv dispatch-order
//   remap, output-neutral:
//   (a) n-tile pair of same (s,b0) placed 8 apart in dispatch order (same
//       XCD, temporally adjacent) -> A-slab read twice while L2-hot;
//   (b) longest-first spatial order (interior S=9*KS first, corners last)
//       -> drain tail runs on the shortest blocks.
//   Mod-8 co-location of same-b0 sharers is preserved by construction.

// LDS bank swizzle (round 5, kept): chunk c (16B) of row r staged into slot
// (c + (r>>1)) & 3; consumer reads chunk qd of row R at (qd + (R>>1)) & 3.
// Verified round 5: SQ_LDS_BANK_CONFLICT 5.5M -> 0.

// ---------------------------------------------------------------------------
// bf16 MFMA GEMM, tile 128 x NT, SINGLE-BARRIER PIPELINED K-LOOP (round 6).
// A: [spatial][Bc][ldA] (k-contiguous). W: [T][N][ldW]. T==9 -> 3x3 conv via
// shift-GEMM. EPI 0: relu(acc*epiA[n]+epiB[n]); EPI 1: tanh(acc+epiB[n]).
// ---------------------------------------------------------------------------
template <int EPI, int NT>
__global__ __launch_bounds__(256, 3) void gemm_bt(
    const u16* __restrict__ A, const u16* __restrict__ W, u16* __restrict__ O,
    const float* __restrict__ epiA, const float* __restrict__ epiB,
    int Kin, int N, int T, int Himg, int Wimg,
    int ldA, int ldW, int ldO,
    long long Az, long long Wz, long long Oz, int epiZ,
    int Bc, int bshift)
{
    constexpr int NJ = NT / 32;          // 4 (NT=128) or 2 (NT=64)
    __shared__ __align__(16) u16 lsA[2][128 * 32];
    __shared__ __align__(16) u16 lsW[2][NT * 32];

    const int tid = threadIdx.x;
    const int z = blockIdx.z;
    A += (long long)z * Az;
    W += (long long)z * Wz;
    O += (long long)z * Oz;
    epiB += (long long)z * epiZ;

    // ---- R12 dispatch-order remap (conv path; identity fallback) ----
    int m0, n0;
    {
        const int bps = Bc >> 7;                  // 128-row blocks per spatial pos
        if (T == 9 && (bps & 7) == 0) {
            const int d = blockIdx.x + gridDim.x * blockIdx.y;  // dispatch index
            int pairid, nidx;
            if (gridDim.y == 2) {
                // n-pair interleave at stride 8: d = g*16 + nidx*8 + sub
                nidx = (d >> 3) & 1;
                pairid = ((d >> 4) << 3) | (d & 7);
            } else {
                pairid = d;
                nidx = 0;
            }
            const int rank = pairid >> (bshift - 7);   // /bps
            const int bidx = pairid & (bps - 1);
            // rank -> spatial pos, longest-first: interior, edges, corners
            const int Hm2 = Himg - 2, Wm2 = Wimg - 2;
            const int Ni = Hm2 * Wm2;
            const int Ne = 2 * Wm2 + 2 * Hm2;
            int hh, ww;
            if (rank < Ni) {
                hh = 1 + rank / Wm2;
                ww = 1 + rank % Wm2;
            } else if (rank < Ni + Ne) {
                const int e = rank - Ni;
                if (e < Wm2)                 { hh = 0;                     ww = 1 + e; }
                else if (e < 2 * Wm2)        { hh = Himg - 1;              ww = 1 + e - Wm2; }
                else if (e < 2 * Wm2 + Hm2)  { hh = 1 + e - 2 * Wm2;       ww = 0; }
                else                         { hh = 1 + e - 2 * Wm2 - Hm2; ww = Wimg - 1; }
            } else {
                const int c2 = rank - Ni - Ne;
                hh = (c2 & 2) ? (Himg - 1) : 0;
                ww = (c2 & 1) ? (Wimg - 1) : 0;
            }
            m0 = ((hh * Wimg + ww) * bps + bidx) * 128;
            n0 = nidx * NT;
        } else {
            m0 = blockIdx.x * 128;
            n0 = blockIdx.y * NT;
        }
    }

    const int s = m0 >> bshift;          // spatial index (0 for MLP)
    const int b0 = m0 & (Bc - 1);        // batch offset
    const int hh0 = s / Wimg, ww0 = s % Wimg;

    const int wave = tid >> 6;
    const int lane = tid & 63;
    const int mbase = (wave >> 1) * 64;
    const int nbase = (wave & 1) * (NT / 2);
    const int ln = lane & 15, qd = lane >> 4;

    const int srow = lane >> 2;                                // staging row in 16-slab
    const int sc = (((lane & 3) - ((srow >> 1) & 3)) & 3) * 8; // swizzled fetch chunk
    const int csel = ((qd + (ln >> 1)) & 3) * 8;               // swizzled read chunk

    // lane-constant staging offsets (elems)
    const int rowA = wave * 32 + srow;
    const int rowW = (NT == 128) ? (wave * 32 + srow) : (wave * 16 + srow);
    const int offA0 = rowA * ldA + sc;
    const int offA1 = offA0 + 16 * ldA;
    const int offW0 = rowW * ldW + sc;
    const int offW1 = offW0 + 16 * ldW;   // NT==128 only
    u16* const lA0 = &lsA[0][0] + wave * 1024;
    u16* const lW0 = (NT == 128) ? (&lsW[0][0] + wave * 1024) : (&lsW[0][0] + wave * 512);
    constexpr int LPAR_A = 128 * 32;      // parity stride (elems)
    constexpr int LPAR_W = NT * 32;

    // tap helpers (all wave-uniform)
    auto tapvalid = [&](int t) -> bool {
        if (T != 9) return true;
        const int hh = hh0 + t / 3 - 1, ww = ww0 + t % 3 - 1;
        return hh >= 0 && hh < Himg && ww >= 0 && ww < Wimg;
    };
    auto tapA = [&](int t) -> const u16* {
        int sp = s;
        if (T == 9) sp = (hh0 + t / 3 - 1) * Wimg + (ww0 + t % 3 - 1);
        return A + (long long)(sp * Bc + b0) * ldA;
    };

    int t0 = 0;
    while (!tapvalid(t0)) ++t0;
    int nvalid = 0;
    for (int t = 0; t < T; ++t) nvalid += tapvalid(t) ? 1 : 0;
    const int KS = Kin >> 5;
    const int S = nvalid * KS;

    const u16* Ab = tapA(t0);
    const u16* Wb = W + ((long long)t0 * N + n0) * ldW;

    // prologue: prefetch step 0 into parity 0
    gld16(Ab + offA0, lA0);
    gld16(Ab + offA1, lA0 + 512);
    gld16(Wb + offW0, lW0);
    if (NT == 128) gld16(Wb + offW1, lW0 + 512);

    int ntap = t0, nkk = 0;

    f32x4 acc[4][NJ];
#pragma unroll
    for (int i = 0; i < 4; ++i)
#pragma unroll
        for (int j = 0; j < NJ; ++j)
            acc[i][j] = (f32x4){0.f, 0.f, 0.f, 0.f};

    for (int st = 0; st < S; ++st) {
        __syncthreads();   // drains prefetch issued at st-1 (had full MFMA phase in flight)
        if (st + 1 < S) {
            nkk += 32;
            if (nkk == Kin) {
                nkk = 0;
                do { ++ntap; } while (!tapvalid(ntap));
                Ab = tapA(ntap);
                Wb = W + ((long long)ntap * N + n0) * ldW;
            }
            const int pp = (st + 1) & 1;
            gld16(Ab + offA0 + nkk, lA0 + pp * LPAR_A);
            gld16(Ab + offA1 + nkk, lA0 + pp * LPAR_A + 512);
            gld16(Wb + offW0 + nkk, lW0 + pp * LPAR_W);
            if (NT == 128) gld16(Wb + offW1 + nkk, lW0 + pp * LPAR_W + 512);
        }
        const int cp = st & 1;
        bf16x8 af[4], bfr[NJ];
#pragma unroll
        for (int f = 0; f < 4; ++f)
            af[f] = *(const bf16x8*)&lsA[cp][(mbase + f * 16 + ln) * 32 + csel];
#pragma unroll
        for (int f = 0; f < NJ; ++f)
            bfr[f] = *(const bf16x8*)&lsW[cp][(nbase + f * 16 + ln) * 32 + csel];
#pragma unroll
        for (int i = 0; i < 4; ++i)
#pragma unroll
            for (int j = 0; j < NJ; ++j)
                acc[i][j] = __builtin_amdgcn_mfma_f32_16x16x32_bf16(
                    af[i], bfr[j], acc[i][j], 0, 0, 0);
    }

#pragma unroll
    for (int j = 0; j < NJ; ++j) {
        const int n = n0 + nbase + j * 16 + ln;
        const float sh = epiB[n];
        float sc2 = 1.f;
        if (EPI == 0) sc2 = epiA[n];
#pragma unroll
        for (int i = 0; i < 4; ++i) {
            const int mrow = mbase + i * 16 + qd * 4;
#pragma unroll
            for (int rr = 0; rr < 4; ++rr) {
                float v = acc[i][j][rr];
                if (EPI == 0) v = fmaxf(v * sc2 + sh, 0.f);
                else          v = tanh_fast(v + sh);
                O[(long long)(m0 + mrow + rr) * ldO + n] = f2bf(v);
            }
        }
    }
}

// ---------------------------------------------------------------------------
// FUSED MLP (Linear->tanh, 5 n-tiles) + logits (600->10 via 640->16) +
// softmax (round 10 form, measured-best). One block = 128 batch rows x one
// node (z). Per n-tile: single-barrier pipelined K-loop computes a 128x128
// h-tile; epilogue applies tanh and writes bf16 into lsH[128][132]; then 4
// k-steps x 2 MFMA/wave accumulate the logits GEMM from lsH (B-frags hoisted
// before the barrier). After 5 tiles: shfl-softmax. LDS 66.3 KB.
// ---------------------------------------------------------------------------
template <int STAGE>
__global__ __launch_bounds__(256, 2) void mlp_head(
    const u16* __restrict__ A, const u16* __restrict__ W,
    const float* __restrict__ bap, const u16* __restrict__ Wbp,
    const float* __restrict__ bbp,
    u16* __restrict__ preds, float* __restrict__ dout,
    int Kin, int Bc, int gbase)
{
    __shared__ __align__(16) u16 lsA[2][128 * 32];
    __shared__ __align__(16) u16 lsW[2][128 * 32];
    __shared__ __align__(16) u16 lsH[128 * 132];

    const int tid = threadIdx.x;
    const int z = blockIdx.z;                 // node 0..24
    A += (long long)z * Bc * Kin;
    W += (long long)z * 640 * 352;
    const float* bz = bap + z * 640;

    const int m0 = blockIdx.x * 128;          // batch row base
    const int wave = tid >> 6;
    const int lane = tid & 63;
    const int mbase = (wave >> 1) * 64;
    const int nbase = (wave & 1) * 64;
    const int ln = lane & 15, qd = lane >> 4;
    const int srow = lane >> 2;
    const int sc = (((lane & 3) - ((srow >> 1) & 3)) & 3) * 8;
    const int csel = ((qd + (ln >> 1)) & 3) * 8;

    const int rowS = wave * 32 + srow;
    const int offA0 = rowS * Kin + sc;        // ldA = Kin
    const int offA1 = offA0 + 16 * Kin;
    const int offW0 = rowS * 352 + sc;        // ldW = 352
    const int offW1 = offW0 + 16 * 352;
    u16* const lA0 = &lsA[0][0] + wave * 1024;
    u16* const lW0 = &lsW[0][0] + wave * 1024;

    const int KS = Kin >> 5;                  // 8 (stage1) or 11 (stage2)
    const int Stot = 5 * KS;

    const u16* Ab = A + (long long)m0 * Kin;
    const u16* Wb = W;
    int pnt = 0, pnkk = 0;

    // prologue: prefetch flat step 0 into parity 0
    gld16(Ab + offA0, lA0);
    gld16(Ab + offA1, lA0 + 512);
    gld16(Wb + offW0, lW0);
    gld16(Wb + offW1, lW0 + 512);

    f32x4 acc[4][4];
#pragma unroll
    for (int i = 0; i < 4; ++i)
#pragma unroll
        for (int j = 0; j < 4; ++j)
            acc[i][j] = (f32x4){0.f, 0.f, 0.f, 0.f};
    f32x4 acc_lg[2];
    acc_lg[0] = (f32x4){0.f, 0.f, 0.f, 0.f};
    acc_lg[1] = (f32x4){0.f, 0.f, 0.f, 0.f};

    int g = 0;   // flat step index
    for (int nt = 0; nt < 5; ++nt) {
        for (int st = 0; st < KS; ++st, ++g) {
            __syncthreads();   // drains prefetch issued at g-1
            if (g + 1 < Stot) {
                pnkk += 32;
                if (pnkk == Kin) {   // next n-tile: K wraps, W column base advances
                    pnkk = 0;
                    ++pnt;
                    Wb = W + (long long)pnt * 128 * 352;
                }
                const int pp = (g + 1) & 1;
                gld16(Ab + offA0 + pnkk, lA0 + pp * (128 * 32));
                gld16(Ab + offA1 + pnkk, lA0 + pp * (128 * 32) + 512);
                gld16(Wb + offW0 + pnkk, lW0 + pp * (128 * 32));
                gld16(Wb + offW1 + pnkk, lW0 + pp * (128 * 32) + 512);
            }
            const int cp = g & 1;
            bf16x8 af[4], bfr[4];
#pragma unroll
            for (int f = 0; f < 4; ++f)
                af[f] = *(const bf16x8*)&lsA[cp][(mbase + f * 16 + ln) * 32 + csel];
#pragma unroll
            for (int f = 0; f < 4; ++f)
                bfr[f] = *(const bf16x8*)&lsW[cp][(nbase + f * 16 + ln) * 32 + csel];
#pragma unroll
            for (int i = 0; i < 4; ++i)
#pragma unroll
                for (int j = 0; j < 4; ++j)
                    acc[i][j] = __builtin_amdgcn_mfma_f32_16x16x32_bf16(
                        af[i], bfr[j], acc[i][j], 0, 0, 0);
        }

        // tile epilogue: tanh -> bf16 h-tile into LDS (no global write)
#pragma unroll
        for (int j = 0; j < 4; ++j) {
            const int hc = nbase + j * 16 + ln;          // local h-col 0..127
            const float sh = bz[nt * 128 + hc];
#pragma unroll
            for (int i = 0; i < 4; ++i) {
                const int br = mbase + i * 16 + qd * 4;  // batch row (local)
#pragma unroll
                for (int rr = 0; rr < 4; ++rr)
                    lsH[(br + rr) * 132 + hc] = f2bf(tanh_fast(acc[i][j][rr] + sh));
                acc[i][j] = (f32x4){0.f, 0.f, 0.f, 0.f};
            }
        }
        // hoist logits B-frags (global, L2-hot) before the barrier
        bf16x8 bfrg[4];
#pragma unroll
        for (int ks = 0; ks < 4; ++ks)
            bfrg[ks] = *(const bf16x8*)&Wbp[((long long)z * 16 + ln) * 640 +
                                            nt * 128 + ks * 32 + qd * 8];
        __syncthreads();   // all h writes visible (also drains next-tile prefetch)

        // logits partial GEMM: rows wave*32..+31, K = this tile's 128 h-cols
#pragma unroll
        for (int ks = 0; ks < 4; ++ks) {
#pragma unroll
            for (int i = 0; i < 2; ++i) {
                const int base = (wave * 32 + i * 16 + ln) * 132 + ks * 32 + qd * 8;
                const uint2 u0 = *(const uint2*)&lsH[base];
                const uint2 u1 = *(const uint2*)&lsH[base + 4];
                u32 w4[4] = {u0.x, u0.y, u1.x, u1.y};
                bf16x8 a8;
                __builtin_memcpy(&a8, w4, 16);
                acc_lg[i] = __builtin_amdgcn_mfma_f32_16x16x32_bf16(
                    a8, bfrg[ks], acc_lg[i], 0, 0, 0);
            }
        }
        // next tile's first MLP step barrier orders lsH reuse
    }

    // softmax over the 16-lane group (pad cols have bbp=-1e30 -> excluded)
    const float bias = bbp[z * 16 + ln];
#pragma unroll
    for (int i = 0; i < 2; ++i) {
#pragma unroll
        for (int rr = 0; rr < 4; ++rr) {
            const float v = acc_lg[i][rr] + bias;
            float mx = v;
#pragma unroll
            for (int mk = 1; mk < 16; mk <<= 1)
                mx = fmaxf(mx, __shfl_xor(mx, mk));
            const float e = __expf(v - mx);
            float ssum = e;
#pragma unroll
            for (int mk = 1; mk < 16; mk <<= 1)
                ssum += __shfl_xor(ssum, mk);
            const float p = e / ssum;
            const int row = m0 + wave * 32 + i * 16 + qd * 4 + rr;
            if (ln < 10) {
                if (STAGE == 1)
                    preds[((long long)z * Bc + row) * 10 + ln] = f2bf(p);
                else
                    dout[81920 + ((long long)z * 8192 + gbase + row) * 10 + ln] = p;
            }
        }
    }
}

// ---------------------------------------------------------------------------
// FUSED conv1 + BN + ReLU + maxpool3s2p1, v2 (round 8): NO LDS, NO BARRIERS.
// ---------------------------------------------------------------------------
__global__ __launch_bounds__(256) void conv1pool(
    const u16* __restrict__ xcol, const u16* __restrict__ W1t, u16* __restrict__ p1,
    const float* __restrict__ epiA, const float* __restrict__ epiB, int Bc)
{
    const int tid = threadIdx.x;
    const int wave = tid >> 6;
    const int lane = tid & 63;
    const int ln = lane & 15, qd = lane >> 4;

    const int b0 = blockIdx.x * 128;
    const int so = blockIdx.y;            // pooled spatial index 0..99
    const int ho = so / 10, wo = so % 10;

    const int mbase = (wave >> 1) * 64;
    const int nbase = (wave & 1) * 32;

    bf16x8 bfr[2];
#pragma unroll
    for (int j = 0; j < 2; ++j)
        bfr[j] = *(const bf16x8*)&W1t[(nbase + j * 16 + ln) * 32 + qd * 8];

    float sc2[2], sh[2];
#pragma unroll
    for (int j = 0; j < 2; ++j) {
        const int n = nbase + j * 16 + ln;
        sc2[j] = epiA[n];
        sh[j] = epiB[n];
    }

    f32x4 best[4][2];
#pragma unroll
    for (int i = 0; i < 4; ++i)
#pragma unroll
        for (int j = 0; j < 2; ++j)
            best[i][j] = (f32x4){0.f, 0.f, 0.f, 0.f};

#pragma unroll
    for (int st = 0; st < 9; ++st) {
        int hh = 2 * ho - 1 + st / 3;
        int ww = 2 * wo - 1 + st % 3;
        hh = hh < 0 ? 0 : (hh > 19 ? 19 : hh);
        ww = ww < 0 ? 0 : (ww > 19 ? 19 : ww);
        const u16* Ab = xcol + (long long)((hh * 20 + ww) * Bc + b0) * 32;

        bf16x8 af[4];
#pragma unroll
        for (int f = 0; f < 4; ++f)
            af[f] = *(const bf16x8*)&Ab[(mbase + f * 16 + ln) * 32 + qd * 8];

#pragma unroll
        for (int i = 0; i < 4; ++i)
#pragma unroll
            for (int j = 0; j < 2; ++j) {
                f32x4 acc = (f32x4){0.f, 0.f, 0.f, 0.f};
                acc = __builtin_amdgcn_mfma_f32_16x16x32_bf16(af[i], bfr[j], acc, 0, 0, 0);
#pragma unroll
                for (int rr = 0; rr < 4; ++rr) {
                    const float v = fmaxf(acc[rr] * sc2[j] + sh[j], 0.f);
                    best[i][j][rr] = fmaxf(best[i][j][rr], v);
                }
            }
    }

#pragma unroll
    for (int j = 0; j < 2; ++j) {
        const int n = nbase + j * 16 + ln;
#pragma unroll
        for (int i = 0; i < 4; ++i) {
            const int mrow = mbase + i * 16 + qd * 4;
#pragma unroll
            for (int rr = 0; rr < 4; ++rr)
                p1[(long long)(so * Bc + b0 + mrow + rr) * 64 + n] = f2bf(best[i][j][rr]);
        }
    }
}

// ---------------------------------------------------------------------------
// x chunk [Bc,3,20,20] fp32 -> xt [400][Bc][4] bf16 (ch padded to 4, pad=0)
// ---------------------------------------------------------------------------
__global__ __launch_bounds__(256) void transpose_x(
    const float* __restrict__ x, u16* __restrict__ xt, int Bc, int bshift)
{
    const int t = blockIdx.x * 256 + threadIdx.x;
    if (t >= 400 * Bc) return;
    const int s = t >> bshift;
    const int b = t & (Bc - 1);
    const u32 c0 = f2bf(x[((long long)b * 3 + 0) * 400 + s]);
    const u32 c1 = f2bf(x[((long long)b * 3 + 1) * 400 + s]);
    const u32 c2 = f2bf(x[((long long)b * 3 + 2) * 400 + s]);
    uint2 st;
    st.x = c0 | (c1 << 16);
    st.y = c2;                              // high 16 = 0 pad
    *(uint2*)(xt + ((long long)s * Bc + b) * 4) = st;
}

// ---------------------------------------------------------------------------
// im2col for conv1: xt[400][Bc][4] -> xcol[400][Bc][32] (k = tap*3+ci, pad 0).
// ---------------------------------------------------------------------------
__global__ __launch_bounds__(256) void im2col1(
    const u16* __restrict__ xt, u16* __restrict__ xcol, int Bc, int bshift)
{
    const int t = blockIdx.x * 256 + threadIdx.x;
    if (t >= 400 * Bc) return;
    const int s = t >> bshift;
    const int b = t & (Bc - 1);
    const int hh = s / 20, ww = s % 20;

    u32 p0, q0, p1, q1, p2, q2, p3, q3, p4, q4, p5, q5, p6, q6, p7, q7, p8, q8;
#define LOADTAP(T, P, Q)                                                      \
    {                                                                         \
        const int ih = hh + (T) / 3 - 1, iw = ww + (T) % 3 - 1;               \
        P = 0u; Q = 0u;                                                       \
        if (ih >= 0 && ih < 20 && iw >= 0 && iw < 20) {                       \
            const uint2 v = *(const uint2*)(xt +                              \
                ((long long)(ih * 20 + iw) * Bc + b) * 4);                    \
            P = v.x; Q = v.y;                                                 \
        }                                                                     \
    }
    LOADTAP(0, p0, q0) LOADTAP(1, p1, q1) LOADTAP(2, p2, q2)
    LOADTAP(3, p3, q3) LOADTAP(4, p4, q4) LOADTAP(5, p5, q5)
    LOADTAP(6, p6, q6) LOADTAP(7, p7, q7) LOADTAP(8, p8, q8)
#undef LOADTAP

    u16* o = xcol + (long long)t * 32;
    uint4 w;
    w.x = p0;                w.y = q0 | (p1 << 16);
    w.z = (p1 >> 16) | (q1 << 16);
    w.w = p2;
    *(uint4*)(o + 0) = w;
    w.x = q2 | (p3 << 16);   w.y = (p3 >> 16) | (q3 << 16);
    w.z = p4;                w.w = q4 | (p5 << 16);
    *(uint4*)(o + 8) = w;
    w.x = (p5 >> 16) | (q5 << 16);
    w.y = p6;                w.z = q6 | (p7 << 16);
    w.w = (p7 >> 16) | (q7 << 16);
    *(uint4*)(o + 16) = w;
    w.x = p8;                w.y = q8;   // k=24..26 (+pad)
    w.z = 0u;                w.w = 0u;
    *(uint4*)(o + 24) = w;
}

// ---------------------------------------------------------------------------
// maxpool 3x3 s2 p1, square maps: src[Hi*Hi][Bc][CH] -> dst[Ho*Ho][Bc][CH].
// ---------------------------------------------------------------------------
template <int CH>
__global__ __launch_bounds__(256) void pool_k(
    const u16* __restrict__ src, u16* __restrict__ dst, int Bc, int Hi, int Ho)
{
    constexpr int G = CH / 8;
    const int t = blockIdx.x * 256 + threadIdx.x;
    const int cc = t & (G - 1);
    const int b = t / G;
    if (b >= Bc) return;
    const int so = blockIdx.y;
    const int ho = so / Ho, wo = so % Ho;
    float best[8];
#pragma unroll
    for (int e = 0; e < 8; ++e) best[e] = 0.f;
    for (int ph = 0; ph < 3; ++ph) {
        const int hh = 2 * ho - 1 + ph;
        if (hh < 0 || hh >= Hi) continue;
        for (int pw = 0; pw < 3; ++pw) {
            const int ww = 2 * wo - 1 + pw;
            if (ww < 0 || ww >= Hi) continue;
            const uint4 u = *(const uint4*)(src + ((long long)(hh * Hi + ww) * Bc + b) * CH + cc * 8);
            const u32 uw[4] = {u.x, u.y, u.z, u.w};
#pragma unroll
            for (int e = 0; e < 4; ++e) {
                best[2 * e]     = fmaxf(best[2 * e],     bf2f((u16)(uw[e] & 0xffff)));
                best[2 * e + 1] = fmaxf(best[2 * e + 1], bf2f((u16)(uw[e] >> 16)));
            }
        }
    }
    u32 pk[4];
#pragma unroll
    for (int e = 0; e < 4; ++e)
        pk[e] = (u32)f2bf(best[2 * e]) | (((u32)f2bf(best[2 * e + 1])) << 16);
    uint4 st;
    st.x = pk[0]; st.y = pk[1]; st.z = pk[2]; st.w = pk[3];
    *(uint4*)(dst + ((long long)so * Bc + b) * CH + cc * 8) = st;
}

// ---------------------------------------------------------------------------
// Stage-2 input assembly.
// ---------------------------------------------------------------------------
__device__ __forceinline__ void neighbors5x5(int i, int* nb) {
    const int w = 5, size = 25;
    int cnt = 0;
    if (i - w >= 0) nb[cnt++] = i - w;
    if (i % w != 0) nb[cnt++] = i - 1;
    if ((i + 1) % w != 0) nb[cnt++] = i + 1;
    if (i + w < size) nb[cnt++] = i + w;
    if (i - w - 1 >= 0 && i % w != 0) nb[cnt++] = i - w - 1;
    if (i - w + 1 >= 0 && (i + 1) % w != 0) nb[cnt++] = i - w + 1;
    if (i + w - 1 < size && i % w != 0) nb[cnt++] = i + w - 1;
    if (i + w + 1 < size && (i + 1) % w != 0) nb[cnt++] = i + w + 1;
    for (; cnt < 8; ++cnt) nb[cnt] = -1;
}

__global__ __launch_bounds__(256) void gather_nb(
    const u16* __restrict__ preds, const u16* __restrict__ feats, u16* __restrict__ A2,
    int Bc, int bshift)
{
    const int g = blockIdx.x * 256 + threadIdx.x;  // n*Bc+b
    if (g >= 25 * Bc) return;
    const int n = g >> bshift;
    const int b = g & (Bc - 1);
    int nb[8];
    neighbors5x5(n, nb);
    u16* dst = A2 + (long long)g * 352;
#pragma unroll
    for (int j = 0; j < 8; ++j) {
        u32* d32 = (u32*)(dst + j * 10);
        if (nb[j] >= 0) {
            const u32* s32 = (const u32*)(preds + ((long long)nb[j] * Bc + b) * 10);
#pragma unroll
            for (int q = 0; q < 5; ++q) d32[q] = s32[q];
        } else {
#pragma unroll
            for (int q = 0; q < 5; ++q) d32[q] = 0u;
        }
    }
    const uint4* fs = (const uint4*)(feats + (long long)g * 256);
    uint4* fd = (uint4*)(dst + 80);
#pragma unroll
    for (int q = 0; q < 32; ++q) fd[q] = fs[q];
    uint4 z;
    z.x = 0u; z.y = 0u; z.z = 0u; z.w = 0u;
    *(uint4*)(dst + 336) = z;
    *(uint4*)(dst + 344) = z;
}

__global__ __launch_bounds__(256) void mean_k(float* __restrict__ dout)
{
    const int t = blockIdx.x * 256 + threadIdx.x;
    float s = 0.f;
#pragma unroll
    for (int n = 0; n < 25; ++n) s += dout[81920 + n * 81920 + t];
    dout[t] = s * 0.04f;
}

// ---------------------------------------------------------------------------
// Weight/param prep (once per launch)
// ---------------------------------------------------------------------------
__global__ void prep_bn_all(
    const float* b1, const float* g1, const float* be1, const float* m1, const float* v1,
    const float* b2, const float* g2, const float* be2, const float* m2, const float* v2,
    const float* b3, const float* g3, const float* be3, const float* m3, const float* v3,
    const float* b4, const float* g4, const float* be4, const float* m4, const float* v4,
    float* bnA, float* bnB)
{
    const int t = blockIdx.x * 256 + threadIdx.x;
    if (t >= 704) return;
    const float *bp, *gp, *bep, *mp, *vp;
    int idx;
    if (t < 64)       { bp=b1; gp=g1; bep=be1; mp=m1; vp=v1; idx=t; }
    else if (t < 192) { bp=b2; gp=g2; bep=be2; mp=m2; vp=v2; idx=t-64; }
    else if (t < 448) { bp=b3; gp=g3; bep=be3; mp=m3; vp=v3; idx=t-192; }
    else              { bp=b4; gp=g4; bep=be4; mp=m4; vp=v4; idx=t-448; }
    const float A = gp[idx] * rsqrtf(vp[idx] + 1e-5f);
    bnA[t] = A;
    bnB[t] = (bp[idx] - mp[idx]) * A + bep[idx];
}

// W1 [64][3][3][3] -> W1t [64][32], k = tap*3+ci (tap = kh*3+kw), pad 0
__global__ void prep_w1col(const float* __restrict__ W1, u16* __restrict__ W1t)
{
    const int t = blockIdx.x * 256 + threadIdx.x;
    if (t >= 64 * 32) return;
    const int n = t >> 5, k = t & 31;
    u16 v = 0;
    if (k < 27) {
        const int tap = k / 3, ci = k % 3;
        v = f2bf(W1[n * 27 + ci * 9 + tap]);
    }
    W1t[t] = v;
}

// W [Co][Ci][3][3] fp32 -> Wt [9][Co][Ci] bf16
__global__ void prep_convw(const float* __restrict__ W, u16* __restrict__ Wt, int Co, int Ci)
{
    const int t = blockIdx.x * 256 + threadIdx.x;
    const int tot = 9 * Co * Ci;
    if (t >= tot) return;
    const int sh = t / (Co * Ci);
    const int rem = t % (Co * Ci);
    const int co = rem / Ci, ci = rem % Ci;
    Wt[t] = f2bf(W[(long long)(co * Ci + ci) * 9 + sh]);
}

__global__ void prep_wat(const float* __restrict__ Wa, u16* __restrict__ Wat)
{
    const int t = blockIdx.x * 256 + threadIdx.x;
    if (t >= 25 * 640 * 352) return;
    const int n = t / (640 * 352);
    const int rem = t % (640 * 352);
    const int hcol = rem / 352;
    const int k = rem % 352;
    float v = 0.f;
    if (hcol < 600 && k < 336) v = Wa[((long long)n * 336 + k) * 600 + hcol];
    Wat[t] = f2bf(v);
}

__global__ void prep_ba(const float* __restrict__ ba, float* __restrict__ bap)
{
    const int t = blockIdx.x * 256 + threadIdx.x;
    if (t >= 25 * 640) return;
    const int n = t / 640, hcol = t % 640;
    bap[t] = (hcol < 600) ? ba[n * 600 + hcol] : 0.f;
}

// Wb [25][600][10] fp32 -> Wbp [25][16][640] bf16 (transposed, zero-pad);
// bb [25][10] -> bbp [25][16] fp32 (pad -1e30 so softmax ignores pad cols)
__global__ void prep_wbt(const float* __restrict__ Wb, const float* __restrict__ bb,
                         u16* __restrict__ Wbp, float* __restrict__ bbp)
{
    const int t = blockIdx.x * 256 + threadIdx.x;
    if (t < 25 * 16 * 640) {
        const int n = t / (16 * 640);
        const int rem = t % (16 * 640);
        const int c = rem / 640, k = rem % 640;
        u16 v = 0;
        if (c < 10 && k < 600) v = f2bf(Wb[((long long)n * 600 + k) * 10 + c]);
        Wbp[t] = v;
    }
    if (t < 25 * 16) {
        const int n = t >> 4, c = t & 15;
        bbp[t] = (c < 10) ? bb[n * 10 + c] : -1e30f;
    }
}

// ---------------------------------------------------------------------------
extern "C" void kernel_launch(void* const* d_in, const int* in_sizes, int n_in,
                              void* d_out, int out_size, void* d_ws, size_t ws_size,
                              hipStream_t stream)
{
    (void)in_sizes; (void)n_in; (void)out_size;

    const float* x  = (const float*)d_in[0];
    const float* W1 = (const float*)d_in[1];
    const float* b1 = (const float*)d_in[2];
    const float* g1 = (const float*)d_in[3];
    const float* be1= (const float*)d_in[4];
    const float* m1 = (const float*)d_in[5];
    const float* v1 = (const float*)d_in[6];
    const float* W2 = (const float*)d_in[7];
    const float* b2 = (const float*)d_in[8];
    const float* g2 = (const float*)d_in[9];
    const float* be2= (const float*)d_in[10];
    const float* m2 = (const float*)d_in[11];
    const float* v2 = (const float*)d_in[12];
    const float* W3 = (const float*)d_in[13];
    const float* b3 = (const float*)d_in[14];
    const float* g3 = (const float*)d_in[15];
    const float* be3= (const float*)d_in[16];
    const float* m3 = (const float*)d_in[17];
    const float* v3 = (const float*)d_in[18];
    const float* W4 = (const float*)d_in[19];
    const float* b4 = (const float*)d_in[20];
    const float* g4 = (const float*)d_in[21];
    const float* be4= (const float*)d_in[22];
    const float* m4 = (const float*)d_in[23];
    const float* v4 = (const float*)d_in[24];
    const float* Wa = (const float*)d_in[25];
    const float* ba = (const float*)d_in[26];
    const float* Wb = (const float*)d_in[27];
    const float* bb = (const float*)d_in[28];
    float* dout = (float*)d_out;

    // ---- choose Bc: overlay peak = 44032 bytes per batch element ----
    auto al = [](long long v) { return (v + 255LL) & ~255LL; };
    const long long fixedB = al(4096) + al(147456) + al(589824) + al(1179648) +
                             al(11264000) + al(64000) + al(2816) + al(2816) +
                             al(512000) + al(1600);
    int Bc = 256;
    for (int cand = 8192; cand >= 256; cand >>= 1) {
        long long need = fixedB + al(44032LL * cand);
        if (need <= (long long)ws_size) { Bc = cand; break; }
    }
    const int bshift = __builtin_ctz((unsigned)Bc);
    const int C = 8192 / Bc;

    // ---- workspace: fixed region + one overlaid chunk region ----
    char* wsp = (char*)d_ws;
    long long off = 0;
    auto alloc = [&](long long bytes) { long long o = off; off += al(bytes); return o; };
    u16* W1t  = (u16*)(wsp + alloc(4096));
    u16* Wt2  = (u16*)(wsp + alloc(147456));
    u16* Wt3  = (u16*)(wsp + alloc(589824));
    u16* Wt4  = (u16*)(wsp + alloc(1179648));
    u16* Wat  = (u16*)(wsp + alloc(11264000));
    float* bap = (float*)(wsp + alloc(64000));
    float* bnA = (float*)(wsp + alloc(2816));
    float* bnB = (float*)(wsp + alloc(2816));
    u16* Wbp  = (u16*)(wsp + alloc(512000));
    float* bbp = (float*)(wsp + alloc(1600));
    char* ch = wsp + alloc(44032LL * Bc);
    // overlay (bytes-per-elem offsets; lifetimes disjoint where ranges overlap):
    u16* xt   = (u16*)(ch + 0LL     * Bc);   // [0,3200)       t1-t1.5
    u16* xcol = (u16*)(ch + 3200LL  * Bc);   // [3200,28800)   t1.5-t2
    u16* p1   = (u16*)(ch + 28800LL * Bc);   // [28800,41600)  t2-t3
    u16* a2   = (u16*)(ch + 0LL     * Bc);   // [0,25600)      t3-t3.5
    u16* p2   = (u16*)(ch + 25600LL * Bc);   // [25600,32000)  t3.5-t4
    u16* a3   = (u16*)(ch + 0LL     * Bc);   // [0,12800)      t4-t5
    u16* a4   = (u16*)(ch + 12800LL * Bc);   // [12800,25600)  t5-t8
    u16* preds= (u16*)(ch + 25600LL * Bc);   // [25600,26112)  t6-t7
    u16* A2   = (u16*)(ch + 26112LL * Bc);   // [26112,43712)  t7-t8

    // ---- prep (once) ----
    prep_bn_all<<<dim3(3), 256, 0, stream>>>(b1,g1,be1,m1,v1, b2,g2,be2,m2,v2,
                                             b3,g3,be3,m3,v3, b4,g4,be4,m4,v4, bnA, bnB);
    prep_w1col<<<dim3(8), 256, 0, stream>>>(W1, W1t);
    prep_convw<<<dim3(288),  256, 0, stream>>>(W2, Wt2, 128, 64);
    prep_convw<<<dim3(1152), 256, 0, stream>>>(W3, Wt3, 256, 128);
    prep_convw<<<dim3(2304), 256, 0, stream>>>(W4, Wt4, 256, 256);
    prep_wat<<<dim3(22000), 256, 0, stream>>>(Wa, Wat);
    prep_ba<<<dim3(63), 256, 0, stream>>>(ba, bap);
    prep_wbt<<<dim3(1000), 256, 0, stream>>>(Wb, bb, Wbp, bbp);

    // ---- batch chunks ----
    for (int c = 0; c < C; ++c) {
        const float* xc = x + (long long)c * Bc * 1200;

        transpose_x<<<dim3(400 * Bc / 256), 256, 0, stream>>>(xc, xt, Bc, bshift);
        im2col1<<<dim3(400 * Bc / 256), 256, 0, stream>>>(xt, xcol, Bc, bshift);
        conv1pool<<<dim3(Bc / 128, 100), 256, 0, stream>>>(xcol, W1t, p1, bnA, bnB, Bc);

        gemm_bt<0,128><<<dim3(100 * Bc / 128, 1), 256, 0, stream>>>(p1, Wt2, a2, bnA + 64, bnB + 64,
            64, 128, 9, 10, 10, 64, 64, 128, 0LL, 0LL, 0LL, 0, Bc, bshift);
        pool_k<128><<<dim3(Bc * 16 / 256, 25), 256, 0, stream>>>(a2, p2, Bc, 10, 5);

        gemm_bt<0,128><<<dim3(25 * Bc / 128, 2), 256, 0, stream>>>(p2, Wt3, a3, bnA + 192, bnB + 192,
            128, 256, 9, 5, 5, 128, 128, 256, 0LL, 0LL, 0LL, 0, Bc, bshift);
        gemm_bt<0,128><<<dim3(25 * Bc / 128, 2), 256, 0, stream>>>(a3, Wt4, a4, bnA + 448, bnB + 448,
            256, 256, 9, 5, 5, 256, 256, 256, 0LL, 0LL, 0LL, 0, Bc, bshift);

        // stage 1: fused MLP+tanh+logits+softmax (zeros||feats -> Wa k-rows [80:336))
        mlp_head<1><<<dim3(Bc / 128, 1, 25), 256, 0, stream>>>(
            a4, Wat + 80, bap, Wbp, bbp, preds, nullptr, 256, Bc, 0);

        // stage 2
        gather_nb<<<dim3(25 * Bc / 256, 1), 256, 0, stream>>>(preds, a4, A2, Bc, bshift);
        mlp_head<2><<<dim3(Bc / 128, 1, 25), 256, 0, stream>>>(
            A2, Wat, bap, Wbp, bbp, nullptr, dout, 352, Bc, c * Bc);
    }

    mean_k<<<dim3(320), 256, 0, stream>>>(dout);
}

// Round 15
// 1355.515 us; speedup vs baseline: 1.1742x; 1.0163x over previous
//
#include <hip/hip_runtime.h>

typedef unsigned short u16;
typedef unsigned int u32;

typedef __attribute__((ext_vector_type(8))) __bf16 bf16x8;
typedef __attribute__((ext_vector_type(4))) float f32x4;

__device__ __forceinline__ float bf2f(u16 u) {
    u32 t = ((u32)u) << 16;
    float f;
    __builtin_memcpy(&f, &t, 4);
    return f;
}
__device__ __forceinline__ u16 f2bf(float f) {
    u32 u;
    __builtin_memcpy(&u, &f, 4);
    u32 r = (u + 0x7fffu + ((u >> 16) & 1u)) >> 16;
    return (u16)r;
}
__device__ __forceinline__ float tanh_fast(float x) {
    float xc = fminf(fmaxf(x, -15.f), 15.f);
    float e = __expf(2.f * xc);
    return (e - 1.f) * __builtin_amdgcn_rcpf(e + 1.f);
}

// Async global->LDS DMA, 16B per lane. LDS dest = wave-uniform base + lane*16.
__device__ __forceinline__ void gld16(const u16* g, u16* l) {
    __builtin_amdgcn_global_load_lds(
        (const __attribute__((address_space(1))) u32*)(uintptr_t)g,
        (__attribute__((address_space(3))) u32*)(u32)(uintptr_t)l,
        16, 0, 0);
}

// HISTORY (journal):
// - R8: XCD "contiguous chunk" swizzle on CONVS REVERTED — FETCH 188->308 MB.
//   Conv same-b0 A-sharers sit at multiples of 8; default id%8 round-robin
//   already co-locates them on one XCD L2.
// - R9: mlp_head lsH-chunking REVERTED — 1398->1481 us (grid/tail-bound).
// - R14: R12 conv dispatch remap MEASURED: total 1435->1377.6 us. Conv FETCH
//   188->127 MB (n-pair A-slab L2 reuse confirmed), dur 129->121 us,
//   MfmaUtil 32.5% (approaching m97-structure ceiling; HBM only 21%).
// - R15 (this): mlp_head XCD z-chunk remap. mlp blocks share NO A data (each
//   owns distinct batch rows) — only the 450 KB/node W panel among same-z
//   blocks. Default round-robin spreads each z across all 8 XCDs (~16
//   concurrent nodes x 450 KB = 7.2 MB > 4 MB L2 -> thrash; FETCH 234 MB vs
//   ~85 ideal). Contiguous z-major chunk per XCD (lin2=(d&7)*(nblk/8)+(d>>3))
//   gives each XCD ~3.1 nodes (~1.4 MB W, L2-fits), same-z temporally
//   adjacent. Bijective for nblk%8==0; identity fallback. Output-neutral.

// LDS bank swizzle (round 5, kept): chunk c (16B) of row r staged into slot
// (c + (r>>1)) & 3; consumer reads chunk qd of row R at (qd + (R>>1)) & 3.
// Verified round 5: SQ_LDS_BANK_CONFLICT 5.5M -> 0.

// ---------------------------------------------------------------------------
// bf16 MFMA GEMM, tile 128 x NT, SINGLE-BARRIER PIPELINED K-LOOP (round 6),
// + R12 dispatch-order remap (measured WIN).
// A: [spatial][Bc][ldA] (k-contiguous). W: [T][N][ldW]. T==9 -> 3x3 conv via
// shift-GEMM. EPI 0: relu(acc*epiA[n]+epiB[n]); EPI 1: tanh(acc+epiB[n]).
// ---------------------------------------------------------------------------
template <int EPI, int NT>
__global__ __launch_bounds__(256, 3) void gemm_bt(
    const u16* __restrict__ A, const u16* __restrict__ W, u16* __restrict__ O,
    const float* __restrict__ epiA, const float* __restrict__ epiB,
    int Kin, int N, int T, int Himg, int Wimg,
    int ldA, int ldW, int ldO,
    long long Az, long long Wz, long long Oz, int epiZ,
    int Bc, int bshift)
{
    constexpr int NJ = NT / 32;          // 4 (NT=128) or 2 (NT=64)
    __shared__ __align__(16) u16 lsA[2][128 * 32];
    __shared__ __align__(16) u16 lsW[2][NT * 32];

    const int tid = threadIdx.x;
    const int z = blockIdx.z;
    A += (long long)z * Az;
    W += (long long)z * Wz;
    O += (long long)z * Oz;
    epiB += (long long)z * epiZ;

    // ---- R12 dispatch-order remap (conv path; identity fallback) ----
    int m0, n0;
    {
        const int bps = Bc >> 7;                  // 128-row blocks per spatial pos
        if (T == 9 && (bps & 7) == 0) {
            const int d = blockIdx.x + gridDim.x * blockIdx.y;  // dispatch index
            int pairid, nidx;
            if (gridDim.y == 2) {
                // n-pair interleave at stride 8: d = g*16 + nidx*8 + sub
                nidx = (d >> 3) & 1;
                pairid = ((d >> 4) << 3) | (d & 7);
            } else {
                pairid = d;
                nidx = 0;
            }
            const int rank = pairid >> (bshift - 7);   // /bps
            const int bidx = pairid & (bps - 1);
            // rank -> spatial pos, longest-first: interior, edges, corners
            const int Hm2 = Himg - 2, Wm2 = Wimg - 2;
            const int Ni = Hm2 * Wm2;
            const int Ne = 2 * Wm2 + 2 * Hm2;
            int hh, ww;
            if (rank < Ni) {
                hh = 1 + rank / Wm2;
                ww = 1 + rank % Wm2;
            } else if (rank < Ni + Ne) {
                const int e = rank - Ni;
                if (e < Wm2)                 { hh = 0;                     ww = 1 + e; }
                else if (e < 2 * Wm2)        { hh = Himg - 1;              ww = 1 + e - Wm2; }
                else if (e < 2 * Wm2 + Hm2)  { hh = 1 + e - 2 * Wm2;       ww = 0; }
                else                         { hh = 1 + e - 2 * Wm2 - Hm2; ww = Wimg - 1; }
            } else {
                const int c2 = rank - Ni - Ne;
                hh = (c2 & 2) ? (Himg - 1) : 0;
                ww = (c2 & 1) ? (Wimg - 1) : 0;
            }
            m0 = ((hh * Wimg + ww) * bps + bidx) * 128;
            n0 = nidx * NT;
        } else {
            m0 = blockIdx.x * 128;
            n0 = blockIdx.y * NT;
        }
    }

    const int s = m0 >> bshift;          // spatial index (0 for MLP)
    const int b0 = m0 & (Bc - 1);        // batch offset
    const int hh0 = s / Wimg, ww0 = s % Wimg;

    const int wave = tid >> 6;
    const int lane = tid & 63;
    const int mbase = (wave >> 1) * 64;
    const int nbase = (wave & 1) * (NT / 2);
    const int ln = lane & 15, qd = lane >> 4;

    const int srow = lane >> 2;                                // staging row in 16-slab
    const int sc = (((lane & 3) - ((srow >> 1) & 3)) & 3) * 8; // swizzled fetch chunk
    const int csel = ((qd + (ln >> 1)) & 3) * 8;               // swizzled read chunk

    // lane-constant staging offsets (elems)
    const int rowA = wave * 32 + srow;
    const int rowW = (NT == 128) ? (wave * 32 + srow) : (wave * 16 + srow);
    const int offA0 = rowA * ldA + sc;
    const int offA1 = offA0 + 16 * ldA;
    const int offW0 = rowW * ldW + sc;
    const int offW1 = offW0 + 16 * ldW;   // NT==128 only
    u16* const lA0 = &lsA[0][0] + wave * 1024;
    u16* const lW0 = (NT == 128) ? (&lsW[0][0] + wave * 1024) : (&lsW[0][0] + wave * 512);
    constexpr int LPAR_A = 128 * 32;      // parity stride (elems)
    constexpr int LPAR_W = NT * 32;

    // tap helpers (all wave-uniform)
    auto tapvalid = [&](int t) -> bool {
        if (T != 9) return true;
        const int hh = hh0 + t / 3 - 1, ww = ww0 + t % 3 - 1;
        return hh >= 0 && hh < Himg && ww >= 0 && ww < Wimg;
    };
    auto tapA = [&](int t) -> const u16* {
        int sp = s;
        if (T == 9) sp = (hh0 + t / 3 - 1) * Wimg + (ww0 + t % 3 - 1);
        return A + (long long)(sp * Bc + b0) * ldA;
    };

    int t0 = 0;
    while (!tapvalid(t0)) ++t0;
    int nvalid = 0;
    for (int t = 0; t < T; ++t) nvalid += tapvalid(t) ? 1 : 0;
    const int KS = Kin >> 5;
    const int S = nvalid * KS;

    const u16* Ab = tapA(t0);
    const u16* Wb = W + ((long long)t0 * N + n0) * ldW;

    // prologue: prefetch step 0 into parity 0
    gld16(Ab + offA0, lA0);
    gld16(Ab + offA1, lA0 + 512);
    gld16(Wb + offW0, lW0);
    if (NT == 128) gld16(Wb + offW1, lW0 + 512);

    int ntap = t0, nkk = 0;

    f32x4 acc[4][NJ];
#pragma unroll
    for (int i = 0; i < 4; ++i)
#pragma unroll
        for (int j = 0; j < NJ; ++j)
            acc[i][j] = (f32x4){0.f, 0.f, 0.f, 0.f};

    for (int st = 0; st < S; ++st) {
        __syncthreads();   // drains prefetch issued at st-1 (had full MFMA phase in flight)
        if (st + 1 < S) {
            nkk += 32;
            if (nkk == Kin) {
                nkk = 0;
                do { ++ntap; } while (!tapvalid(ntap));
                Ab = tapA(ntap);
                Wb = W + ((long long)ntap * N + n0) * ldW;
            }
            const int pp = (st + 1) & 1;
            gld16(Ab + offA0 + nkk, lA0 + pp * LPAR_A);
            gld16(Ab + offA1 + nkk, lA0 + pp * LPAR_A + 512);
            gld16(Wb + offW0 + nkk, lW0 + pp * LPAR_W);
            if (NT == 128) gld16(Wb + offW1 + nkk, lW0 + pp * LPAR_W + 512);
        }
        const int cp = st & 1;
        bf16x8 af[4], bfr[NJ];
#pragma unroll
        for (int f = 0; f < 4; ++f)
            af[f] = *(const bf16x8*)&lsA[cp][(mbase + f * 16 + ln) * 32 + csel];
#pragma unroll
        for (int f = 0; f < NJ; ++f)
            bfr[f] = *(const bf16x8*)&lsW[cp][(nbase + f * 16 + ln) * 32 + csel];
#pragma unroll
        for (int i = 0; i < 4; ++i)
#pragma unroll
            for (int j = 0; j < NJ; ++j)
                acc[i][j] = __builtin_amdgcn_mfma_f32_16x16x32_bf16(
                    af[i], bfr[j], acc[i][j], 0, 0, 0);
    }

#pragma unroll
    for (int j = 0; j < NJ; ++j) {
        const int n = n0 + nbase + j * 16 + ln;
        const float sh = epiB[n];
        float sc2 = 1.f;
        if (EPI == 0) sc2 = epiA[n];
#pragma unroll
        for (int i = 0; i < 4; ++i) {
            const int mrow = mbase + i * 16 + qd * 4;
#pragma unroll
            for (int rr = 0; rr < 4; ++rr) {
                float v = acc[i][j][rr];
                if (EPI == 0) v = fmaxf(v * sc2 + sh, 0.f);
                else          v = tanh_fast(v + sh);
                O[(long long)(m0 + mrow + rr) * ldO + n] = f2bf(v);
            }
        }
    }
}

// ---------------------------------------------------------------------------
// FUSED MLP (Linear->tanh, 5 n-tiles) + logits (600->10 via 640->16) +
// softmax (round 10 form) + R15 XCD z-chunk remap: each XCD gets a contiguous
// z-major chunk of blocks so the 450 KB/node W panel stays L2-resident
// (~3.1 nodes/XCD = ~1.4 MB). mlp blocks share no A data, so unlike the
// convs (R8) contiguous chunking is safe here. Output-neutral permutation.
// ---------------------------------------------------------------------------
template <int STAGE>
__global__ __launch_bounds__(256, 2) void mlp_head(
    const u16* __restrict__ A, const u16* __restrict__ W,
    const float* __restrict__ bap, const u16* __restrict__ Wbp,
    const float* __restrict__ bbp,
    u16* __restrict__ preds, float* __restrict__ dout,
    int Kin, int Bc, int gbase)
{
    __shared__ __align__(16) u16 lsA[2][128 * 32];
    __shared__ __align__(16) u16 lsW[2][128 * 32];
    __shared__ __align__(16) u16 lsH[128 * 132];

    const int tid = threadIdx.x;

    // ---- R15 XCD z-chunk remap (identity fallback) ----
    int z, m0;
    {
        const int nblk = gridDim.x * 25;
        const int d = blockIdx.x + gridDim.x * blockIdx.z;   // dispatch index
        if ((nblk & 7) == 0) {
            const int lin2 = (d & 7) * (nblk >> 3) + (d >> 3);
            z = lin2 / gridDim.x;
            m0 = (lin2 % gridDim.x) * 128;
        } else {
            z = blockIdx.z;
            m0 = blockIdx.x * 128;
        }
    }

    A += (long long)z * Bc * Kin;
    W += (long long)z * 640 * 352;
    const float* bz = bap + z * 640;

    const int wave = tid >> 6;
    const int lane = tid & 63;
    const int mbase = (wave >> 1) * 64;
    const int nbase = (wave & 1) * 64;
    const int ln = lane & 15, qd = lane >> 4;
    const int srow = lane >> 2;
    const int sc = (((lane & 3) - ((srow >> 1) & 3)) & 3) * 8;
    const int csel = ((qd + (ln >> 1)) & 3) * 8;

    const int rowS = wave * 32 + srow;
    const int offA0 = rowS * Kin + sc;        // ldA = Kin
    const int offA1 = offA0 + 16 * Kin;
    const int offW0 = rowS * 352 + sc;        // ldW = 352
    const int offW1 = offW0 + 16 * 352;
    u16* const lA0 = &lsA[0][0] + wave * 1024;
    u16* const lW0 = &lsW[0][0] + wave * 1024;

    const int KS = Kin >> 5;                  // 8 (stage1) or 11 (stage2)
    const int Stot = 5 * KS;

    const u16* Ab = A + (long long)m0 * Kin;
    const u16* Wb = W;
    int pnt = 0, pnkk = 0;

    // prologue: prefetch flat step 0 into parity 0
    gld16(Ab + offA0, lA0);
    gld16(Ab + offA1, lA0 + 512);
    gld16(Wb + offW0, lW0);
    gld16(Wb + offW1, lW0 + 512);

    f32x4 acc[4][4];
#pragma unroll
    for (int i = 0; i < 4; ++i)
#pragma unroll
        for (int j = 0; j < 4; ++j)
            acc[i][j] = (f32x4){0.f, 0.f, 0.f, 0.f};
    f32x4 acc_lg[2];
    acc_lg[0] = (f32x4){0.f, 0.f, 0.f, 0.f};
    acc_lg[1] = (f32x4){0.f, 0.f, 0.f, 0.f};

    int g = 0;   // flat step index
    for (int nt = 0; nt < 5; ++nt) {
        for (int st = 0; st < KS; ++st, ++g) {
            __syncthreads();   // drains prefetch issued at g-1
            if (g + 1 < Stot) {
                pnkk += 32;
                if (pnkk == Kin) {   // next n-tile: K wraps, W column base advances
                    pnkk = 0;
                    ++pnt;
                    Wb = W + (long long)pnt * 128 * 352;
                }
                const int pp = (g + 1) & 1;
                gld16(Ab + offA0 + pnkk, lA0 + pp * (128 * 32));
                gld16(Ab + offA1 + pnkk, lA0 + pp * (128 * 32) + 512);
                gld16(Wb + offW0 + pnkk, lW0 + pp * (128 * 32));
                gld16(Wb + offW1 + pnkk, lW0 + pp * (128 * 32) + 512);
            }
            const int cp = g & 1;
            bf16x8 af[4], bfr[4];
#pragma unroll
            for (int f = 0; f < 4; ++f)
                af[f] = *(const bf16x8*)&lsA[cp][(mbase + f * 16 + ln) * 32 + csel];
#pragma unroll
            for (int f = 0; f < 4; ++f)
                bfr[f] = *(const bf16x8*)&lsW[cp][(nbase + f * 16 + ln) * 32 + csel];
#pragma unroll
            for (int i = 0; i < 4; ++i)
#pragma unroll
                for (int j = 0; j < 4; ++j)
                    acc[i][j] = __builtin_amdgcn_mfma_f32_16x16x32_bf16(
                        af[i], bfr[j], acc[i][j], 0, 0, 0);
        }

        // tile epilogue: tanh -> bf16 h-tile into LDS (no global write)
#pragma unroll
        for (int j = 0; j < 4; ++j) {
            const int hc = nbase + j * 16 + ln;          // local h-col 0..127
            const float sh = bz[nt * 128 + hc];
#pragma unroll
            for (int i = 0; i < 4; ++i) {
                const int br = mbase + i * 16 + qd * 4;  // batch row (local)
#pragma unroll
                for (int rr = 0; rr < 4; ++rr)
                    lsH[(br + rr) * 132 + hc] = f2bf(tanh_fast(acc[i][j][rr] + sh));
                acc[i][j] = (f32x4){0.f, 0.f, 0.f, 0.f};
            }
        }
        // hoist logits B-frags (global, L2-hot) before the barrier
        bf16x8 bfrg[4];
#pragma unroll
        for (int ks = 0; ks < 4; ++ks)
            bfrg[ks] = *(const bf16x8*)&Wbp[((long long)z * 16 + ln) * 640 +
                                            nt * 128 + ks * 32 + qd * 8];
        __syncthreads();   // all h writes visible (also drains next-tile prefetch)

        // logits partial GEMM: rows wave*32..+31, K = this tile's 128 h-cols
#pragma unroll
        for (int ks = 0; ks < 4; ++ks) {
#pragma unroll
            for (int i = 0; i < 2; ++i) {
                const int base = (wave * 32 + i * 16 + ln) * 132 + ks * 32 + qd * 8;
                const uint2 u0 = *(const uint2*)&lsH[base];
                const uint2 u1 = *(const uint2*)&lsH[base + 4];
                u32 w4[4] = {u0.x, u0.y, u1.x, u1.y};
                bf16x8 a8;
                __builtin_memcpy(&a8, w4, 16);
                acc_lg[i] = __builtin_amdgcn_mfma_f32_16x16x32_bf16(
                    a8, bfrg[ks], acc_lg[i], 0, 0, 0);
            }
        }
        // next tile's first MLP step barrier orders lsH reuse
    }

    // softmax over the 16-lane group (pad cols have bbp=-1e30 -> excluded)
    const float bias = bbp[z * 16 + ln];
#pragma unroll
    for (int i = 0; i < 2; ++i) {
#pragma unroll
        for (int rr = 0; rr < 4; ++rr) {
            const float v = acc_lg[i][rr] + bias;
            float mx = v;
#pragma unroll
            for (int mk = 1; mk < 16; mk <<= 1)
                mx = fmaxf(mx, __shfl_xor(mx, mk));
            const float e = __expf(v - mx);
            float ssum = e;
#pragma unroll
            for (int mk = 1; mk < 16; mk <<= 1)
                ssum += __shfl_xor(ssum, mk);
            const float p = e / ssum;
            const int row = m0 + wave * 32 + i * 16 + qd * 4 + rr;
            if (ln < 10) {
                if (STAGE == 1)
                    preds[((long long)z * Bc + row) * 10 + ln] = f2bf(p);
                else
                    dout[81920 + ((long long)z * 8192 + gbase + row) * 10 + ln] = p;
            }
        }
    }
}

// ---------------------------------------------------------------------------
// FUSED conv1 + BN + ReLU + maxpool3s2p1, v2 (round 8): NO LDS, NO BARRIERS.
// ---------------------------------------------------------------------------
__global__ __launch_bounds__(256) void conv1pool(
    const u16* __restrict__ xcol, const u16* __restrict__ W1t, u16* __restrict__ p1,
    const float* __restrict__ epiA, const float* __restrict__ epiB, int Bc)
{
    const int tid = threadIdx.x;
    const int wave = tid >> 6;
    const int lane = tid & 63;
    const int ln = lane & 15, qd = lane >> 4;

    const int b0 = blockIdx.x * 128;
    const int so = blockIdx.y;            // pooled spatial index 0..99
    const int ho = so / 10, wo = so % 10;

    const int mbase = (wave >> 1) * 64;
    const int nbase = (wave & 1) * 32;

    bf16x8 bfr[2];
#pragma unroll
    for (int j = 0; j < 2; ++j)
        bfr[j] = *(const bf16x8*)&W1t[(nbase + j * 16 + ln) * 32 + qd * 8];

    float sc2[2], sh[2];
#pragma unroll
    for (int j = 0; j < 2; ++j) {
        const int n = nbase + j * 16 + ln;
        sc2[j] = epiA[n];
        sh[j] = epiB[n];
    }

    f32x4 best[4][2];
#pragma unroll
    for (int i = 0; i < 4; ++i)
#pragma unroll
        for (int j = 0; j < 2; ++j)
            best[i][j] = (f32x4){0.f, 0.f, 0.f, 0.f};

#pragma unroll
    for (int st = 0; st < 9; ++st) {
        int hh = 2 * ho - 1 + st / 3;
        int ww = 2 * wo - 1 + st % 3;
        hh = hh < 0 ? 0 : (hh > 19 ? 19 : hh);
        ww = ww < 0 ? 0 : (ww > 19 ? 19 : ww);
        const u16* Ab = xcol + (long long)((hh * 20 + ww) * Bc + b0) * 32;

        bf16x8 af[4];
#pragma unroll
        for (int f = 0; f < 4; ++f)
            af[f] = *(const bf16x8*)&Ab[(mbase + f * 16 + ln) * 32 + qd * 8];

#pragma unroll
        for (int i = 0; i < 4; ++i)
#pragma unroll
            for (int j = 0; j < 2; ++j) {
                f32x4 acc = (f32x4){0.f, 0.f, 0.f, 0.f};
                acc = __builtin_amdgcn_mfma_f32_16x16x32_bf16(af[i], bfr[j], acc, 0, 0, 0);
#pragma unroll
                for (int rr = 0; rr < 4; ++rr) {
                    const float v = fmaxf(acc[rr] * sc2[j] + sh[j], 0.f);
                    best[i][j][rr] = fmaxf(best[i][j][rr], v);
                }
            }
    }

#pragma unroll
    for (int j = 0; j < 2; ++j) {
        const int n = nbase + j * 16 + ln;
#pragma unroll
        for (int i = 0; i < 4; ++i) {
            const int mrow = mbase + i * 16 + qd * 4;
#pragma unroll
            for (int rr = 0; rr < 4; ++rr)
                p1[(long long)(so * Bc + b0 + mrow + rr) * 64 + n] = f2bf(best[i][j][rr]);
        }
    }
}

// ---------------------------------------------------------------------------
// x chunk [Bc,3,20,20] fp32 -> xt [400][Bc][4] bf16 (ch padded to 4, pad=0)
// ---------------------------------------------------------------------------
__global__ __launch_bounds__(256) void transpose_x(
    const float* __restrict__ x, u16* __restrict__ xt, int Bc, int bshift)
{
    const int t = blockIdx.x * 256 + threadIdx.x;
    if (t >= 400 * Bc) return;
    const int s = t >> bshift;
    const int b = t & (Bc - 1);
    const u32 c0 = f2bf(x[((long long)b * 3 + 0) * 400 + s]);
    const u32 c1 = f2bf(x[((long long)b * 3 + 1) * 400 + s]);
    const u32 c2 = f2bf(x[((long long)b * 3 + 2) * 400 + s]);
    uint2 st;
    st.x = c0 | (c1 << 16);
    st.y = c2;                              // high 16 = 0 pad
    *(uint2*)(xt + ((long long)s * Bc + b) * 4) = st;
}

// ---------------------------------------------------------------------------
// im2col for conv1: xt[400][Bc][4] -> xcol[400][Bc][32] (k = tap*3+ci, pad 0).
// ---------------------------------------------------------------------------
__global__ __launch_bounds__(256) void im2col1(
    const u16* __restrict__ xt, u16* __restrict__ xcol, int Bc, int bshift)
{
    const int t = blockIdx.x * 256 + threadIdx.x;
    if (t >= 400 * Bc) return;
    const int s = t >> bshift;
    const int b = t & (Bc - 1);
    const int hh = s / 20, ww = s % 20;

    u32 p0, q0, p1, q1, p2, q2, p3, q3, p4, q4, p5, q5, p6, q6, p7, q7, p8, q8;
#define LOADTAP(T, P, Q)                                                      \
    {                                                                         \
        const int ih = hh + (T) / 3 - 1, iw = ww + (T) % 3 - 1;               \
        P = 0u; Q = 0u;                                                       \
        if (ih >= 0 && ih < 20 && iw >= 0 && iw < 20) {                       \
            const uint2 v = *(const uint2*)(xt +                              \
                ((long long)(ih * 20 + iw) * Bc + b) * 4);                    \
            P = v.x; Q = v.y;                                                 \
        }                                                                     \
    }
    LOADTAP(0, p0, q0) LOADTAP(1, p1, q1) LOADTAP(2, p2, q2)
    LOADTAP(3, p3, q3) LOADTAP(4, p4, q4) LOADTAP(5, p5, q5)
    LOADTAP(6, p6, q6) LOADTAP(7, p7, q7) LOADTAP(8, p8, q8)
#undef LOADTAP

    u16* o = xcol + (long long)t * 32;
    uint4 w;
    w.x = p0;                w.y = q0 | (p1 << 16);
    w.z = (p1 >> 16) | (q1 << 16);
    w.w = p2;
    *(uint4*)(o + 0) = w;
    w.x = q2 | (p3 << 16);   w.y = (p3 >> 16) | (q3 << 16);
    w.z = p4;                w.w = q4 | (p5 << 16);
    *(uint4*)(o + 8) = w;
    w.x = (p5 >> 16) | (q5 << 16);
    w.y = p6;                w.z = q6 | (p7 << 16);
    w.w = (p7 >> 16) | (q7 << 16);
    *(uint4*)(o + 16) = w;
    w.x = p8;                w.y = q8;   // k=24..26 (+pad)
    w.z = 0u;                w.w = 0u;
    *(uint4*)(o + 24) = w;
}

// ---------------------------------------------------------------------------
// maxpool 3x3 s2 p1, square maps: src[Hi*Hi][Bc][CH] -> dst[Ho*Ho][Bc][CH].
// ---------------------------------------------------------------------------
template <int CH>
__global__ __launch_bounds__(256) void pool_k(
    const u16* __restrict__ src, u16* __restrict__ dst, int Bc, int Hi, int Ho)
{
    constexpr int G = CH / 8;
    const int t = blockIdx.x * 256 + threadIdx.x;
    const int cc = t & (G - 1);
    const int b = t / G;
    if (b >= Bc) return;
    const int so = blockIdx.y;
    const int ho = so / Ho, wo = so % Ho;
    float best[8];
#pragma unroll
    for (int e = 0; e < 8; ++e) best[e] = 0.f;
    for (int ph = 0; ph < 3; ++ph) {
        const int hh = 2 * ho - 1 + ph;
        if (hh < 0 || hh >= Hi) continue;
        for (int pw = 0; pw < 3; ++pw) {
            const int ww = 2 * wo - 1 + pw;
            if (ww < 0 || ww >= Hi) continue;
            const uint4 u = *(const uint4*)(src + ((long long)(hh * Hi + ww) * Bc + b) * CH + cc * 8);
            const u32 uw[4] = {u.x, u.y, u.z, u.w};
#pragma unroll
            for (int e = 0; e < 4; ++e) {
                best[2 * e]     = fmaxf(best[2 * e],     bf2f((u16)(uw[e] & 0xffff)));
                best[2 * e + 1] = fmaxf(best[2 * e + 1], bf2f((u16)(uw[e] >> 16)));
            }
        }
    }
    u32 pk[4];
#pragma unroll
    for (int e = 0; e < 4; ++e)
        pk[e] = (u32)f2bf(best[2 * e]) | (((u32)f2bf(best[2 * e + 1])) << 16);
    uint4 st;
    st.x = pk[0]; st.y = pk[1]; st.z = pk[2]; st.w = pk[3];
    *(uint4*)(dst + ((long long)so * Bc + b) * CH + cc * 8) = st;
}

// ---------------------------------------------------------------------------
// Stage-2 input assembly.
// ---------------------------------------------------------------------------
__device__ __forceinline__ void neighbors5x5(int i, int* nb) {
    const int w = 5, size = 25;
    int cnt = 0;
    if (i - w >= 0) nb[cnt++] = i - w;
    if (i % w != 0) nb[cnt++] = i - 1;
    if ((i + 1) % w != 0) nb[cnt++] = i + 1;
    if (i + w < size) nb[cnt++] = i + w;
    if (i - w - 1 >= 0 && i % w != 0) nb[cnt++] = i - w - 1;
    if (i - w + 1 >= 0 && (i + 1) % w != 0) nb[cnt++] = i - w + 1;
    if (i + w - 1 < size && i % w != 0) nb[cnt++] = i + w - 1;
    if (i + w + 1 < size && (i + 1) % w != 0) nb[cnt++] = i + w + 1;
    for (; cnt < 8; ++cnt) nb[cnt] = -1;
}

__global__ __launch_bounds__(256) void gather_nb(
    const u16* __restrict__ preds, const u16* __restrict__ feats, u16* __restrict__ A2,
    int Bc, int bshift)
{
    const int g = blockIdx.x * 256 + threadIdx.x;  // n*Bc+b
    if (g >= 25 * Bc) return;
    const int n = g >> bshift;
    const int b = g & (Bc - 1);
    int nb[8];
    neighbors5x5(n, nb);
    u16* dst = A2 + (long long)g * 352;
#pragma unroll
    for (int j = 0; j < 8; ++j) {
        u32* d32 = (u32*)(dst + j * 10);
        if (nb[j] >= 0) {
            const u32* s32 = (const u32*)(preds + ((long long)nb[j] * Bc + b) * 10);
#pragma unroll
            for (int q = 0; q < 5; ++q) d32[q] = s32[q];
        } else {
#pragma unroll
            for (int q = 0; q < 5; ++q) d32[q] = 0u;
        }
    }
    const uint4* fs = (const uint4*)(feats + (long long)g * 256);
    uint4* fd = (uint4*)(dst + 80);
#pragma unroll
    for (int q = 0; q < 32; ++q) fd[q] = fs[q];
    uint4 z;
    z.x = 0u; z.y = 0u; z.z = 0u; z.w = 0u;
    *(uint4*)(dst + 336) = z;
    *(uint4*)(dst + 344) = z;
}

__global__ __launch_bounds__(256) void mean_k(float* __restrict__ dout)
{
    const int t = blockIdx.x * 256 + threadIdx.x;
    float s = 0.f;
#pragma unroll
    for (int n = 0; n < 25; ++n) s += dout[81920 + n * 81920 + t];
    dout[t] = s * 0.04f;
}

// ---------------------------------------------------------------------------
// Weight/param prep (once per launch)
// ---------------------------------------------------------------------------
__global__ void prep_bn_all(
    const float* b1, const float* g1, const float* be1, const float* m1, const float* v1,
    const float* b2, const float* g2, const float* be2, const float* m2, const float* v2,
    const float* b3, const float* g3, const float* be3, const float* m3, const float* v3,
    const float* b4, const float* g4, const float* be4, const float* m4, const float* v4,
    float* bnA, float* bnB)
{
    const int t = blockIdx.x * 256 + threadIdx.x;
    if (t >= 704) return;
    const float *bp, *gp, *bep, *mp, *vp;
    int idx;
    if (t < 64)       { bp=b1; gp=g1; bep=be1; mp=m1; vp=v1; idx=t; }
    else if (t < 192) { bp=b2; gp=g2; bep=be2; mp=m2; vp=v2; idx=t-64; }
    else if (t < 448) { bp=b3; gp=g3; bep=be3; mp=m3; vp=v3; idx=t-192; }
    else              { bp=b4; gp=g4; bep=be4; mp=m4; vp=v4; idx=t-448; }
    const float A = gp[idx] * rsqrtf(vp[idx] + 1e-5f);
    bnA[t] = A;
    bnB[t] = (bp[idx] - mp[idx]) * A + bep[idx];
}

// W1 [64][3][3][3] -> W1t [64][32], k = tap*3+ci (tap = kh*3+kw), pad 0
__global__ void prep_w1col(const float* __restrict__ W1, u16* __restrict__ W1t)
{
    const int t = blockIdx.x * 256 + threadIdx.x;
    if (t >= 64 * 32) return;
    const int n = t >> 5, k = t & 31;
    u16 v = 0;
    if (k < 27) {
        const int tap = k / 3, ci = k % 3;
        v = f2bf(W1[n * 27 + ci * 9 + tap]);
    }
    W1t[t] = v;
}

// W [Co][Ci][3][3] fp32 -> Wt [9][Co][Ci] bf16
__global__ void prep_convw(const float* __restrict__ W, u16* __restrict__ Wt, int Co, int Ci)
{
    const int t = blockIdx.x * 256 + threadIdx.x;
    const int tot = 9 * Co * Ci;
    if (t >= tot) return;
    const int sh = t / (Co * Ci);
    const int rem = t % (Co * Ci);
    const int co = rem / Ci, ci = rem % Ci;
    Wt[t] = f2bf(W[(long long)(co * Ci + ci) * 9 + sh]);
}

__global__ void prep_wat(const float* __restrict__ Wa, u16* __restrict__ Wat)
{
    const int t = blockIdx.x * 256 + threadIdx.x;
    if (t >= 25 * 640 * 352) return;
    const int n = t / (640 * 352);
    const int rem = t % (640 * 352);
    const int hcol = rem / 352;
    const int k = rem % 352;
    float v = 0.f;
    if (hcol < 600 && k < 336) v = Wa[((long long)n * 336 + k) * 600 + hcol];
    Wat[t] = f2bf(v);
}

__global__ void prep_ba(const float* __restrict__ ba, float* __restrict__ bap)
{
    const int t = blockIdx.x * 256 + threadIdx.x;
    if (t >= 25 * 640) return;
    const int n = t / 640, hcol = t % 640;
    bap[t] = (hcol < 600) ? ba[n * 600 + hcol] : 0.f;
}

// Wb [25][600][10] fp32 -> Wbp [25][16][640] bf16 (transposed, zero-pad);
// bb [25][10] -> bbp [25][16] fp32 (pad -1e30 so softmax ignores pad cols)
__global__ void prep_wbt(const float* __restrict__ Wb, const float* __restrict__ bb,
                         u16* __restrict__ Wbp, float* __restrict__ bbp)
{
    const int t = blockIdx.x * 256 + threadIdx.x;
    if (t < 25 * 16 * 640) {
        const int n = t / (16 * 640);
        const int rem = t % (16 * 640);
        const int c = rem / 640, k = rem % 640;
        u16 v = 0;
        if (c < 10 && k < 600) v = f2bf(Wb[((long long)n * 600 + k) * 10 + c]);
        Wbp[t] = v;
    }
    if (t < 25 * 16) {
        const int n = t >> 4, c = t & 15;
        bbp[t] = (c < 10) ? bb[n * 10 + c] : -1e30f;
    }
}

// ---------------------------------------------------------------------------
extern "C" void kernel_launch(void* const* d_in, const int* in_sizes, int n_in,
                              void* d_out, int out_size, void* d_ws, size_t ws_size,
                              hipStream_t stream)
{
    (void)in_sizes; (void)n_in; (void)out_size;

    const float* x  = (const float*)d_in[0];
    const float* W1 = (const float*)d_in[1];
    const float* b1 = (const float*)d_in[2];
    const float* g1 = (const float*)d_in[3];
    const float* be1= (const float*)d_in[4];
    const float* m1 = (const float*)d_in[5];
    const float* v1 = (const float*)d_in[6];
    const float* W2 = (const float*)d_in[7];
    const float* b2 = (const float*)d_in[8];
    const float* g2 = (const float*)d_in[9];
    const float* be2= (const float*)d_in[10];
    const float* m2 = (const float*)d_in[11];
    const float* v2 = (const float*)d_in[12];
    const float* W3 = (const float*)d_in[13];
    const float* b3 = (const float*)d_in[14];
    const float* g3 = (const float*)d_in[15];
    const float* be3= (const float*)d_in[16];
    const float* m3 = (const float*)d_in[17];
    const float* v3 = (const float*)d_in[18];
    const float* W4 = (const float*)d_in[19];
    const float* b4 = (const float*)d_in[20];
    const float* g4 = (const float*)d_in[21];
    const float* be4= (const float*)d_in[22];
    const float* m4 = (const float*)d_in[23];
    const float* v4 = (const float*)d_in[24];
    const float* Wa = (const float*)d_in[25];
    const float* ba = (const float*)d_in[26];
    const float* Wb = (const float*)d_in[27];
    const float* bb = (const float*)d_in[28];
    float* dout = (float*)d_out;

    // ---- choose Bc: overlay peak = 44032 bytes per batch element ----
    auto al = [](long long v) { return (v + 255LL) & ~255LL; };
    const long long fixedB = al(4096) + al(147456) + al(589824) + al(1179648) +
                             al(11264000) + al(64000) + al(2816) + al(2816) +
                             al(512000) + al(1600);
    int Bc = 256;
    for (int cand = 8192; cand >= 256; cand >>= 1) {
        long long need = fixedB + al(44032LL * cand);
        if (need <= (long long)ws_size) { Bc = cand; break; }
    }
    const int bshift = __builtin_ctz((unsigned)Bc);
    const int C = 8192 / Bc;

    // ---- workspace: fixed region + one overlaid chunk region ----
    char* wsp = (char*)d_ws;
    long long off = 0;
    auto alloc = [&](long long bytes) { long long o = off; off += al(bytes); return o; };
    u16* W1t  = (u16*)(wsp + alloc(4096));
    u16* Wt2  = (u16*)(wsp + alloc(147456));
    u16* Wt3  = (u16*)(wsp + alloc(589824));
    u16* Wt4  = (u16*)(wsp + alloc(1179648));
    u16* Wat  = (u16*)(wsp + alloc(11264000));
    float* bap = (float*)(wsp + alloc(64000));
    float* bnA = (float*)(wsp + alloc(2816));
    float* bnB = (float*)(wsp + alloc(2816));
    u16* Wbp  = (u16*)(wsp + alloc(512000));
    float* bbp = (float*)(wsp + alloc(1600));
    char* ch = wsp + alloc(44032LL * Bc);
    // overlay (bytes-per-elem offsets; lifetimes disjoint where ranges overlap):
    u16* xt   = (u16*)(ch + 0LL     * Bc);   // [0,3200)       t1-t1.5
    u16* xcol = (u16*)(ch + 3200LL  * Bc);   // [3200,28800)   t1.5-t2
    u16* p1   = (u16*)(ch + 28800LL * Bc);   // [28800,41600)  t2-t3
    u16* a2   = (u16*)(ch + 0LL     * Bc);   // [0,25600)      t3-t3.5
    u16* p2   = (u16*)(ch + 25600LL * Bc);   // [25600,32000)  t3.5-t4
    u16* a3   = (u16*)(ch + 0LL     * Bc);   // [0,12800)      t4-t5
    u16* a4   = (u16*)(ch + 12800LL * Bc);   // [12800,25600)  t5-t8
    u16* preds= (u16*)(ch + 25600LL * Bc);   // [25600,26112)  t6-t7
    u16* A2   = (u16*)(ch + 26112LL * Bc);   // [26112,43712)  t7-t8

    // ---- prep (once) ----
    prep_bn_all<<<dim3(3), 256, 0, stream>>>(b1,g1,be1,m1,v1, b2,g2,be2,m2,v2,
                                             b3,g3,be3,m3,v3, b4,g4,be4,m4,v4, bnA, bnB);
    prep_w1col<<<dim3(8), 256, 0, stream>>>(W1, W1t);
    prep_convw<<<dim3(288),  256, 0, stream>>>(W2, Wt2, 128, 64);
    prep_convw<<<dim3(1152), 256, 0, stream>>>(W3, Wt3, 256, 128);
    prep_convw<<<dim3(2304), 256, 0, stream>>>(W4, Wt4, 256, 256);
    prep_wat<<<dim3(22000), 256, 0, stream>>>(Wa, Wat);
    prep_ba<<<dim3(63), 256, 0, stream>>>(ba, bap);
    prep_wbt<<<dim3(1000), 256, 0, stream>>>(Wb, bb, Wbp, bbp);

    // ---- batch chunks ----
    for (int c = 0; c < C; ++c) {
        const float* xc = x + (long long)c * Bc * 1200;

        transpose_x<<<dim3(400 * Bc / 256), 256, 0, stream>>>(xc, xt, Bc, bshift);
        im2col1<<<dim3(400 * Bc / 256), 256, 0, stream>>>(xt, xcol, Bc, bshift);
        conv1pool<<<dim3(Bc / 128, 100), 256, 0, stream>>>(xcol, W1t, p1, bnA, bnB, Bc);

        gemm_bt<0,128><<<dim3(100 * Bc / 128, 1), 256, 0, stream>>>(p1, Wt2, a2, bnA + 64, bnB + 64,
            64, 128, 9, 10, 10, 64, 64, 128, 0LL, 0LL, 0LL, 0, Bc, bshift);
        pool_k<128><<<dim3(Bc * 16 / 256, 25), 256, 0, stream>>>(a2, p2, Bc, 10, 5);

        gemm_bt<0,128><<<dim3(25 * Bc / 128, 2), 256, 0, stream>>>(p2, Wt3, a3, bnA + 192, bnB + 192,
            128, 256, 9, 5, 5, 128, 128, 256, 0LL, 0LL, 0LL, 0, Bc, bshift);
        gemm_bt<0,128><<<dim3(25 * Bc / 128, 2), 256, 0, stream>>>(a3, Wt4, a4, bnA + 448, bnB + 448,
            256, 256, 9, 5, 5, 256, 256, 256, 0LL, 0LL, 0LL, 0, Bc, bshift);

        // stage 1: fused MLP+tanh+logits+softmax (zeros||feats -> Wa k-rows [80:336))
        mlp_head<1><<<dim3(Bc / 128, 1, 25), 256, 0, stream>>>(
            a4, Wat + 80, bap, Wbp, bbp, preds, nullptr, 256, Bc, 0);

        // stage 2
        gather_nb<<<dim3(25 * Bc / 256, 1), 256, 0, stream>>>(preds, a4, A2, Bc, bshift);
        mlp_head<2><<<dim3(Bc / 128, 1, 25), 256, 0, stream>>>(
            A2, Wat, bap, Wbp, bbp, nullptr, dout, 352, Bc, c * Bc);
    }

    mean_k<<<dim3(320), 256, 0, stream>>>(dout);
}